// Round 1
// baseline (2434.940 us; speedup 1.0000x reference)
//
#include <hip/hip_runtime.h>
#include <cstdint>
#include <cmath>

// Problem constants (from reference):
#define NN 50000
#define EE 500000
#define GG 2000
// IN=64, H=128, ED=16, OUT=1, NUM_GAT=2, T=2

#define DEV __device__ __forceinline__

DEV float sigf(float x) { return 1.f / (1.f + expf(-x)); }

DEV float actf(float x, int act) {
    if (act == 1) return x >= 0.f ? x : 0.01f * x;        // leaky 0.01
    if (act == 2) return x > 0.f ? x : expf(x) - 1.f;     // elu
    if (act == 3) return x > 0.f ? x : 0.f;               // relu
    return x;
}

// float atomic max via int/uint atomics (works for mixed signs; init to -inf)
DEV void atomicMaxF(float* addr, float v) {
    if (v >= 0.f) atomicMax((int*)addr, __float_as_int(v));
    else          atomicMin((unsigned int*)addr, __float_as_uint(v));
}

// ---------------------------------------------------------------------------
// Generic tiled fp32 GEMM: C[M,Nout] = act(A[M,K] @ W[Nout,K]^T + bias)
// W row pitch = wpitch (>= K) to support strided weight views (nd_lin1_w).
// BM=BN=64, BK=16, 256 threads, 4x4 per thread. Nout % 64 == 0, K % 16 == 0.
// ---------------------------------------------------------------------------
__global__ __launch_bounds__(256) void gemm_k(
    const float* __restrict__ A, const float* __restrict__ W,
    const float* __restrict__ bias, float* __restrict__ C,
    int M, int K, int Nout, int wpitch, int act)
{
    __shared__ float As[16][65];
    __shared__ float Bs[16][65];
    const int tid = threadIdx.x;
    const int bm = blockIdx.y * 64;
    const int bn = blockIdx.x * 64;
    const int tx = tid & 15, ty = tid >> 4;
    const int lrow = tid >> 2;          // 0..63
    const int lkq  = (tid & 3) << 2;    // 0,4,8,12

    float acc[4][4] = {};

    for (int k0 = 0; k0 < K; k0 += 16) {
        float4 av = make_float4(0.f, 0.f, 0.f, 0.f);
        int m = bm + lrow;
        if (m < M) av = *(const float4*)(A + (size_t)m * K + k0 + lkq);
        float4 wv = make_float4(0.f, 0.f, 0.f, 0.f);
        int n = bn + lrow;
        if (n < Nout) wv = *(const float4*)(W + (size_t)n * wpitch + k0 + lkq);

        __syncthreads();
        As[lkq + 0][lrow] = av.x; As[lkq + 1][lrow] = av.y;
        As[lkq + 2][lrow] = av.z; As[lkq + 3][lrow] = av.w;
        Bs[lkq + 0][lrow] = wv.x; Bs[lkq + 1][lrow] = wv.y;
        Bs[lkq + 2][lrow] = wv.z; Bs[lkq + 3][lrow] = wv.w;
        __syncthreads();

#pragma unroll
        for (int k = 0; k < 16; ++k) {
            float a0 = As[k][ty * 4 + 0], a1 = As[k][ty * 4 + 1];
            float a2 = As[k][ty * 4 + 2], a3 = As[k][ty * 4 + 3];
            float b0 = Bs[k][tx * 4 + 0], b1 = Bs[k][tx * 4 + 1];
            float b2 = Bs[k][tx * 4 + 2], b3 = Bs[k][tx * 4 + 3];
            acc[0][0] += a0 * b0; acc[0][1] += a0 * b1; acc[0][2] += a0 * b2; acc[0][3] += a0 * b3;
            acc[1][0] += a1 * b0; acc[1][1] += a1 * b1; acc[1][2] += a1 * b2; acc[1][3] += a1 * b3;
            acc[2][0] += a2 * b0; acc[2][1] += a2 * b1; acc[2][2] += a2 * b2; acc[2][3] += a2 * b3;
            acc[3][0] += a3 * b0; acc[3][1] += a3 * b1; acc[3][2] += a3 * b2; acc[3][3] += a3 * b3;
        }
    }

#pragma unroll
    for (int i = 0; i < 4; ++i) {
        int m = bm + ty * 4 + i;
        if (m >= M) continue;
#pragma unroll
        for (int j = 0; j < 4; ++j) {
            int n = bn + tx * 4 + j;
            float v = acc[i][j];
            if (bias) v += bias[n];
            C[(size_t)m * Nout + n] = actf(v, act);
        }
    }
}

// ---------------------------------------------------------------------------
// nd_conv edge scatter: acc[dst] += leaky(p[src] + edge_attr @ W1b^T)
// one thread per (edge, h); W1b is nd_lin1_w[:,128:144] (pitch 144).
// ---------------------------------------------------------------------------
__global__ void nd_edge_k(const int* __restrict__ ei, const float* __restrict__ ea,
                          const float* __restrict__ ndw, const float* __restrict__ p,
                          float* __restrict__ acc, int E)
{
    int gid = blockIdx.x * 256 + threadIdx.x;
    if (gid >= E * 128) return;
    int e = gid >> 7, h = gid & 127;
    int s = ei[e], d = ei[E + e];
    const float* eav = ea + e * 16;
    const float* wr = ndw + h * 144 + 128;
    float q = 0.f;
#pragma unroll
    for (int k = 0; k < 16; ++k) q += eav[k] * wr[k];
    float t = p[s * 128 + h] + q;
    t = t >= 0.f ? t : 0.01f * t;
    atomicAdd(acc + d * 128 + h, t);
}

// per-node dots with attention vectors: s_src[n] = xp[n]·asrc, s_dst[n] = xp[n]·adst
__global__ void node_dots_k(const float* __restrict__ xp, const float* __restrict__ asrc,
                            const float* __restrict__ adst, float* __restrict__ ssrc,
                            float* __restrict__ sdst)
{
    int n = blockIdx.x, t = threadIdx.x;   // 128 threads
    float v = xp[n * 128 + t];
    float a = v * asrc[t];
    float b = v * adst[t];
    for (int off = 32; off; off >>= 1) { a += __shfl_down(a, off); b += __shfl_down(b, off); }
    __shared__ float sa[2], sb[2];
    if ((t & 63) == 0) { sa[t >> 6] = a; sb[t >> 6] = b; }
    __syncthreads();
    if (t == 0) { ssrc[n] = sa[0] + sa[1]; sdst[n] = sb[0] + sb[1]; }
}

__global__ void edge_a_k(const int* __restrict__ ei, const float* __restrict__ ssrc,
                         const float* __restrict__ sdst, float* __restrict__ ae,
                         float* __restrict__ amax, int E)
{
    int e = blockIdx.x * 256 + threadIdx.x;
    if (e >= E) return;
    int s = ei[e], d = ei[E + e];
    float a = ssrc[s] + sdst[d];
    a = a >= 0.f ? a : 0.01f * a;
    ae[e] = a;
    atomicMaxF(amax + d, a);
}

__global__ void edge_b_k(const int* __restrict__ ei, float* __restrict__ ae,
                         const float* __restrict__ amax, float* __restrict__ den, int E)
{
    int e = blockIdx.x * 256 + threadIdx.x;
    if (e >= E) return;
    int d = ei[E + e];
    float v = expf(ae[e] - amax[d]);
    ae[e] = v;
    atomicAdd(den + d, v);
}

__global__ void edge_c_k(const int* __restrict__ ei, const float* __restrict__ ae,
                         const float* __restrict__ den, const float* __restrict__ xp,
                         float* __restrict__ acc, int E)
{
    int gid = blockIdx.x * 256 + threadIdx.x;
    if (gid >= E * 128) return;
    int e = gid >> 7, h = gid & 127;
    int s = ei[e], d = ei[E + e];
    float w = ae[e] / den[d];
    atomicAdd(acc + d * 128 + h, w * xp[s * 128 + h]);
}

// out[i] = act(in[i] + bias[i % 128])   (bias may be null)
__global__ void bias_act_k(const float* __restrict__ in, const float* __restrict__ bias,
                           float* __restrict__ outp, int total, int act)
{
    int gid = blockIdx.x * 256 + threadIdx.x;
    if (gid >= total) return;
    float v = in[gid];
    if (bias) v += bias[gid & 127];
    outp[gid] = actf(v, act);
}

__global__ void gru_combine_k(const float* __restrict__ gi, const float* __restrict__ gh,
                              const float* __restrict__ xprev, float* __restrict__ xout, int M)
{
    int gid = blockIdx.x * 256 + threadIdx.x;
    if (gid >= M * 128) return;
    int n = gid >> 7, j = gid & 127;
    const float* a = gi + n * 384;
    const float* b = gh + n * 384;
    float r = sigf(a[j] + b[j]);
    float z = sigf(a[j + 128] + b[j + 128]);
    float nn = tanhf(a[j + 256] + r * b[j + 256]);
    float v = (1.f - z) * nn + z * xprev[gid];
    xout[gid] = v > 0.f ? v : 0.f;   // relu(gru(...))
}

__global__ void agg_k(const float* __restrict__ xin, const int* __restrict__ batch,
                      float* __restrict__ agg, int total)
{
    int gid = blockIdx.x * 256 + threadIdx.x;
    if (gid >= total) return;
    int n = gid >> 7, j = gid & 127;
    atomicAdd(agg + batch[n] * 128 + j, xin[gid]);
}

__global__ void add_k(const float* __restrict__ a, const float* __restrict__ b,
                      float* __restrict__ c, int total)
{
    int gid = blockIdx.x * 256 + threadIdx.x;
    if (gid >= total) return;
    c[gid] = a[gid] + b[gid];
}

__global__ void lstm_combine_k(const float* __restrict__ g1, const float* __restrict__ g2,
                               const float* __restrict__ hg, float* __restrict__ outp, int total)
{
    int gid = blockIdx.x * 256 + threadIdx.x;
    if (gid >= total) return;
    int g = gid >> 7, j = gid & 127;
    const float* a = g1 + g * 512;
    const float* b = g2 + g * 512;
    float ii = a[j]       + b[j];
    float ff = a[j + 128] + b[j + 128];
    float gg = a[j + 256] + b[j + 256];
    float oo = a[j + 384] + b[j + 384];
    float c  = hg[gid];
    float c2 = sigf(ff) * c + sigf(ii) * tanhf(gg);
    outp[gid] = sigf(oo) * tanhf(c2);
}

__global__ void fill_k(float* __restrict__ p, float v, int n)
{
    int gid = blockIdx.x * 256 + threadIdx.x;
    if (gid < n) p[gid] = v;
}

__global__ void final_k(const float* __restrict__ oin, const float* __restrict__ w,
                        const float* __restrict__ b, float* __restrict__ y)
{
    int g = blockIdx.x, t = threadIdx.x;  // 128 threads
    float v = oin[g * 128 + t] * w[t];
    for (int off = 32; off; off >>= 1) v += __shfl_down(v, off);
    __shared__ float s2[2];
    if ((t & 63) == 0) s2[t >> 6] = v;
    __syncthreads();
    if (t == 0) y[g] = s2[0] + s2[1] + b[0];
}

// ---------------------------------------------------------------------------

extern "C" void kernel_launch(void* const* d_in, const int* in_sizes, int n_in,
                              void* d_out, int out_size, void* d_ws, size_t ws_size,
                              hipStream_t stream)
{
    const float* x      = (const float*)d_in[0];
    const int*   ei     = (const int*)  d_in[1];
    const float* ea     = (const float*)d_in[2];
    const int*   batch  = (const int*)  d_in[3];
    const float* lin1_w = (const float*)d_in[4];
    const float* lin1_b = (const float*)d_in[5];
    const float* nd1w   = (const float*)d_in[6];
    const float* nd2w   = (const float*)d_in[7];
    const float* ndb    = (const float*)d_in[8];
    const float* g0wih  = (const float*)d_in[9];
    const float* g0whh  = (const float*)d_in[10];
    const float* g0bih  = (const float*)d_in[11];
    const float* g0bhh  = (const float*)d_in[12];
    const float* gatw   = (const float*)d_in[13];
    const float* gatas  = (const float*)d_in[14];
    const float* gatad  = (const float*)d_in[15];
    const float* gatb   = (const float*)d_in[16];
    const float* gwih   = (const float*)d_in[17];
    const float* gwhh   = (const float*)d_in[18];
    const float* gbih   = (const float*)d_in[19];
    const float* gbhh   = (const float*)d_in[20];
    const float* ginw   = (const float*)d_in[21];
    const float* ginb   = (const float*)d_in[22];
    const float* lwih   = (const float*)d_in[23];
    const float* lwhh   = (const float*)d_in[24];
    const float* lbih   = (const float*)d_in[25];
    const float* lbhh   = (const float*)d_in[26];
    const float* l2w    = (const float*)d_in[27];
    const float* l2b    = (const float*)d_in[28];
    float* outp = (float*)d_out;

    const int N = NN, E = EE, G = GG;
    const int CH = 10000;   // GRU row chunk (N % CH == 0) to bound gi/gh scratch

    float* ws = (float*)d_ws;
    size_t off = 0;
    auto alloc = [&](size_t n) {
        float* r = ws + off;
        off += (n + 63) & ~(size_t)63;
        return r;
    };
    float* x1   = alloc((size_t)N * 128);  // also reused as xcur after GAT0 GRU
    float* hbuf = alloc((size_t)N * 128);
    float* accb = alloc((size_t)N * 128);
    float* xpb  = alloc((size_t)N * 128);  // holds p, then xp per GAT layer
    float* xc   = alloc((size_t)N * 128);
    float* gib  = alloc((size_t)CH * 384);
    float* ghb  = alloc((size_t)CH * 384);
    float* aeb  = alloc((size_t)E);
    float* amax = alloc((size_t)N);
    float* den  = alloc((size_t)N);
    float* ssrc = alloc((size_t)N);
    float* sdst = alloc((size_t)N);
    float* agg  = alloc((size_t)G * 128);
    float* oA   = alloc((size_t)G * 128);
    float* oB   = alloc((size_t)G * 128);
    float* hgb  = alloc((size_t)G * 128);
    float* tGA  = alloc((size_t)G * 128);
    float* g1b  = alloc((size_t)G * 512);
    float* g2b  = alloc((size_t)G * 512);
    (void)ws_size; // needs ~175 MB

    auto gemm = [&](const float* A, const float* W, const float* bias, float* C,
                    int M, int K, int Nout, int wpitch, int act) {
        dim3 grid(Nout / 64, (M + 63) / 64);
        gemm_k<<<grid, 256, 0, stream>>>(A, W, bias, C, M, K, Nout, wpitch, act);
    };
    auto nb = [](int n) { return (n + 255) / 256; };

    // GRU: xout = relu(gru_cell(xin, hin));  gi from xin, gh+carry from hin
    auto gru = [&](const float* xin, const float* hin,
                   const float* wih, const float* whh,
                   const float* bih, const float* bhh, float* xout) {
        for (int c = 0; c < N; c += CH) {
            gemm(xin + (size_t)c * 128, wih, bih, gib, CH, 128, 384, 128, 0);
            gemm(hin + (size_t)c * 128, whh, bhh, ghb, CH, 128, 384, 128, 0);
            gru_combine_k<<<nb(CH * 128), 256, 0, stream>>>(
                gib, ghb, hin + (size_t)c * 128, xout + (size_t)c * 128, CH);
        }
    };

    // 1) x1 = leaky(x @ lin1_w^T + lin1_b)
    gemm(x, lin1_w, lin1_b, x1, N, 64, 128, 64, 1);

    // 2) nd_conv. W2 hoisted out of the segment_sum:
    //    p = x1 @ W1a^T ; acc[dst] += leaky(p[src] + ea @ W1b^T) ; h = elu(acc @ W2^T + ndb)
    gemm(x1, nd1w, nullptr, xpb, N, 128, 128, 144, 0);
    hipMemsetAsync(accb, 0, (size_t)N * 128 * 4, stream);
    nd_edge_k<<<nb(E * 128), 256, 0, stream>>>(ei, ea, nd1w, xpb, accb, E);
    gemm(accb, nd2w, ndb, hbuf, N, 128, 128, 128, 2);

    // 3) xcur = relu(gru_cell(h, x1))  -> xc
    gru(hbuf, x1, g0wih, g0whh, g0bih, g0bhh, xc);

    // 4) GAT layers. xcur ping-pongs xc -> x1 -> xc.
    const float* xcur = xc;
    float* xnext = x1;
    for (int l = 0; l < 2; ++l) {
        gemm(xcur, gatw + (size_t)l * 128 * 128, nullptr, xpb, N, 128, 128, 128, 0);
        node_dots_k<<<N, 128, 0, stream>>>(xpb, gatas + l * 128, gatad + l * 128, ssrc, sdst);
        fill_k<<<nb(N), 256, 0, stream>>>(amax, -INFINITY, N);
        hipMemsetAsync(den, 0, (size_t)N * 4, stream);
        edge_a_k<<<nb(E), 256, 0, stream>>>(ei, ssrc, sdst, aeb, amax, E);
        edge_b_k<<<nb(E), 256, 0, stream>>>(ei, aeb, amax, den, E);
        hipMemsetAsync(accb, 0, (size_t)N * 128 * 4, stream);
        edge_c_k<<<nb(E * 128), 256, 0, stream>>>(ei, aeb, den, xpb, accb, E);
        bias_act_k<<<nb(N * 128), 256, 0, stream>>>(accb, gatb + l * 128, hbuf, N * 128, 2);
        gru(hbuf, xcur, gwih + (size_t)l * 384 * 128, gwhh + (size_t)l * 384 * 128,
            gbih + l * 384, gbhh + l * 384, xnext);
        const float* t = xcur; xcur = xnext; xnext = (float*)t;
    }

    // 5) readout: agg = segment_sum(xcur, batch); out = relu(agg)
    hipMemsetAsync(agg, 0, (size_t)G * 128 * 4, stream);
    agg_k<<<nb(N * 128), 256, 0, stream>>>(xcur, batch, agg, N * 128);
    bias_act_k<<<nb(G * 128), 256, 0, stream>>>(agg, nullptr, oA, G * 128, 3);

    // 6) T=2 GIN+LSTM refinement
    float* cur = oA; float* nxt = oB;
    for (int t = 0; t < 2; ++t) {
        add_k<<<nb(G * 128), 256, 0, stream>>>(cur, agg, tGA, G * 128);
        gemm(tGA, ginw, ginb, hgb, G, 128, 128, 128, 2);
        gemm(cur, lwih, lbih, g1b, G, 128, 512, 128, 0);
        gemm(hgb, lwhh, lbhh, g2b, G, 128, 512, 128, 0);
        lstm_combine_k<<<nb(G * 128), 256, 0, stream>>>(g1b, g2b, hgb, nxt, G * 128);
        float* tmp = cur; cur = nxt; nxt = tmp;
    }

    // 7) y = out @ lin2_w^T + lin2_b
    final_k<<<G, 128, 0, stream>>>(cur, l2w, l2b, outp);
}

// Round 2
// 1857.999 us; speedup vs baseline: 1.3105x; 1.3105x over previous
//
#include <hip/hip_runtime.h>
#include <cstdint>
#include <cmath>

// Problem constants (from reference):
#define NN 50000
#define EE 500000
#define GG 2000
// IN=64, H=128, ED=16, OUT=1, NUM_GAT=2, T=2

#define DEV __device__ __forceinline__

DEV float sigf(float x) { return 1.f / (1.f + expf(-x)); }

DEV float actf(float x, int act) {
    if (act == 1) return x >= 0.f ? x : 0.01f * x;        // leaky 0.01
    if (act == 2) return x > 0.f ? x : expf(x) - 1.f;     // elu
    if (act == 3) return x > 0.f ? x : 0.f;               // relu
    return x;
}

// ---------------------------------------------------------------------------
// Generic tiled fp32 GEMM: C[M,Nout] = act(A[M,K] @ W[Nout,K]^T + bias)
// ---------------------------------------------------------------------------
__global__ __launch_bounds__(256) void gemm_k(
    const float* __restrict__ A, const float* __restrict__ W,
    const float* __restrict__ bias, float* __restrict__ C,
    int M, int K, int Nout, int wpitch, int act)
{
    __shared__ float As[16][65];
    __shared__ float Bs[16][65];
    const int tid = threadIdx.x;
    const int bm = blockIdx.y * 64;
    const int bn = blockIdx.x * 64;
    const int tx = tid & 15, ty = tid >> 4;
    const int lrow = tid >> 2;          // 0..63
    const int lkq  = (tid & 3) << 2;    // 0,4,8,12

    float acc[4][4] = {};

    for (int k0 = 0; k0 < K; k0 += 16) {
        float4 av = make_float4(0.f, 0.f, 0.f, 0.f);
        int m = bm + lrow;
        if (m < M) av = *(const float4*)(A + (size_t)m * K + k0 + lkq);
        float4 wv = make_float4(0.f, 0.f, 0.f, 0.f);
        int n = bn + lrow;
        if (n < Nout) wv = *(const float4*)(W + (size_t)n * wpitch + k0 + lkq);

        __syncthreads();
        As[lkq + 0][lrow] = av.x; As[lkq + 1][lrow] = av.y;
        As[lkq + 2][lrow] = av.z; As[lkq + 3][lrow] = av.w;
        Bs[lkq + 0][lrow] = wv.x; Bs[lkq + 1][lrow] = wv.y;
        Bs[lkq + 2][lrow] = wv.z; Bs[lkq + 3][lrow] = wv.w;
        __syncthreads();

#pragma unroll
        for (int k = 0; k < 16; ++k) {
            float a0 = As[k][ty * 4 + 0], a1 = As[k][ty * 4 + 1];
            float a2 = As[k][ty * 4 + 2], a3 = As[k][ty * 4 + 3];
            float b0 = Bs[k][tx * 4 + 0], b1 = Bs[k][tx * 4 + 1];
            float b2 = Bs[k][tx * 4 + 2], b3 = Bs[k][tx * 4 + 3];
            acc[0][0] += a0 * b0; acc[0][1] += a0 * b1; acc[0][2] += a0 * b2; acc[0][3] += a0 * b3;
            acc[1][0] += a1 * b0; acc[1][1] += a1 * b1; acc[1][2] += a1 * b2; acc[1][3] += a1 * b3;
            acc[2][0] += a2 * b0; acc[2][1] += a2 * b1; acc[2][2] += a2 * b2; acc[2][3] += a2 * b3;
            acc[3][0] += a3 * b0; acc[3][1] += a3 * b1; acc[3][2] += a3 * b2; acc[3][3] += a3 * b3;
        }
    }

#pragma unroll
    for (int i = 0; i < 4; ++i) {
        int m = bm + ty * 4 + i;
        if (m >= M) continue;
#pragma unroll
        for (int j = 0; j < 4; ++j) {
            int n = bn + tx * 4 + j;
            float v = acc[i][j];
            if (bias) v += bias[n];
            C[(size_t)m * Nout + n] = actf(v, act);
        }
    }
}

// ---------------------------------------------------------------------------
// CSR build (dst-sorted edge list), rebuilt every launch (stateless).
// ---------------------------------------------------------------------------
__global__ void hist_k(const int* __restrict__ ei, int* __restrict__ deg, int E)
{
    int e = blockIdx.x * 256 + threadIdx.x;
    if (e >= E) return;
    atomicAdd(deg + ei[E + e], 1);
}

// single-block chunked exclusive scan over n ints -> rowptr[n+1]
__global__ __launch_bounds__(1024) void scan_k(const int* __restrict__ deg,
                                               int* __restrict__ rowptr, int n)
{
    __shared__ int buf[1024];
    __shared__ int sc;
    const int t = threadIdx.x;
    if (t == 0) sc = 0;
    __syncthreads();
    for (int base = 0; base < n; base += 1024) {
        int idx = base + t;
        int v = (idx < n) ? deg[idx] : 0;
        buf[t] = v;
        __syncthreads();
#pragma unroll
        for (int off = 1; off < 1024; off <<= 1) {
            int add = (t >= off) ? buf[t - off] : 0;
            __syncthreads();
            buf[t] += add;
            __syncthreads();
        }
        if (idx < n) rowptr[idx] = sc + buf[t] - v;   // exclusive
        __syncthreads();
        if (t == 0) sc += buf[1023];
        __syncthreads();
    }
    if (t == 0) rowptr[n] = sc;
}

__global__ void fill_csr_k(const int* __restrict__ ei, const int* __restrict__ rowptr,
                           int* __restrict__ cursor, int* __restrict__ csr_src,
                           int* __restrict__ csr_eid, int E)
{
    int e = blockIdx.x * 256 + threadIdx.x;
    if (e >= E) return;
    int s = ei[e], d = ei[E + e];
    int pos = atomicAdd(cursor + d, 1);
    int slot = rowptr[d] + pos;
    csr_src[slot] = s;
    csr_eid[slot] = e;
}

// ---------------------------------------------------------------------------
// nd_conv gather: out[d,h] = sum_e leaky(p[src_e,h] + ea[e] . W1b[h])
// one 128-thread block per dst node; no atomics.
// ---------------------------------------------------------------------------
__global__ __launch_bounds__(128) void nd_gather_k(
    const int* __restrict__ rowptr, const int* __restrict__ csr_src,
    const int* __restrict__ csr_eid, const float* __restrict__ ea,
    const float* __restrict__ ndw, const float* __restrict__ p,
    float* __restrict__ outp)
{
    const int d = blockIdx.x;
    const int t = threadIdx.x;   // feature index 0..127
    float wr[16];
#pragma unroll
    for (int k = 0; k < 16; ++k) wr[k] = ndw[t * 144 + 128 + k];
    const int b0 = rowptr[d], b1 = rowptr[d + 1];
    float acc = 0.f;
    for (int i = b0; i < b1; ++i) {
        int s = csr_src[i], e = csr_eid[i];
        const float* eav = ea + e * 16;
        float q = 0.f;
#pragma unroll
        for (int k = 0; k < 16; ++k) q += eav[k] * wr[k];
        float v = p[s * 128 + t] + q;
        acc += v >= 0.f ? v : 0.01f * v;
    }
    outp[d * 128 + t] = acc;
}

// per-node dots with attention vectors: s_src[n] = xp[n]·asrc, s_dst[n] = xp[n]·adst
__global__ void node_dots_k(const float* __restrict__ xp, const float* __restrict__ asrc,
                            const float* __restrict__ adst, float* __restrict__ ssrc,
                            float* __restrict__ sdst)
{
    int n = blockIdx.x, t = threadIdx.x;   // 128 threads
    float v = xp[n * 128 + t];
    float a = v * asrc[t];
    float b = v * adst[t];
    for (int off = 32; off; off >>= 1) { a += __shfl_down(a, off); b += __shfl_down(b, off); }
    __shared__ float sa[2], sb[2];
    if ((t & 63) == 0) { sa[t >> 6] = a; sb[t >> 6] = b; }
    __syncthreads();
    if (t == 0) { ssrc[n] = sa[0] + sa[1]; sdst[n] = sb[0] + sb[1]; }
}

// ---------------------------------------------------------------------------
// Fused GAT aggregation: per dst node, softmax over incoming edges + weighted
// gather of xp[src] + bias + elu. out = elu( (Σ w_e xp[src_e]) / Σ w_e + b ).
// ---------------------------------------------------------------------------
__global__ __launch_bounds__(128) void gat_gather_k(
    const int* __restrict__ rowptr, const int* __restrict__ csr_src,
    const float* __restrict__ ssrc, const float* __restrict__ sdst,
    const float* __restrict__ xp, const float* __restrict__ bias,
    float* __restrict__ outp)
{
    const int d = blockIdx.x;
    const int t = threadIdx.x;   // 128 threads
    __shared__ float red[128];
    __shared__ float lw[128];
    __shared__ int   ls[128];

    const int b0 = rowptr[d], b1 = rowptr[d + 1];
    const int deg = b1 - b0;
    const float sdd = sdst[d];

    // pass A: exact segment max of a = leaky(ssrc[s] + sdd)
    float lm = -INFINITY;
    for (int i = b0 + t; i < b1; i += 128) {
        float a = ssrc[csr_src[i]] + sdd;
        a = a >= 0.f ? a : 0.01f * a;
        lm = fmaxf(lm, a);
    }
    red[t] = lm;
    __syncthreads();
#pragma unroll
    for (int off = 64; off; off >>= 1) {
        if (t < off) red[t] = fmaxf(red[t], red[t + off]);
        __syncthreads();
    }
    const float amax = red[0];
    __syncthreads();

    // pass B: unnormalized weighted gather + denom
    float acc = 0.f, dpart = 0.f;
    for (int base = b0; base < b1; base += 128) {
        int len = min(128, b1 - base);
        if (t < len) {
            int s = csr_src[base + t];
            float a = ssrc[s] + sdd;
            a = a >= 0.f ? a : 0.01f * a;
            float w = expf(a - amax);
            lw[t] = w;
            ls[t] = s;
            dpart += w;
        }
        __syncthreads();
        for (int j = 0; j < len; ++j)
            acc += lw[j] * xp[ls[j] * 128 + t];
        __syncthreads();
    }
    red[t] = dpart;
    __syncthreads();
#pragma unroll
    for (int off = 64; off; off >>= 1) {
        if (t < off) red[t] += red[t + off];
        __syncthreads();
    }
    const float denom = red[0];

    float v = (deg > 0 ? acc / denom : 0.f) + bias[t];
    outp[d * 128 + t] = v > 0.f ? v : expf(v) - 1.f;   // elu
}

// out[i] = act(in[i] + bias[i % 128])   (bias may be null)
__global__ void bias_act_k(const float* __restrict__ in, const float* __restrict__ bias,
                           float* __restrict__ outp, int total, int act)
{
    int gid = blockIdx.x * 256 + threadIdx.x;
    if (gid >= total) return;
    float v = in[gid];
    if (bias) v += bias[gid & 127];
    outp[gid] = actf(v, act);
}

__global__ void gru_combine_k(const float* __restrict__ gi, const float* __restrict__ gh,
                              const float* __restrict__ xprev, float* __restrict__ xout, int M)
{
    int gid = blockIdx.x * 256 + threadIdx.x;
    if (gid >= M * 128) return;
    int n = gid >> 7, j = gid & 127;
    const float* a = gi + n * 384;
    const float* b = gh + n * 384;
    float r = sigf(a[j] + b[j]);
    float z = sigf(a[j + 128] + b[j + 128]);
    float nn = tanhf(a[j + 256] + r * b[j + 256]);
    float v = (1.f - z) * nn + z * xprev[gid];
    xout[gid] = v > 0.f ? v : 0.f;   // relu(gru(...))
}

__global__ void agg_k(const float* __restrict__ xin, const int* __restrict__ batch,
                      float* __restrict__ agg, int total)
{
    int gid = blockIdx.x * 256 + threadIdx.x;
    if (gid >= total) return;
    int n = gid >> 7, j = gid & 127;
    atomicAdd(agg + batch[n] * 128 + j, xin[gid]);
}

__global__ void add_k(const float* __restrict__ a, const float* __restrict__ b,
                      float* __restrict__ c, int total)
{
    int gid = blockIdx.x * 256 + threadIdx.x;
    if (gid >= total) return;
    c[gid] = a[gid] + b[gid];
}

__global__ void lstm_combine_k(const float* __restrict__ g1, const float* __restrict__ g2,
                               const float* __restrict__ hg, float* __restrict__ outp, int total)
{
    int gid = blockIdx.x * 256 + threadIdx.x;
    if (gid >= total) return;
    int g = gid >> 7, j = gid & 127;
    const float* a = g1 + g * 512;
    const float* b = g2 + g * 512;
    float ii = a[j]       + b[j];
    float ff = a[j + 128] + b[j + 128];
    float gg = a[j + 256] + b[j + 256];
    float oo = a[j + 384] + b[j + 384];
    float c  = hg[gid];
    float c2 = sigf(ff) * c + sigf(ii) * tanhf(gg);
    outp[gid] = sigf(oo) * tanhf(c2);
}

__global__ void final_k(const float* __restrict__ oin, const float* __restrict__ w,
                        const float* __restrict__ b, float* __restrict__ y)
{
    int g = blockIdx.x, t = threadIdx.x;  // 128 threads
    float v = oin[g * 128 + t] * w[t];
    for (int off = 32; off; off >>= 1) v += __shfl_down(v, off);
    __shared__ float s2[2];
    if ((t & 63) == 0) s2[t >> 6] = v;
    __syncthreads();
    if (t == 0) y[g] = s2[0] + s2[1] + b[0];
}

// ---------------------------------------------------------------------------

extern "C" void kernel_launch(void* const* d_in, const int* in_sizes, int n_in,
                              void* d_out, int out_size, void* d_ws, size_t ws_size,
                              hipStream_t stream)
{
    const float* x      = (const float*)d_in[0];
    const int*   ei     = (const int*)  d_in[1];
    const float* ea     = (const float*)d_in[2];
    const int*   batch  = (const int*)  d_in[3];
    const float* lin1_w = (const float*)d_in[4];
    const float* lin1_b = (const float*)d_in[5];
    const float* nd1w   = (const float*)d_in[6];
    const float* nd2w   = (const float*)d_in[7];
    const float* ndb    = (const float*)d_in[8];
    const float* g0wih  = (const float*)d_in[9];
    const float* g0whh  = (const float*)d_in[10];
    const float* g0bih  = (const float*)d_in[11];
    const float* g0bhh  = (const float*)d_in[12];
    const float* gatw   = (const float*)d_in[13];
    const float* gatas  = (const float*)d_in[14];
    const float* gatad  = (const float*)d_in[15];
    const float* gatb   = (const float*)d_in[16];
    const float* gwih   = (const float*)d_in[17];
    const float* gwhh   = (const float*)d_in[18];
    const float* gbih   = (const float*)d_in[19];
    const float* gbhh   = (const float*)d_in[20];
    const float* ginw   = (const float*)d_in[21];
    const float* ginb   = (const float*)d_in[22];
    const float* lwih   = (const float*)d_in[23];
    const float* lwhh   = (const float*)d_in[24];
    const float* lbih   = (const float*)d_in[25];
    const float* lbhh   = (const float*)d_in[26];
    const float* l2w    = (const float*)d_in[27];
    const float* l2b    = (const float*)d_in[28];
    float* outp = (float*)d_out;

    const int N = NN, E = EE, G = GG;
    const int CH = 10000;   // GRU row chunk

    float* ws = (float*)d_ws;
    size_t off = 0;
    auto alloc = [&](size_t n) {
        float* r = ws + off;
        off += (n + 63) & ~(size_t)63;
        return r;
    };
    float* x1   = alloc((size_t)N * 128);
    float* hbuf = alloc((size_t)N * 128);
    float* accb = alloc((size_t)N * 128);
    float* xpb  = alloc((size_t)N * 128);
    float* xc   = alloc((size_t)N * 128);
    float* gib  = alloc((size_t)CH * 384);
    float* ghb  = alloc((size_t)CH * 384);
    float* ssrc = alloc((size_t)N);
    float* sdst = alloc((size_t)N);
    float* agg  = alloc((size_t)G * 128);
    float* oA   = alloc((size_t)G * 128);
    float* oB   = alloc((size_t)G * 128);
    float* hgb  = alloc((size_t)G * 128);
    float* tGA  = alloc((size_t)G * 128);
    float* g1b  = alloc((size_t)G * 512);
    float* g2b  = alloc((size_t)G * 512);
    // CSR arrays (int)
    int* deg     = (int*)alloc((size_t)N);
    int* rowptr  = (int*)alloc((size_t)N + 1);
    int* cursor  = (int*)alloc((size_t)N);
    int* csr_src = (int*)alloc((size_t)E);
    int* csr_eid = (int*)alloc((size_t)E);
    (void)ws_size;

    auto gemm = [&](const float* A, const float* W, const float* bias, float* C,
                    int M, int K, int Nout, int wpitch, int act) {
        dim3 grid(Nout / 64, (M + 63) / 64);
        gemm_k<<<grid, 256, 0, stream>>>(A, W, bias, C, M, K, Nout, wpitch, act);
    };
    auto nb = [](int n) { return (n + 255) / 256; };

    auto gru = [&](const float* xin, const float* hin,
                   const float* wih, const float* whh,
                   const float* bih, const float* bhh, float* xout) {
        for (int c = 0; c < N; c += CH) {
            gemm(xin + (size_t)c * 128, wih, bih, gib, CH, 128, 384, 128, 0);
            gemm(hin + (size_t)c * 128, whh, bhh, ghb, CH, 128, 384, 128, 0);
            gru_combine_k<<<nb(CH * 128), 256, 0, stream>>>(
                gib, ghb, hin + (size_t)c * 128, xout + (size_t)c * 128, CH);
        }
    };

    // 0) CSR build (dst-major)
    hipMemsetAsync(deg, 0, (size_t)N * 4, stream);
    hipMemsetAsync(cursor, 0, (size_t)N * 4, stream);
    hist_k<<<nb(E), 256, 0, stream>>>(ei, deg, E);
    scan_k<<<1, 1024, 0, stream>>>(deg, rowptr, N);
    fill_csr_k<<<nb(E), 256, 0, stream>>>(ei, rowptr, cursor, csr_src, csr_eid, E);

    // 1) x1 = leaky(x @ lin1_w^T + lin1_b)
    gemm(x, lin1_w, lin1_b, x1, N, 64, 128, 64, 1);

    // 2) nd_conv (W2 hoisted out of segment_sum):
    gemm(x1, nd1w, nullptr, xpb, N, 128, 128, 144, 0);
    nd_gather_k<<<N, 128, 0, stream>>>(rowptr, csr_src, csr_eid, ea, nd1w, xpb, accb);
    gemm(accb, nd2w, ndb, hbuf, N, 128, 128, 128, 2);

    // 3) xcur = relu(gru_cell(h, x1))  -> xc
    gru(hbuf, x1, g0wih, g0whh, g0bih, g0bhh, xc);

    // 4) GAT layers
    const float* xcur = xc;
    float* xnext = x1;
    for (int l = 0; l < 2; ++l) {
        gemm(xcur, gatw + (size_t)l * 128 * 128, nullptr, xpb, N, 128, 128, 128, 0);
        node_dots_k<<<N, 128, 0, stream>>>(xpb, gatas + l * 128, gatad + l * 128, ssrc, sdst);
        gat_gather_k<<<N, 128, 0, stream>>>(rowptr, csr_src, ssrc, sdst, xpb,
                                            gatb + l * 128, hbuf);
        gru(hbuf, xcur, gwih + (size_t)l * 384 * 128, gwhh + (size_t)l * 384 * 128,
            gbih + l * 384, gbhh + l * 384, xnext);
        const float* t = xcur; xcur = xnext; xnext = (float*)t;
    }

    // 5) readout
    hipMemsetAsync(agg, 0, (size_t)G * 128 * 4, stream);
    agg_k<<<nb(N * 128), 256, 0, stream>>>(xcur, batch, agg, N * 128);
    bias_act_k<<<nb(G * 128), 256, 0, stream>>>(agg, nullptr, oA, G * 128, 3);

    // 6) T=2 GIN+LSTM refinement
    float* cur = oA; float* nxt = oB;
    for (int t = 0; t < 2; ++t) {
        add_k<<<nb(G * 128), 256, 0, stream>>>(cur, agg, tGA, G * 128);
        gemm(tGA, ginw, ginb, hgb, G, 128, 128, 128, 2);
        gemm(cur, lwih, lbih, g1b, G, 128, 512, 128, 0);
        gemm(hgb, lwhh, lbhh, g2b, G, 128, 512, 128, 0);
        lstm_combine_k<<<nb(G * 128), 256, 0, stream>>>(g1b, g2b, hgb, nxt, G * 128);
        float* tmp = cur; cur = nxt; nxt = tmp;
    }

    // 7) y = out @ lin2_w^T + lin2_b
    final_k<<<G, 128, 0, stream>>>(cur, l2w, l2b, outp);
}

// Round 3
// 1223.441 us; speedup vs baseline: 1.9902x; 1.5187x over previous
//
#include <hip/hip_runtime.h>
#include <cstdint>
#include <cmath>

// Problem constants (from reference):
#define NN 50000
#define EE 500000
#define GG 2000
// IN=64, H=128, ED=16, OUT=1, NUM_GAT=2, T=2

#define DEV __device__ __forceinline__

typedef __attribute__((ext_vector_type(8))) short short8;     // 8 bf16 (4 VGPRs)
typedef __attribute__((ext_vector_type(4))) float floatx4;
typedef __attribute__((ext_vector_type(4))) unsigned short ushort4v;

DEV float sigf(float x) { return 1.f / (1.f + expf(-x)); }

DEV float actf(float x, int act) {
    if (act == 1) return x >= 0.f ? x : 0.01f * x;        // leaky 0.01
    if (act == 2) return x > 0.f ? x : expf(x) - 1.f;     // elu
    if (act == 3) return x > 0.f ? x : 0.f;               // relu
    return x;
}

// fp32 -> bf16 with round-to-nearest-even (values are finite here)
DEV unsigned short f2bf(float f) {
    unsigned u = __float_as_uint(f);
    u += 0x7FFFu + ((u >> 16) & 1u);
    return (unsigned short)(u >> 16);
}

// ---------------------------------------------------------------------------
// MFMA GEMM: C[M,Nout] = act(A[M,K] @ W[Nout,K]^T + bias), fp32 in/out,
// bf16 MFMA compute. K in {64,128} (pow2), Nout % 64 == 0, A pitch == K,
// W pitch == wpitch. Block 256 thr / 4 waves; 64x64 tile; full-K staging.
// ---------------------------------------------------------------------------
__global__ __launch_bounds__(256) void gemm_mfma_k(
    const float* __restrict__ A, const float* __restrict__ W,
    const float* __restrict__ bias, float* __restrict__ C,
    int M, int K, int Nout, int wpitch, int act)
{
    __shared__ unsigned short Als[64 * 136];
    __shared__ unsigned short Bls[64 * 136];
    const int tid = threadIdx.x;
    const int bm = blockIdx.y * 64;
    const int bn = blockIdx.x * 64;

    // ---- stage A (with M bounds -> zeros) and B tiles, fp32 -> bf16 ----
    const int ks = (K == 128) ? 7 : 6;
    const int km = K - 1;
    const int nvec = (64 * K) >> 2;     // float4 count per tile
    for (int i = tid; i < nvec; i += 256) {
        const int e4 = i << 2;
        const int r = e4 >> ks;
        const int c = e4 & km;
        float4 av = make_float4(0.f, 0.f, 0.f, 0.f);
        if (bm + r < M) av = *(const float4*)(A + (size_t)(bm + r) * K + c);
        ushort4v ua;
        ua[0] = f2bf(av.x); ua[1] = f2bf(av.y); ua[2] = f2bf(av.z); ua[3] = f2bf(av.w);
        *(ushort4v*)(Als + r * 136 + c) = ua;
        const float4 wv = *(const float4*)(W + (size_t)(bn + r) * wpitch + c);
        ushort4v uw;
        uw[0] = f2bf(wv.x); uw[1] = f2bf(wv.y); uw[2] = f2bf(wv.z); uw[3] = f2bf(wv.w);
        *(ushort4v*)(Bls + r * 136 + c) = uw;
    }
    __syncthreads();

    // ---- MFMA compute: wave -> 32x32 tile (2x2 of 16x16x32) ----
    const int wave = tid >> 6;
    const int lane = tid & 63;
    const int wr = (wave >> 1) * 32;    // wave row offset in tile
    const int wc = (wave & 1) * 32;     // wave col offset in tile
    const int l15 = lane & 15;
    const int quad = lane >> 4;

    floatx4 acc00 = {}, acc01 = {}, acc10 = {}, acc11 = {};
    for (int k0 = 0; k0 < K; k0 += 32) {
        const short8 a0 = *(const short8*)(Als + (wr + l15) * 136 + k0 + quad * 8);
        const short8 a1 = *(const short8*)(Als + (wr + 16 + l15) * 136 + k0 + quad * 8);
        const short8 b0 = *(const short8*)(Bls + (wc + l15) * 136 + k0 + quad * 8);
        const short8 b1 = *(const short8*)(Bls + (wc + 16 + l15) * 136 + k0 + quad * 8);
        acc00 = __builtin_amdgcn_mfma_f32_16x16x32_bf16(a0, b0, acc00, 0, 0, 0);
        acc01 = __builtin_amdgcn_mfma_f32_16x16x32_bf16(a0, b1, acc01, 0, 0, 0);
        acc10 = __builtin_amdgcn_mfma_f32_16x16x32_bf16(a1, b0, acc10, 0, 0, 0);
        acc11 = __builtin_amdgcn_mfma_f32_16x16x32_bf16(a1, b1, acc11, 0, 0, 0);
    }

    // ---- epilogue: bias + act, fp32 store (mask M edge) ----
    const floatx4* accs[4] = { &acc00, &acc01, &acc10, &acc11 };
#pragma unroll
    for (int r = 0; r < 2; ++r) {
#pragma unroll
        for (int c = 0; c < 2; ++c) {
            const floatx4 a = *accs[r * 2 + c];
            const int n = bn + wc + c * 16 + l15;
            const float bv = bias ? bias[n] : 0.f;
#pragma unroll
            for (int i = 0; i < 4; ++i) {
                const int m = bm + wr + r * 16 + quad * 4 + i;
                if (m < M) C[(size_t)m * Nout + n] = actf(a[i] + bv, act);
            }
        }
    }
}

// ---------------------------------------------------------------------------
// CSR build (dst-sorted edge list), rebuilt every launch (stateless).
// ---------------------------------------------------------------------------
__global__ void hist_k(const int* __restrict__ ei, int* __restrict__ deg, int E)
{
    int e = blockIdx.x * 256 + threadIdx.x;
    if (e >= E) return;
    atomicAdd(deg + ei[E + e], 1);
}

// single-block chunked exclusive scan over n ints -> rowptr[n+1]
__global__ __launch_bounds__(1024) void scan_k(const int* __restrict__ deg,
                                               int* __restrict__ rowptr, int n)
{
    __shared__ int buf[1024];
    __shared__ int sc;
    const int t = threadIdx.x;
    if (t == 0) sc = 0;
    __syncthreads();
    for (int base = 0; base < n; base += 1024) {
        int idx = base + t;
        int v = (idx < n) ? deg[idx] : 0;
        buf[t] = v;
        __syncthreads();
#pragma unroll
        for (int off = 1; off < 1024; off <<= 1) {
            int add = (t >= off) ? buf[t - off] : 0;
            __syncthreads();
            buf[t] += add;
            __syncthreads();
        }
        if (idx < n) rowptr[idx] = sc + buf[t] - v;   // exclusive
        __syncthreads();
        if (t == 0) sc += buf[1023];
        __syncthreads();
    }
    if (t == 0) rowptr[n] = sc;
}

__global__ void fill_csr_k(const int* __restrict__ ei, const int* __restrict__ rowptr,
                           int* __restrict__ cursor, int* __restrict__ csr_src,
                           int* __restrict__ csr_eid, int E)
{
    int e = blockIdx.x * 256 + threadIdx.x;
    if (e >= E) return;
    int s = ei[e], d = ei[E + e];
    int pos = atomicAdd(cursor + d, 1);
    int slot = rowptr[d] + pos;
    csr_src[slot] = s;
    csr_eid[slot] = e;
}

// ---------------------------------------------------------------------------
// nd_conv gather: out[d,h] = sum_e leaky(p[src_e,h] + ea[e] . W1b[h])
// ---------------------------------------------------------------------------
__global__ __launch_bounds__(128) void nd_gather_k(
    const int* __restrict__ rowptr, const int* __restrict__ csr_src,
    const int* __restrict__ csr_eid, const float* __restrict__ ea,
    const float* __restrict__ ndw, const float* __restrict__ p,
    float* __restrict__ outp)
{
    const int d = blockIdx.x;
    const int t = threadIdx.x;   // feature index 0..127
    float wr[16];
#pragma unroll
    for (int k = 0; k < 16; ++k) wr[k] = ndw[t * 144 + 128 + k];
    const int b0 = rowptr[d], b1 = rowptr[d + 1];
    float acc = 0.f;
    for (int i = b0; i < b1; ++i) {
        int s = csr_src[i], e = csr_eid[i];
        const float* eav = ea + e * 16;
        float q = 0.f;
#pragma unroll
        for (int k = 0; k < 16; ++k) q += eav[k] * wr[k];
        float v = p[s * 128 + t] + q;
        acc += v >= 0.f ? v : 0.01f * v;
    }
    outp[d * 128 + t] = acc;
}

// per-node dots: s_src[n] = xp[n]·asrc, s_dst[n] = xp[n]·adst
__global__ void node_dots_k(const float* __restrict__ xp, const float* __restrict__ asrc,
                            const float* __restrict__ adst, float* __restrict__ ssrc,
                            float* __restrict__ sdst)
{
    int n = blockIdx.x, t = threadIdx.x;   // 128 threads
    float v = xp[n * 128 + t];
    float a = v * asrc[t];
    float b = v * adst[t];
    for (int off = 32; off; off >>= 1) { a += __shfl_down(a, off); b += __shfl_down(b, off); }
    __shared__ float sa[2], sb[2];
    if ((t & 63) == 0) { sa[t >> 6] = a; sb[t >> 6] = b; }
    __syncthreads();
    if (t == 0) { ssrc[n] = sa[0] + sa[1]; sdst[n] = sb[0] + sb[1]; }
}

// ---------------------------------------------------------------------------
// Fused GAT aggregation per dst node (exact softmax, normalized at the end)
// ---------------------------------------------------------------------------
__global__ __launch_bounds__(128) void gat_gather_k(
    const int* __restrict__ rowptr, const int* __restrict__ csr_src,
    const float* __restrict__ ssrc, const float* __restrict__ sdst,
    const float* __restrict__ xp, const float* __restrict__ bias,
    float* __restrict__ outp)
{
    const int d = blockIdx.x;
    const int t = threadIdx.x;   // 128 threads
    __shared__ float red[128];
    __shared__ float lw[128];
    __shared__ int   ls[128];

    const int b0 = rowptr[d], b1 = rowptr[d + 1];
    const int deg = b1 - b0;
    const float sdd = sdst[d];

    float lm = -INFINITY;
    for (int i = b0 + t; i < b1; i += 128) {
        float a = ssrc[csr_src[i]] + sdd;
        a = a >= 0.f ? a : 0.01f * a;
        lm = fmaxf(lm, a);
    }
    red[t] = lm;
    __syncthreads();
#pragma unroll
    for (int off = 64; off; off >>= 1) {
        if (t < off) red[t] = fmaxf(red[t], red[t + off]);
        __syncthreads();
    }
    const float amax = red[0];
    __syncthreads();

    float acc = 0.f, dpart = 0.f;
    for (int base = b0; base < b1; base += 128) {
        int len = min(128, b1 - base);
        if (t < len) {
            int s = csr_src[base + t];
            float a = ssrc[s] + sdd;
            a = a >= 0.f ? a : 0.01f * a;
            float w = expf(a - amax);
            lw[t] = w;
            ls[t] = s;
            dpart += w;
        }
        __syncthreads();
        for (int j = 0; j < len; ++j)
            acc += lw[j] * xp[ls[j] * 128 + t];
        __syncthreads();
    }
    red[t] = dpart;
    __syncthreads();
#pragma unroll
    for (int off = 64; off; off >>= 1) {
        if (t < off) red[t] += red[t + off];
        __syncthreads();
    }
    const float denom = red[0];

    float v = (deg > 0 ? acc / denom : 0.f) + bias[t];
    outp[d * 128 + t] = v > 0.f ? v : expf(v) - 1.f;   // elu
}

// out[i] = act(in[i] + bias[i % 128])   (bias may be null)
__global__ void bias_act_k(const float* __restrict__ in, const float* __restrict__ bias,
                           float* __restrict__ outp, int total, int act)
{
    int gid = blockIdx.x * 256 + threadIdx.x;
    if (gid >= total) return;
    float v = in[gid];
    if (bias) v += bias[gid & 127];
    outp[gid] = actf(v, act);
}

__global__ void gru_combine_k(const float* __restrict__ gi, const float* __restrict__ gh,
                              const float* __restrict__ xprev, float* __restrict__ xout, int M)
{
    int gid = blockIdx.x * 256 + threadIdx.x;
    if (gid >= M * 128) return;
    int n = gid >> 7, j = gid & 127;
    const float* a = gi + n * 384;
    const float* b = gh + n * 384;
    float r = sigf(a[j] + b[j]);
    float z = sigf(a[j + 128] + b[j + 128]);
    float nn = tanhf(a[j + 256] + r * b[j + 256]);
    float v = (1.f - z) * nn + z * xprev[gid];
    xout[gid] = v > 0.f ? v : 0.f;   // relu(gru(...))
}

__global__ void agg_k(const float* __restrict__ xin, const int* __restrict__ batch,
                      float* __restrict__ agg, int total)
{
    int gid = blockIdx.x * 256 + threadIdx.x;
    if (gid >= total) return;
    int n = gid >> 7, j = gid & 127;
    atomicAdd(agg + batch[n] * 128 + j, xin[gid]);
}

__global__ void add_k(const float* __restrict__ a, const float* __restrict__ b,
                      float* __restrict__ c, int total)
{
    int gid = blockIdx.x * 256 + threadIdx.x;
    if (gid >= total) return;
    c[gid] = a[gid] + b[gid];
}

__global__ void lstm_combine_k(const float* __restrict__ g1, const float* __restrict__ g2,
                               const float* __restrict__ hg, float* __restrict__ outp, int total)
{
    int gid = blockIdx.x * 256 + threadIdx.x;
    if (gid >= total) return;
    int g = gid >> 7, j = gid & 127;
    const float* a = g1 + g * 512;
    const float* b = g2 + g * 512;
    float ii = a[j]       + b[j];
    float ff = a[j + 128] + b[j + 128];
    float gg = a[j + 256] + b[j + 256];
    float oo = a[j + 384] + b[j + 384];
    float c  = hg[gid];
    float c2 = sigf(ff) * c + sigf(ii) * tanhf(gg);
    outp[gid] = sigf(oo) * tanhf(c2);
}

__global__ void final_k(const float* __restrict__ oin, const float* __restrict__ w,
                        const float* __restrict__ b, float* __restrict__ y)
{
    int g = blockIdx.x, t = threadIdx.x;  // 128 threads
    float v = oin[g * 128 + t] * w[t];
    for (int off = 32; off; off >>= 1) v += __shfl_down(v, off);
    __shared__ float s2[2];
    if ((t & 63) == 0) s2[t >> 6] = v;
    __syncthreads();
    if (t == 0) y[g] = s2[0] + s2[1] + b[0];
}

// ---------------------------------------------------------------------------

extern "C" void kernel_launch(void* const* d_in, const int* in_sizes, int n_in,
                              void* d_out, int out_size, void* d_ws, size_t ws_size,
                              hipStream_t stream)
{
    const float* x      = (const float*)d_in[0];
    const int*   ei     = (const int*)  d_in[1];
    const float* ea     = (const float*)d_in[2];
    const int*   batch  = (const int*)  d_in[3];
    const float* lin1_w = (const float*)d_in[4];
    const float* lin1_b = (const float*)d_in[5];
    const float* nd1w   = (const float*)d_in[6];
    const float* nd2w   = (const float*)d_in[7];
    const float* ndb    = (const float*)d_in[8];
    const float* g0wih  = (const float*)d_in[9];
    const float* g0whh  = (const float*)d_in[10];
    const float* g0bih  = (const float*)d_in[11];
    const float* g0bhh  = (const float*)d_in[12];
    const float* gatw   = (const float*)d_in[13];
    const float* gatas  = (const float*)d_in[14];
    const float* gatad  = (const float*)d_in[15];
    const float* gatb   = (const float*)d_in[16];
    const float* gwih   = (const float*)d_in[17];
    const float* gwhh   = (const float*)d_in[18];
    const float* gbih   = (const float*)d_in[19];
    const float* gbhh   = (const float*)d_in[20];
    const float* ginw   = (const float*)d_in[21];
    const float* ginb   = (const float*)d_in[22];
    const float* lwih   = (const float*)d_in[23];
    const float* lwhh   = (const float*)d_in[24];
    const float* lbih   = (const float*)d_in[25];
    const float* lbhh   = (const float*)d_in[26];
    const float* l2w    = (const float*)d_in[27];
    const float* l2b    = (const float*)d_in[28];
    float* outp = (float*)d_out;

    const int N = NN, E = EE, G = GG;
    const int CH = 10000;   // GRU row chunk

    float* ws = (float*)d_ws;
    size_t off = 0;
    auto alloc = [&](size_t n) {
        float* r = ws + off;
        off += (n + 63) & ~(size_t)63;
        return r;
    };
    float* x1   = alloc((size_t)N * 128);
    float* hbuf = alloc((size_t)N * 128);
    float* accb = alloc((size_t)N * 128);
    float* xpb  = alloc((size_t)N * 128);
    float* xc   = alloc((size_t)N * 128);
    float* gib  = alloc((size_t)CH * 384);
    float* ghb  = alloc((size_t)CH * 384);
    float* ssrc = alloc((size_t)N);
    float* sdst = alloc((size_t)N);
    float* agg  = alloc((size_t)G * 128);
    float* oA   = alloc((size_t)G * 128);
    float* oB   = alloc((size_t)G * 128);
    float* hgb  = alloc((size_t)G * 128);
    float* tGA  = alloc((size_t)G * 128);
    float* g1b  = alloc((size_t)G * 512);
    float* g2b  = alloc((size_t)G * 512);
    // CSR arrays (int)
    int* deg     = (int*)alloc((size_t)N);
    int* rowptr  = (int*)alloc((size_t)N + 1);
    int* cursor  = (int*)alloc((size_t)N);
    int* csr_src = (int*)alloc((size_t)E);
    int* csr_eid = (int*)alloc((size_t)E);
    (void)ws_size;

    auto gemm = [&](const float* A, const float* W, const float* bias, float* C,
                    int M, int K, int Nout, int wpitch, int act) {
        dim3 grid(Nout / 64, (M + 63) / 64);
        gemm_mfma_k<<<grid, 256, 0, stream>>>(A, W, bias, C, M, K, Nout, wpitch, act);
    };
    auto nb = [](int n) { return (n + 255) / 256; };

    auto gru = [&](const float* xin, const float* hin,
                   const float* wih, const float* whh,
                   const float* bih, const float* bhh, float* xout) {
        for (int c = 0; c < N; c += CH) {
            gemm(xin + (size_t)c * 128, wih, bih, gib, CH, 128, 384, 128, 0);
            gemm(hin + (size_t)c * 128, whh, bhh, ghb, CH, 128, 384, 128, 0);
            gru_combine_k<<<nb(CH * 128), 256, 0, stream>>>(
                gib, ghb, hin + (size_t)c * 128, xout + (size_t)c * 128, CH);
        }
    };

    // 0) CSR build (dst-major)
    hipMemsetAsync(deg, 0, (size_t)N * 4, stream);
    hipMemsetAsync(cursor, 0, (size_t)N * 4, stream);
    hist_k<<<nb(E), 256, 0, stream>>>(ei, deg, E);
    scan_k<<<1, 1024, 0, stream>>>(deg, rowptr, N);
    fill_csr_k<<<nb(E), 256, 0, stream>>>(ei, rowptr, cursor, csr_src, csr_eid, E);

    // 1) x1 = leaky(x @ lin1_w^T + lin1_b)
    gemm(x, lin1_w, lin1_b, x1, N, 64, 128, 64, 1);

    // 2) nd_conv (W2 hoisted out of segment_sum):
    gemm(x1, nd1w, nullptr, xpb, N, 128, 128, 144, 0);
    nd_gather_k<<<N, 128, 0, stream>>>(rowptr, csr_src, csr_eid, ea, nd1w, xpb, accb);
    gemm(accb, nd2w, ndb, hbuf, N, 128, 128, 128, 2);

    // 3) xcur = relu(gru_cell(h, x1))  -> xc
    gru(hbuf, x1, g0wih, g0whh, g0bih, g0bhh, xc);

    // 4) GAT layers
    const float* xcur = xc;
    float* xnext = x1;
    for (int l = 0; l < 2; ++l) {
        gemm(xcur, gatw + (size_t)l * 128 * 128, nullptr, xpb, N, 128, 128, 128, 0);
        node_dots_k<<<N, 128, 0, stream>>>(xpb, gatas + l * 128, gatad + l * 128, ssrc, sdst);
        gat_gather_k<<<N, 128, 0, stream>>>(rowptr, csr_src, ssrc, sdst, xpb,
                                            gatb + l * 128, hbuf);
        gru(hbuf, xcur, gwih + (size_t)l * 384 * 128, gwhh + (size_t)l * 384 * 128,
            gbih + l * 384, gbhh + l * 384, xnext);
        const float* t = xcur; xcur = xnext; xnext = (float*)t;
    }

    // 5) readout
    hipMemsetAsync(agg, 0, (size_t)G * 128 * 4, stream);
    agg_k<<<nb(N * 128), 256, 0, stream>>>(xcur, batch, agg, N * 128);
    bias_act_k<<<nb(G * 128), 256, 0, stream>>>(agg, nullptr, oA, G * 128, 3);

    // 6) T=2 GIN+LSTM refinement
    float* cur = oA; float* nxt = oB;
    for (int t = 0; t < 2; ++t) {
        add_k<<<nb(G * 128), 256, 0, stream>>>(cur, agg, tGA, G * 128);
        gemm(tGA, ginw, ginb, hgb, G, 128, 128, 128, 2);
        gemm(cur, lwih, lbih, g1b, G, 128, 512, 128, 0);
        gemm(hgb, lwhh, lbhh, g2b, G, 128, 512, 128, 0);
        lstm_combine_k<<<nb(G * 128), 256, 0, stream>>>(g1b, g2b, hgb, nxt, G * 128);
        float* tmp = cur; cur = nxt; nxt = tmp;
    }

    // 7) y = out @ lin2_w^T + lin2_b
    final_k<<<G, 128, 0, stream>>>(cur, l2w, l2b, outp);
}

// Round 4
// 1042.924 us; speedup vs baseline: 2.3347x; 1.1731x over previous
//
#include <hip/hip_runtime.h>
#include <cstdint>
#include <cmath>

// Problem constants (from reference):
#define NN 50000
#define EE 500000
#define GG 2000
// IN=64, H=128, ED=16, OUT=1, NUM_GAT=2, T=2

#define DEV __device__ __forceinline__

typedef __attribute__((ext_vector_type(8))) short short8;     // 8 bf16 (4 VGPRs)
typedef __attribute__((ext_vector_type(4))) float floatx4;
typedef __attribute__((ext_vector_type(4))) unsigned short ushort4v;

DEV float sigf(float x) { return 1.f / (1.f + expf(-x)); }

DEV float actf(float x, int act) {
    if (act == 1) return x >= 0.f ? x : 0.01f * x;        // leaky 0.01
    if (act == 2) return x > 0.f ? x : expf(x) - 1.f;     // elu
    if (act == 3) return x > 0.f ? x : 0.f;               // relu
    return x;
}

// fp32 -> bf16 round-to-nearest-even
DEV unsigned short f2bf(float f) {
    unsigned u = __float_as_uint(f);
    u += 0x7FFFu + ((u >> 16) & 1u);
    return (unsigned short)(u >> 16);
}
DEV float bf2f(unsigned short u) {
    return __uint_as_float(((unsigned)u) << 16);
}

// ---------------------------------------------------------------------------
// MFMA GEMM: C[M,Nout] = act(A[M,K] @ W[Nout,K]^T + bias), fp32 in/out,
// bf16 MFMA compute. K in {64,128}, Nout % 64 == 0. Block 256/4 waves, 64x64.
// ---------------------------------------------------------------------------
__global__ __launch_bounds__(256) void gemm_mfma_k(
    const float* __restrict__ A, const float* __restrict__ W,
    const float* __restrict__ bias, float* __restrict__ C,
    int M, int K, int Nout, int wpitch, int act)
{
    __shared__ unsigned short Als[64 * 136];
    __shared__ unsigned short Bls[64 * 136];
    const int tid = threadIdx.x;
    const int bm = blockIdx.y * 64;
    const int bn = blockIdx.x * 64;

    const int ks = (K == 128) ? 7 : 6;
    const int km = K - 1;
    const int nvec = (64 * K) >> 2;
    for (int i = tid; i < nvec; i += 256) {
        const int e4 = i << 2;
        const int r = e4 >> ks;
        const int c = e4 & km;
        float4 av = make_float4(0.f, 0.f, 0.f, 0.f);
        if (bm + r < M) av = *(const float4*)(A + (size_t)(bm + r) * K + c);
        ushort4v ua;
        ua[0] = f2bf(av.x); ua[1] = f2bf(av.y); ua[2] = f2bf(av.z); ua[3] = f2bf(av.w);
        *(ushort4v*)(Als + r * 136 + c) = ua;
        const float4 wv = *(const float4*)(W + (size_t)(bn + r) * wpitch + c);
        ushort4v uw;
        uw[0] = f2bf(wv.x); uw[1] = f2bf(wv.y); uw[2] = f2bf(wv.z); uw[3] = f2bf(wv.w);
        *(ushort4v*)(Bls + r * 136 + c) = uw;
    }
    __syncthreads();

    const int wave = tid >> 6;
    const int lane = tid & 63;
    const int wr = (wave >> 1) * 32;
    const int wc = (wave & 1) * 32;
    const int l15 = lane & 15;
    const int quad = lane >> 4;

    floatx4 acc00 = {}, acc01 = {}, acc10 = {}, acc11 = {};
    for (int k0 = 0; k0 < K; k0 += 32) {
        const short8 a0 = *(const short8*)(Als + (wr + l15) * 136 + k0 + quad * 8);
        const short8 a1 = *(const short8*)(Als + (wr + 16 + l15) * 136 + k0 + quad * 8);
        const short8 b0 = *(const short8*)(Bls + (wc + l15) * 136 + k0 + quad * 8);
        const short8 b1 = *(const short8*)(Bls + (wc + 16 + l15) * 136 + k0 + quad * 8);
        acc00 = __builtin_amdgcn_mfma_f32_16x16x32_bf16(a0, b0, acc00, 0, 0, 0);
        acc01 = __builtin_amdgcn_mfma_f32_16x16x32_bf16(a0, b1, acc01, 0, 0, 0);
        acc10 = __builtin_amdgcn_mfma_f32_16x16x32_bf16(a1, b0, acc10, 0, 0, 0);
        acc11 = __builtin_amdgcn_mfma_f32_16x16x32_bf16(a1, b1, acc11, 0, 0, 0);
    }

    const floatx4* accs[4] = { &acc00, &acc01, &acc10, &acc11 };
#pragma unroll
    for (int r = 0; r < 2; ++r) {
#pragma unroll
        for (int c = 0; c < 2; ++c) {
            const floatx4 a = *accs[r * 2 + c];
            const int n = bn + wc + c * 16 + l15;
            const float bv = bias ? bias[n] : 0.f;
#pragma unroll
            for (int i = 0; i < 4; ++i) {
                const int m = bm + wr + r * 16 + quad * 4 + i;
                if (m < M) C[(size_t)m * Nout + n] = actf(a[i] + bv, act);
            }
        }
    }
}

// Same GEMM but bf16 output (for gather tables p / xp), no bias.
__global__ __launch_bounds__(256) void gemm_mfma_o16_k(
    const float* __restrict__ A, const float* __restrict__ W,
    unsigned short* __restrict__ C, int M, int K, int Nout, int wpitch)
{
    __shared__ unsigned short Als[64 * 136];
    __shared__ unsigned short Bls[64 * 136];
    const int tid = threadIdx.x;
    const int bm = blockIdx.y * 64;
    const int bn = blockIdx.x * 64;

    const int ks = (K == 128) ? 7 : 6;
    const int km = K - 1;
    const int nvec = (64 * K) >> 2;
    for (int i = tid; i < nvec; i += 256) {
        const int e4 = i << 2;
        const int r = e4 >> ks;
        const int c = e4 & km;
        float4 av = make_float4(0.f, 0.f, 0.f, 0.f);
        if (bm + r < M) av = *(const float4*)(A + (size_t)(bm + r) * K + c);
        ushort4v ua;
        ua[0] = f2bf(av.x); ua[1] = f2bf(av.y); ua[2] = f2bf(av.z); ua[3] = f2bf(av.w);
        *(ushort4v*)(Als + r * 136 + c) = ua;
        const float4 wv = *(const float4*)(W + (size_t)(bn + r) * wpitch + c);
        ushort4v uw;
        uw[0] = f2bf(wv.x); uw[1] = f2bf(wv.y); uw[2] = f2bf(wv.z); uw[3] = f2bf(wv.w);
        *(ushort4v*)(Bls + r * 136 + c) = uw;
    }
    __syncthreads();

    const int wave = tid >> 6;
    const int lane = tid & 63;
    const int wr = (wave >> 1) * 32;
    const int wc = (wave & 1) * 32;
    const int l15 = lane & 15;
    const int quad = lane >> 4;

    floatx4 acc00 = {}, acc01 = {}, acc10 = {}, acc11 = {};
    for (int k0 = 0; k0 < K; k0 += 32) {
        const short8 a0 = *(const short8*)(Als + (wr + l15) * 136 + k0 + quad * 8);
        const short8 a1 = *(const short8*)(Als + (wr + 16 + l15) * 136 + k0 + quad * 8);
        const short8 b0 = *(const short8*)(Bls + (wc + l15) * 136 + k0 + quad * 8);
        const short8 b1 = *(const short8*)(Bls + (wc + 16 + l15) * 136 + k0 + quad * 8);
        acc00 = __builtin_amdgcn_mfma_f32_16x16x32_bf16(a0, b0, acc00, 0, 0, 0);
        acc01 = __builtin_amdgcn_mfma_f32_16x16x32_bf16(a0, b1, acc01, 0, 0, 0);
        acc10 = __builtin_amdgcn_mfma_f32_16x16x32_bf16(a1, b0, acc10, 0, 0, 0);
        acc11 = __builtin_amdgcn_mfma_f32_16x16x32_bf16(a1, b1, acc11, 0, 0, 0);
    }

    const floatx4* accs[4] = { &acc00, &acc01, &acc10, &acc11 };
#pragma unroll
    for (int r = 0; r < 2; ++r) {
#pragma unroll
        for (int c = 0; c < 2; ++c) {
            const floatx4 a = *accs[r * 2 + c];
            const int n = bn + wc + c * 16 + l15;
#pragma unroll
            for (int i = 0; i < 4; ++i) {
                const int m = bm + wr + r * 16 + quad * 4 + i;
                if (m < M) C[(size_t)m * Nout + n] = f2bf(a[i]);
            }
        }
    }
}

// ---------------------------------------------------------------------------
// Fully fused GRU cell: xout = relu(gru_cell(xin, hin, wih, whh, bih, bhh)).
// Block: 64 rows x 16 output cols. 256 thr / 4 waves: wave = (sel<<1)|rowgrp,
// sel 0 -> gi (A=xin, W=wih), sel 1 -> gh (A=hin, W=whh). Each wave: 2 row
// frags x 3 gates of 16x16x32 MFMA. Gate tiles exchanged via LDS; combine +
// relu in epilogue. LDS 61 KB (stride 136 = conflict-free per R3 evidence).
// ---------------------------------------------------------------------------
__global__ __launch_bounds__(256) void gru_fused_k(
    const float* __restrict__ xin, const float* __restrict__ hin,
    const float* __restrict__ wih, const float* __restrict__ whh,
    const float* __restrict__ bih, const float* __restrict__ bhh,
    float* __restrict__ xout, int M)
{
    __shared__ unsigned short sm[30464];   // 60928 B
    // staging layout (ushort): sX[64*136] | sH[64*136] | sW[2][3*16*136]
    unsigned short* sX = sm;
    unsigned short* sH = sm + 8704;
    unsigned short* sW = sm + 17408;       // sel-major: 2 x 6528
    float* eg = (float*)sm;                // epilogue alias: [6][64][17]

    const int tid = threadIdx.x;
    const int bm = blockIdx.x * 64;
    const int j0 = blockIdx.y * 16;        // output col block within H=128

    // ---- stage xin/hin (64x128, fp32 -> bf16) ----
    for (int i = tid; i < 2048; i += 256) {
        const int e4 = i << 2;
        const int r = e4 >> 7;
        const int c = e4 & 127;
        const int m = bm + r;
        float4 xv = make_float4(0.f, 0.f, 0.f, 0.f);
        float4 hv = make_float4(0.f, 0.f, 0.f, 0.f);
        if (m < M) {
            xv = *(const float4*)(xin + (size_t)m * 128 + c);
            hv = *(const float4*)(hin + (size_t)m * 128 + c);
        }
        ushort4v ux, uh;
        ux[0] = f2bf(xv.x); ux[1] = f2bf(xv.y); ux[2] = f2bf(xv.z); ux[3] = f2bf(xv.w);
        uh[0] = f2bf(hv.x); uh[1] = f2bf(hv.y); uh[2] = f2bf(hv.z); uh[3] = f2bf(hv.w);
        *(ushort4v*)(sX + r * 136 + c) = ux;
        *(ushort4v*)(sH + r * 136 + c) = uh;
    }
    // ---- stage weight slices: 3 gates x 16 rows x 128, both tensors ----
    for (int i = tid; i < 1536; i += 256) {
        const int e4 = i << 2;
        const int gr = e4 >> 7;            // g*16 + r, 0..47
        const int c = e4 & 127;
        const int g = gr >> 4;
        const int r = gr & 15;
        const size_t grow = (size_t)(g * 128 + j0 + r) * 128 + c;
        const float4 wv = *(const float4*)(wih + grow);
        const float4 hv = *(const float4*)(whh + grow);
        ushort4v uw, uh;
        uw[0] = f2bf(wv.x); uw[1] = f2bf(wv.y); uw[2] = f2bf(wv.z); uw[3] = f2bf(wv.w);
        uh[0] = f2bf(hv.x); uh[1] = f2bf(hv.y); uh[2] = f2bf(hv.z); uh[3] = f2bf(hv.w);
        *(ushort4v*)(sW + gr * 136 + c) = uw;                // wih at sel 0
        *(ushort4v*)(sW + 6528 + gr * 136 + c) = uh;         // whh at sel 1
    }
    __syncthreads();

    // ---- MFMA: 6 accumulators = 2 row frags x 3 gates ----
    const int wave = tid >> 6;
    const int lane = tid & 63;
    const int sel = wave >> 1;             // 0: gi, 1: gh
    const int rowgrp = wave & 1;           // rows [rowgrp*32, +32)
    const int l15 = lane & 15;
    const int quad = lane >> 4;

    const unsigned short* sa = sel ? sH : sX;
    const unsigned short* sw = sW + sel * 6528;

    floatx4 acc[6] = {};                   // [g*2 + rf]
    for (int k0 = 0; k0 < 128; k0 += 32) {
        const short8 a0 = *(const short8*)(sa + (rowgrp * 32 + l15) * 136 + k0 + quad * 8);
        const short8 a1 = *(const short8*)(sa + (rowgrp * 32 + 16 + l15) * 136 + k0 + quad * 8);
#pragma unroll
        for (int g = 0; g < 3; ++g) {
            const short8 b = *(const short8*)(sw + (g * 16 + l15) * 136 + k0 + quad * 8);
            acc[g * 2 + 0] = __builtin_amdgcn_mfma_f32_16x16x32_bf16(a0, b, acc[g * 2 + 0], 0, 0, 0);
            acc[g * 2 + 1] = __builtin_amdgcn_mfma_f32_16x16x32_bf16(a1, b, acc[g * 2 + 1], 0, 0, 0);
        }
    }

    // ---- exchange gate tiles via LDS (alias) ----
    __syncthreads();   // staging reads done before overwrite
#pragma unroll
    for (int g = 0; g < 3; ++g) {
#pragma unroll
        for (int rf = 0; rf < 2; ++rf) {
            const floatx4 a = acc[g * 2 + rf];
            const int rl = rowgrp * 32 + rf * 16 + quad * 4;
#pragma unroll
            for (int i = 0; i < 4; ++i)
                eg[((sel * 3 + g) * 64 + rl + i) * 17 + l15] = a[i];
        }
    }
    __syncthreads();

    // ---- combine: 64x16 outputs, 4 per thread ----
    for (int i = tid; i < 1024; i += 256) {
        const int r = i >> 4;
        const int c = i & 15;
        const int m = bm + r;
        if (m >= M) continue;
        const int jc = j0 + c;
        const float gir = eg[(0 * 64 + r) * 17 + c] + bih[jc];
        const float giz = eg[(1 * 64 + r) * 17 + c] + bih[128 + jc];
        const float gin = eg[(2 * 64 + r) * 17 + c] + bih[256 + jc];
        const float ghr = eg[(3 * 64 + r) * 17 + c] + bhh[jc];
        const float ghz = eg[(4 * 64 + r) * 17 + c] + bhh[128 + jc];
        const float ghn = eg[(5 * 64 + r) * 17 + c] + bhh[256 + jc];
        const float rg = sigf(gir + ghr);
        const float zg = sigf(giz + ghz);
        const float ng = tanhf(gin + rg * ghn);
        const float hp = hin[(size_t)m * 128 + jc];
        const float v = (1.f - zg) * ng + zg * hp;
        xout[(size_t)m * 128 + jc] = v > 0.f ? v : 0.f;
    }
}

// ---------------------------------------------------------------------------
// CSR build (dst-sorted), rebuilt every launch (stateless).
// ---------------------------------------------------------------------------
__global__ void hist_k(const int* __restrict__ ei, int* __restrict__ deg, int E)
{
    int e = blockIdx.x * 256 + threadIdx.x;
    if (e >= E) return;
    atomicAdd(deg + ei[E + e], 1);
}

__global__ __launch_bounds__(1024) void scan_k(const int* __restrict__ deg,
                                               int* __restrict__ rowptr, int n)
{
    __shared__ int buf[1024];
    __shared__ int sc;
    const int t = threadIdx.x;
    if (t == 0) sc = 0;
    __syncthreads();
    for (int base = 0; base < n; base += 1024) {
        int idx = base + t;
        int v = (idx < n) ? deg[idx] : 0;
        buf[t] = v;
        __syncthreads();
#pragma unroll
        for (int off = 1; off < 1024; off <<= 1) {
            int add = (t >= off) ? buf[t - off] : 0;
            __syncthreads();
            buf[t] += add;
            __syncthreads();
        }
        if (idx < n) rowptr[idx] = sc + buf[t] - v;
        __syncthreads();
        if (t == 0) sc += buf[1023];
        __syncthreads();
    }
    if (t == 0) rowptr[n] = sc;
}

__global__ void fill_csr_k(const int* __restrict__ ei, const int* __restrict__ rowptr,
                           int* __restrict__ cursor, int* __restrict__ csr_src,
                           int* __restrict__ csr_eid, int E)
{
    int e = blockIdx.x * 256 + threadIdx.x;
    if (e >= E) return;
    int s = ei[e], d = ei[E + e];
    int pos = atomicAdd(cursor + d, 1);
    int slot = rowptr[d] + pos;
    csr_src[slot] = s;
    csr_eid[slot] = e;
}

// fp32 -> bf16 elementwise (for edge_attr)
__global__ void cvt_bf16_k(const float* __restrict__ in, unsigned short* __restrict__ outp, int n)
{
    int gid = blockIdx.x * 256 + threadIdx.x;
    if (gid >= n) return;
    outp[gid] = f2bf(in[gid]);
}

// ---------------------------------------------------------------------------
// nd_conv gather (bf16 tables): out[d,h] = sum_e leaky(p[src,h] + ea[e].W1b[h])
// ---------------------------------------------------------------------------
__global__ __launch_bounds__(128) void nd_gather_k(
    const int* __restrict__ rowptr, const int* __restrict__ csr_src,
    const int* __restrict__ csr_eid, const unsigned short* __restrict__ ea16,
    const float* __restrict__ ndw, const unsigned short* __restrict__ p16,
    float* __restrict__ outp)
{
    const int d = blockIdx.x;
    const int t = threadIdx.x;
    float wr[16];
#pragma unroll
    for (int k = 0; k < 16; ++k) wr[k] = ndw[t * 144 + 128 + k];
    const int b0 = rowptr[d], b1 = rowptr[d + 1];
    float acc = 0.f;
    for (int i = b0; i < b1; ++i) {
        const int s = csr_src[i], e = csr_eid[i];
        const unsigned short* ev = ea16 + e * 16;
        float q = 0.f;
#pragma unroll
        for (int k = 0; k < 16; ++k) q += bf2f(ev[k]) * wr[k];
        const float v = bf2f(p16[(size_t)s * 128 + t]) + q;
        acc += v >= 0.f ? v : 0.01f * v;
    }
    outp[(size_t)d * 128 + t] = acc;
}

// per-node dots (bf16 xp): ssrc[n] = xp[n].asrc, sdst[n] = xp[n].adst
__global__ void node_dots_k(const unsigned short* __restrict__ xp,
                            const float* __restrict__ asrc,
                            const float* __restrict__ adst,
                            float* __restrict__ ssrc, float* __restrict__ sdst)
{
    int n = blockIdx.x, t = threadIdx.x;   // 128 threads
    float v = bf2f(xp[(size_t)n * 128 + t]);
    float a = v * asrc[t];
    float b = v * adst[t];
    for (int off = 32; off; off >>= 1) { a += __shfl_down(a, off); b += __shfl_down(b, off); }
    __shared__ float sa[2], sb[2];
    if ((t & 63) == 0) { sa[t >> 6] = a; sb[t >> 6] = b; }
    __syncthreads();
    if (t == 0) { ssrc[n] = sa[0] + sa[1]; sdst[n] = sb[0] + sb[1]; }
}

// ---------------------------------------------------------------------------
// Fused GAT aggregation per dst node (exact softmax; bf16 xp gather)
// ---------------------------------------------------------------------------
__global__ __launch_bounds__(128) void gat_gather_k(
    const int* __restrict__ rowptr, const int* __restrict__ csr_src,
    const float* __restrict__ ssrc, const float* __restrict__ sdst,
    const unsigned short* __restrict__ xp, const float* __restrict__ bias,
    float* __restrict__ outp)
{
    const int d = blockIdx.x;
    const int t = threadIdx.x;
    __shared__ float red[128];
    __shared__ float lw[128];
    __shared__ int   ls[128];

    const int b0 = rowptr[d], b1 = rowptr[d + 1];
    const int deg = b1 - b0;
    const float sdd = sdst[d];

    float lm = -INFINITY;
    for (int i = b0 + t; i < b1; i += 128) {
        float a = ssrc[csr_src[i]] + sdd;
        a = a >= 0.f ? a : 0.01f * a;
        lm = fmaxf(lm, a);
    }
    red[t] = lm;
    __syncthreads();
#pragma unroll
    for (int off = 64; off; off >>= 1) {
        if (t < off) red[t] = fmaxf(red[t], red[t + off]);
        __syncthreads();
    }
    const float amax = red[0];
    __syncthreads();

    float acc = 0.f, dpart = 0.f;
    for (int base = b0; base < b1; base += 128) {
        int len = min(128, b1 - base);
        if (t < len) {
            int s = csr_src[base + t];
            float a = ssrc[s] + sdd;
            a = a >= 0.f ? a : 0.01f * a;
            float w = expf(a - amax);
            lw[t] = w;
            ls[t] = s;
            dpart += w;
        }
        __syncthreads();
        for (int j = 0; j < len; ++j)
            acc += lw[j] * bf2f(xp[(size_t)ls[j] * 128 + t]);
        __syncthreads();
    }
    red[t] = dpart;
    __syncthreads();
#pragma unroll
    for (int off = 64; off; off >>= 1) {
        if (t < off) red[t] += red[t + off];
        __syncthreads();
    }
    const float denom = red[0];

    float v = (deg > 0 ? acc / denom : 0.f) + bias[t];
    outp[(size_t)d * 128 + t] = v > 0.f ? v : expf(v) - 1.f;   // elu
}

// out[i] = act(in[i] + bias[i % 128])   (bias may be null)
__global__ void bias_act_k(const float* __restrict__ in, const float* __restrict__ bias,
                           float* __restrict__ outp, int total, int act)
{
    int gid = blockIdx.x * 256 + threadIdx.x;
    if (gid >= total) return;
    float v = in[gid];
    if (bias) v += bias[gid & 127];
    outp[gid] = actf(v, act);
}

__global__ void agg_k(const float* __restrict__ xin, const int* __restrict__ batch,
                      float* __restrict__ agg, int total)
{
    int gid = blockIdx.x * 256 + threadIdx.x;
    if (gid >= total) return;
    int n = gid >> 7, j = gid & 127;
    atomicAdd(agg + batch[n] * 128 + j, xin[gid]);
}

__global__ void add_k(const float* __restrict__ a, const float* __restrict__ b,
                      float* __restrict__ c, int total)
{
    int gid = blockIdx.x * 256 + threadIdx.x;
    if (gid >= total) return;
    c[gid] = a[gid] + b[gid];
}

__global__ void lstm_combine_k(const float* __restrict__ g1, const float* __restrict__ g2,
                               const float* __restrict__ hg, float* __restrict__ outp, int total)
{
    int gid = blockIdx.x * 256 + threadIdx.x;
    if (gid >= total) return;
    int g = gid >> 7, j = gid & 127;
    const float* a = g1 + g * 512;
    const float* b = g2 + g * 512;
    float ii = a[j]       + b[j];
    float ff = a[j + 128] + b[j + 128];
    float gg = a[j + 256] + b[j + 256];
    float oo = a[j + 384] + b[j + 384];
    float c  = hg[gid];
    float c2 = sigf(ff) * c + sigf(ii) * tanhf(gg);
    outp[gid] = sigf(oo) * tanhf(c2);
}

__global__ void final_k(const float* __restrict__ oin, const float* __restrict__ w,
                        const float* __restrict__ b, float* __restrict__ y)
{
    int g = blockIdx.x, t = threadIdx.x;  // 128 threads
    float v = oin[g * 128 + t] * w[t];
    for (int off = 32; off; off >>= 1) v += __shfl_down(v, off);
    __shared__ float s2[2];
    if ((t & 63) == 0) s2[t >> 6] = v;
    __syncthreads();
    if (t == 0) y[g] = s2[0] + s2[1] + b[0];
}

// ---------------------------------------------------------------------------

extern "C" void kernel_launch(void* const* d_in, const int* in_sizes, int n_in,
                              void* d_out, int out_size, void* d_ws, size_t ws_size,
                              hipStream_t stream)
{
    const float* x      = (const float*)d_in[0];
    const int*   ei     = (const int*)  d_in[1];
    const float* ea     = (const float*)d_in[2];
    const int*   batch  = (const int*)  d_in[3];
    const float* lin1_w = (const float*)d_in[4];
    const float* lin1_b = (const float*)d_in[5];
    const float* nd1w   = (const float*)d_in[6];
    const float* nd2w   = (const float*)d_in[7];
    const float* ndb    = (const float*)d_in[8];
    const float* g0wih  = (const float*)d_in[9];
    const float* g0whh  = (const float*)d_in[10];
    const float* g0bih  = (const float*)d_in[11];
    const float* g0bhh  = (const float*)d_in[12];
    const float* gatw   = (const float*)d_in[13];
    const float* gatas  = (const float*)d_in[14];
    const float* gatad  = (const float*)d_in[15];
    const float* gatb   = (const float*)d_in[16];
    const float* gwih   = (const float*)d_in[17];
    const float* gwhh   = (const float*)d_in[18];
    const float* gbih   = (const float*)d_in[19];
    const float* gbhh   = (const float*)d_in[20];
    const float* ginw   = (const float*)d_in[21];
    const float* ginb   = (const float*)d_in[22];
    const float* lwih   = (const float*)d_in[23];
    const float* lwhh   = (const float*)d_in[24];
    const float* lbih   = (const float*)d_in[25];
    const float* lbhh   = (const float*)d_in[26];
    const float* l2w    = (const float*)d_in[27];
    const float* l2b    = (const float*)d_in[28];
    float* outp = (float*)d_out;

    const int N = NN, E = EE, G = GG;

    float* ws = (float*)d_ws;
    size_t off = 0;
    auto alloc = [&](size_t n) {
        float* r = ws + off;
        off += (n + 63) & ~(size_t)63;
        return r;
    };
    float* x1   = alloc((size_t)N * 128);
    float* hbuf = alloc((size_t)N * 128);
    float* accb = alloc((size_t)N * 128);
    float* xc   = alloc((size_t)N * 128);
    unsigned short* pb16 = (unsigned short*)alloc((size_t)N * 64);  // N*128 bf16 (p, then xp)
    unsigned short* ea16 = (unsigned short*)alloc((size_t)E * 8);   // E*16 bf16
    float* ssrc = alloc((size_t)N);
    float* sdst = alloc((size_t)N);
    float* agg  = alloc((size_t)G * 128);
    float* oA   = alloc((size_t)G * 128);
    float* oB   = alloc((size_t)G * 128);
    float* hgb  = alloc((size_t)G * 128);
    float* tGA  = alloc((size_t)G * 128);
    float* g1b  = alloc((size_t)G * 512);
    float* g2b  = alloc((size_t)G * 512);
    int* deg     = (int*)alloc((size_t)N);
    int* rowptr  = (int*)alloc((size_t)N + 1);
    int* cursor  = (int*)alloc((size_t)N);
    int* csr_src = (int*)alloc((size_t)E);
    int* csr_eid = (int*)alloc((size_t)E);
    (void)ws_size;

    auto gemm = [&](const float* A, const float* W, const float* bias, float* C,
                    int M, int K, int Nout, int wpitch, int act) {
        dim3 grid(Nout / 64, (M + 63) / 64);
        gemm_mfma_k<<<grid, 256, 0, stream>>>(A, W, bias, C, M, K, Nout, wpitch, act);
    };
    auto gemm16 = [&](const float* A, const float* W, unsigned short* C,
                      int M, int K, int Nout, int wpitch) {
        dim3 grid(Nout / 64, (M + 63) / 64);
        gemm_mfma_o16_k<<<grid, 256, 0, stream>>>(A, W, C, M, K, Nout, wpitch);
    };
    auto nb = [](int n) { return (n + 255) / 256; };

    auto gru = [&](const float* xin, const float* hin,
                   const float* wih, const float* whh,
                   const float* bih, const float* bhh, float* xout) {
        dim3 grid((N + 63) / 64, 8);
        gru_fused_k<<<grid, 256, 0, stream>>>(xin, hin, wih, whh, bih, bhh, xout, N);
    };

    // 0) CSR build (dst-major) + ea -> bf16
    hipMemsetAsync(deg, 0, (size_t)N * 4, stream);
    hipMemsetAsync(cursor, 0, (size_t)N * 4, stream);
    hist_k<<<nb(E), 256, 0, stream>>>(ei, deg, E);
    scan_k<<<1, 1024, 0, stream>>>(deg, rowptr, N);
    fill_csr_k<<<nb(E), 256, 0, stream>>>(ei, rowptr, cursor, csr_src, csr_eid, E);
    cvt_bf16_k<<<nb(E * 16), 256, 0, stream>>>(ea, ea16, E * 16);

    // 1) x1 = leaky(x @ lin1_w^T + lin1_b)
    gemm(x, lin1_w, lin1_b, x1, N, 64, 128, 64, 1);

    // 2) nd_conv (W2 hoisted out of segment_sum); p stored bf16
    gemm16(x1, nd1w, pb16, N, 128, 128, 144);
    nd_gather_k<<<N, 128, 0, stream>>>(rowptr, csr_src, csr_eid, ea16, nd1w, pb16, accb);
    gemm(accb, nd2w, ndb, hbuf, N, 128, 128, 128, 2);

    // 3) xcur = relu(gru_cell(h, x1))  -> xc
    gru(hbuf, x1, g0wih, g0whh, g0bih, g0bhh, xc);

    // 4) GAT layers (xp stored bf16)
    const float* xcur = xc;
    float* xnext = x1;
    for (int l = 0; l < 2; ++l) {
        gemm16(xcur, gatw + (size_t)l * 128 * 128, pb16, N, 128, 128, 128);
        node_dots_k<<<N, 128, 0, stream>>>(pb16, gatas + l * 128, gatad + l * 128, ssrc, sdst);
        gat_gather_k<<<N, 128, 0, stream>>>(rowptr, csr_src, ssrc, sdst, pb16,
                                            gatb + l * 128, hbuf);
        gru(hbuf, xcur, gwih + (size_t)l * 384 * 128, gwhh + (size_t)l * 384 * 128,
            gbih + l * 384, gbhh + l * 384, xnext);
        const float* t = xcur; xcur = xnext; xnext = (float*)t;
    }

    // 5) readout
    hipMemsetAsync(agg, 0, (size_t)G * 128 * 4, stream);
    agg_k<<<nb(N * 128), 256, 0, stream>>>(xcur, batch, agg, N * 128);
    bias_act_k<<<nb(G * 128), 256, 0, stream>>>(agg, nullptr, oA, G * 128, 3);

    // 6) T=2 GIN+LSTM refinement
    float* cur = oA; float* nxt = oB;
    for (int t = 0; t < 2; ++t) {
        add_k<<<nb(G * 128), 256, 0, stream>>>(cur, agg, tGA, G * 128);
        gemm(tGA, ginw, ginb, hgb, G, 128, 128, 128, 2);
        gemm(cur, lwih, lbih, g1b, G, 128, 512, 128, 0);
        gemm(hgb, lwhh, lbhh, g2b, G, 128, 512, 128, 0);
        lstm_combine_k<<<nb(G * 128), 256, 0, stream>>>(g1b, g2b, hgb, nxt, G * 128);
        float* tmp = cur; cur = nxt; nxt = tmp;
    }

    // 7) y = out @ lin2_w^T + lin2_b
    final_k<<<G, 128, 0, stream>>>(cur, l2w, l2b, outp);
}

// Round 5
// 1023.601 us; speedup vs baseline: 2.3788x; 1.0189x over previous
//
#include <hip/hip_runtime.h>
#include <cstdint>
#include <cmath>

// Problem constants (from reference):
#define NN 50000
#define EE 500000
#define GG 2000
// IN=64, H=128, ED=16, OUT=1, NUM_GAT=2, T=2

#define DEV __device__ __forceinline__

typedef __attribute__((ext_vector_type(8))) short short8;     // 8 bf16 (4 VGPRs)
typedef __attribute__((ext_vector_type(4))) float floatx4;
typedef __attribute__((ext_vector_type(4))) unsigned short ushort4v;

DEV float sigf(float x) { return 1.f / (1.f + expf(-x)); }

DEV float actf(float x, int act) {
    if (act == 1) return x >= 0.f ? x : 0.01f * x;        // leaky 0.01
    if (act == 2) return x > 0.f ? x : expf(x) - 1.f;     // elu
    if (act == 3) return x > 0.f ? x : 0.f;               // relu
    return x;
}

// fp32 -> bf16 round-to-nearest-even
DEV unsigned short f2bf(float f) {
    unsigned u = __float_as_uint(f);
    u += 0x7FFFu + ((u >> 16) & 1u);
    return (unsigned short)(u >> 16);
}
DEV float bf2f(unsigned short u) {
    return __uint_as_float(((unsigned)u) << 16);
}

// ---------------------------------------------------------------------------
// MFMA GEMM: C[M,Nout] = act(A[M,K] @ W[Nout,K]^T + bias), fp32 in/out,
// bf16 MFMA compute. K in {64,128}, Nout % 64 == 0. Block 256/4 waves, 64x64.
// ---------------------------------------------------------------------------
__global__ __launch_bounds__(256) void gemm_mfma_k(
    const float* __restrict__ A, const float* __restrict__ W,
    const float* __restrict__ bias, float* __restrict__ C,
    int M, int K, int Nout, int wpitch, int act)
{
    __shared__ unsigned short Als[64 * 136];
    __shared__ unsigned short Bls[64 * 136];
    const int tid = threadIdx.x;
    const int bm = blockIdx.y * 64;
    const int bn = blockIdx.x * 64;

    const int ks = (K == 128) ? 7 : 6;
    const int km = K - 1;
    const int nvec = (64 * K) >> 2;
    for (int i = tid; i < nvec; i += 256) {
        const int e4 = i << 2;
        const int r = e4 >> ks;
        const int c = e4 & km;
        float4 av = make_float4(0.f, 0.f, 0.f, 0.f);
        if (bm + r < M) av = *(const float4*)(A + (size_t)(bm + r) * K + c);
        ushort4v ua;
        ua[0] = f2bf(av.x); ua[1] = f2bf(av.y); ua[2] = f2bf(av.z); ua[3] = f2bf(av.w);
        *(ushort4v*)(Als + r * 136 + c) = ua;
        const float4 wv = *(const float4*)(W + (size_t)(bn + r) * wpitch + c);
        ushort4v uw;
        uw[0] = f2bf(wv.x); uw[1] = f2bf(wv.y); uw[2] = f2bf(wv.z); uw[3] = f2bf(wv.w);
        *(ushort4v*)(Bls + r * 136 + c) = uw;
    }
    __syncthreads();

    const int wave = tid >> 6;
    const int lane = tid & 63;
    const int wr = (wave >> 1) * 32;
    const int wc = (wave & 1) * 32;
    const int l15 = lane & 15;
    const int quad = lane >> 4;

    floatx4 acc00 = {}, acc01 = {}, acc10 = {}, acc11 = {};
    for (int k0 = 0; k0 < K; k0 += 32) {
        const short8 a0 = *(const short8*)(Als + (wr + l15) * 136 + k0 + quad * 8);
        const short8 a1 = *(const short8*)(Als + (wr + 16 + l15) * 136 + k0 + quad * 8);
        const short8 b0 = *(const short8*)(Bls + (wc + l15) * 136 + k0 + quad * 8);
        const short8 b1 = *(const short8*)(Bls + (wc + 16 + l15) * 136 + k0 + quad * 8);
        acc00 = __builtin_amdgcn_mfma_f32_16x16x32_bf16(a0, b0, acc00, 0, 0, 0);
        acc01 = __builtin_amdgcn_mfma_f32_16x16x32_bf16(a0, b1, acc01, 0, 0, 0);
        acc10 = __builtin_amdgcn_mfma_f32_16x16x32_bf16(a1, b0, acc10, 0, 0, 0);
        acc11 = __builtin_amdgcn_mfma_f32_16x16x32_bf16(a1, b1, acc11, 0, 0, 0);
    }

    const floatx4* accs[4] = { &acc00, &acc01, &acc10, &acc11 };
#pragma unroll
    for (int r = 0; r < 2; ++r) {
#pragma unroll
        for (int c = 0; c < 2; ++c) {
            const floatx4 a = *accs[r * 2 + c];
            const int n = bn + wc + c * 16 + l15;
            const float bv = bias ? bias[n] : 0.f;
#pragma unroll
            for (int i = 0; i < 4; ++i) {
                const int m = bm + wr + r * 16 + quad * 4 + i;
                if (m < M) C[(size_t)m * Nout + n] = actf(a[i] + bv, act);
            }
        }
    }
}

// Same GEMM but bf16 output (for gather tables p / xp), no bias.
__global__ __launch_bounds__(256) void gemm_mfma_o16_k(
    const float* __restrict__ A, const float* __restrict__ W,
    unsigned short* __restrict__ C, int M, int K, int Nout, int wpitch)
{
    __shared__ unsigned short Als[64 * 136];
    __shared__ unsigned short Bls[64 * 136];
    const int tid = threadIdx.x;
    const int bm = blockIdx.y * 64;
    const int bn = blockIdx.x * 64;

    const int ks = (K == 128) ? 7 : 6;
    const int km = K - 1;
    const int nvec = (64 * K) >> 2;
    for (int i = tid; i < nvec; i += 256) {
        const int e4 = i << 2;
        const int r = e4 >> ks;
        const int c = e4 & km;
        float4 av = make_float4(0.f, 0.f, 0.f, 0.f);
        if (bm + r < M) av = *(const float4*)(A + (size_t)(bm + r) * K + c);
        ushort4v ua;
        ua[0] = f2bf(av.x); ua[1] = f2bf(av.y); ua[2] = f2bf(av.z); ua[3] = f2bf(av.w);
        *(ushort4v*)(Als + r * 136 + c) = ua;
        const float4 wv = *(const float4*)(W + (size_t)(bn + r) * wpitch + c);
        ushort4v uw;
        uw[0] = f2bf(wv.x); uw[1] = f2bf(wv.y); uw[2] = f2bf(wv.z); uw[3] = f2bf(wv.w);
        *(ushort4v*)(Bls + r * 136 + c) = uw;
    }
    __syncthreads();

    const int wave = tid >> 6;
    const int lane = tid & 63;
    const int wr = (wave >> 1) * 32;
    const int wc = (wave & 1) * 32;
    const int l15 = lane & 15;
    const int quad = lane >> 4;

    floatx4 acc00 = {}, acc01 = {}, acc10 = {}, acc11 = {};
    for (int k0 = 0; k0 < K; k0 += 32) {
        const short8 a0 = *(const short8*)(Als + (wr + l15) * 136 + k0 + quad * 8);
        const short8 a1 = *(const short8*)(Als + (wr + 16 + l15) * 136 + k0 + quad * 8);
        const short8 b0 = *(const short8*)(Bls + (wc + l15) * 136 + k0 + quad * 8);
        const short8 b1 = *(const short8*)(Bls + (wc + 16 + l15) * 136 + k0 + quad * 8);
        acc00 = __builtin_amdgcn_mfma_f32_16x16x32_bf16(a0, b0, acc00, 0, 0, 0);
        acc01 = __builtin_amdgcn_mfma_f32_16x16x32_bf16(a0, b1, acc01, 0, 0, 0);
        acc10 = __builtin_amdgcn_mfma_f32_16x16x32_bf16(a1, b0, acc10, 0, 0, 0);
        acc11 = __builtin_amdgcn_mfma_f32_16x16x32_bf16(a1, b1, acc11, 0, 0, 0);
    }

    const floatx4* accs[4] = { &acc00, &acc01, &acc10, &acc11 };
#pragma unroll
    for (int r = 0; r < 2; ++r) {
#pragma unroll
        for (int c = 0; c < 2; ++c) {
            const floatx4 a = *accs[r * 2 + c];
            const int n = bn + wc + c * 16 + l15;
#pragma unroll
            for (int i = 0; i < 4; ++i) {
                const int m = bm + wr + r * 16 + quad * 4 + i;
                if (m < M) C[(size_t)m * Nout + n] = f2bf(a[i]);
            }
        }
    }
}

// ---------------------------------------------------------------------------
// Fused GRU v2: xout = relu(gru_cell(xin, hin)). Block = 64 rows, 4 waves =
// 4 row-groups of 16. x/h staged once in LDS (bf16, stride 136, 34.8 KB).
// Weights pre-converted bf16, B-frags read directly from global (L2-hot).
// Per col-tile (8 of them): 6 gate accs in registers, in-register combine.
// No LDS gate exchange, no input re-read.
// ---------------------------------------------------------------------------
__global__ __launch_bounds__(256) void gru_fused2_k(
    const float* __restrict__ xin, const float* __restrict__ hin,
    const unsigned short* __restrict__ wih16, const unsigned short* __restrict__ whh16,
    const float* __restrict__ bih, const float* __restrict__ bhh,
    float* __restrict__ xout, int M)
{
    __shared__ unsigned short sX[64 * 136];
    __shared__ unsigned short sH[64 * 136];

    const int tid = threadIdx.x;
    const int bm = blockIdx.x * 64;

    // ---- stage xin/hin (64x128, fp32 -> bf16), rows >= M zeroed ----
    for (int i = tid; i < 2048; i += 256) {
        const int e4 = i << 2;
        const int r = e4 >> 7;
        const int c = e4 & 127;
        const int m = bm + r;
        float4 xv = make_float4(0.f, 0.f, 0.f, 0.f);
        float4 hv = make_float4(0.f, 0.f, 0.f, 0.f);
        if (m < M) {
            xv = *(const float4*)(xin + (size_t)m * 128 + c);
            hv = *(const float4*)(hin + (size_t)m * 128 + c);
        }
        ushort4v ux, uh;
        ux[0] = f2bf(xv.x); ux[1] = f2bf(xv.y); ux[2] = f2bf(xv.z); ux[3] = f2bf(xv.w);
        uh[0] = f2bf(hv.x); uh[1] = f2bf(hv.y); uh[2] = f2bf(hv.z); uh[3] = f2bf(hv.w);
        *(ushort4v*)(sX + r * 136 + c) = ux;
        *(ushort4v*)(sH + r * 136 + c) = uh;
    }
    __syncthreads();

    const int wave = tid >> 6;          // row-group 0..3 (16 rows each)
    const int lane = tid & 63;
    const int l15 = lane & 15;
    const int quad = lane >> 4;
    const int rbase = wave * 16;        // tile row base within block

    // 8 output col-tiles of 16
    for (int ct = 0; ct < 8; ++ct) {
        const int j0 = ct * 16;
        floatx4 acc[6] = {};            // [0..2]=gi r,z,n  [3..5]=gh r,z,n
#pragma unroll
        for (int k0 = 0; k0 < 128; k0 += 32) {
            const short8 ax = *(const short8*)(sX + (rbase + l15) * 136 + k0 + quad * 8);
            const short8 ah = *(const short8*)(sH + (rbase + l15) * 136 + k0 + quad * 8);
#pragma unroll
            for (int g = 0; g < 3; ++g) {
                const short8 bi = *(const short8*)(wih16 + (size_t)(g * 128 + j0 + l15) * 128 + k0 + quad * 8);
                const short8 bh = *(const short8*)(whh16 + (size_t)(g * 128 + j0 + l15) * 128 + k0 + quad * 8);
                acc[g]     = __builtin_amdgcn_mfma_f32_16x16x32_bf16(ax, bi, acc[g], 0, 0, 0);
                acc[3 + g] = __builtin_amdgcn_mfma_f32_16x16x32_bf16(ah, bh, acc[3 + g], 0, 0, 0);
            }
        }
        // ---- in-register combine; C layout: row = quad*4+i, col = l15 ----
        const int j = j0 + l15;
        const float bir = bih[j],       bhr = bhh[j];
        const float biz = bih[128 + j], bhz = bhh[128 + j];
        const float bin = bih[256 + j], bhn = bhh[256 + j];
#pragma unroll
        for (int i = 0; i < 4; ++i) {
            const int m = bm + rbase + quad * 4 + i;
            if (m >= M) continue;
            const float rg = sigf(acc[0][i] + bir + acc[3][i] + bhr);
            const float zg = sigf(acc[1][i] + biz + acc[4][i] + bhz);
            const float ng = tanhf(acc[2][i] + bin + rg * (acc[5][i] + bhn));
            const float hp = hin[(size_t)m * 128 + j];
            const float v = (1.f - zg) * ng + zg * hp;
            xout[(size_t)m * 128 + j] = v > 0.f ? v : 0.f;
        }
    }
}

// ---------------------------------------------------------------------------
// CSR build (dst-sorted), rebuilt every launch (stateless).
// ---------------------------------------------------------------------------
__global__ void hist_k(const int* __restrict__ ei, int* __restrict__ deg, int E)
{
    int e = blockIdx.x * 256 + threadIdx.x;
    if (e >= E) return;
    atomicAdd(deg + ei[E + e], 1);
}

__global__ __launch_bounds__(1024) void scan_k(const int* __restrict__ deg,
                                               int* __restrict__ rowptr, int n)
{
    __shared__ int buf[1024];
    __shared__ int sc;
    const int t = threadIdx.x;
    if (t == 0) sc = 0;
    __syncthreads();
    for (int base = 0; base < n; base += 1024) {
        int idx = base + t;
        int v = (idx < n) ? deg[idx] : 0;
        buf[t] = v;
        __syncthreads();
#pragma unroll
        for (int off = 1; off < 1024; off <<= 1) {
            int add = (t >= off) ? buf[t - off] : 0;
            __syncthreads();
            buf[t] += add;
            __syncthreads();
        }
        if (idx < n) rowptr[idx] = sc + buf[t] - v;
        __syncthreads();
        if (t == 0) sc += buf[1023];
        __syncthreads();
    }
    if (t == 0) rowptr[n] = sc;
}

__global__ void fill_csr_k(const int* __restrict__ ei, const int* __restrict__ rowptr,
                           int* __restrict__ cursor, int* __restrict__ csr_src,
                           int* __restrict__ csr_eid, int E)
{
    int e = blockIdx.x * 256 + threadIdx.x;
    if (e >= E) return;
    int s = ei[e], d = ei[E + e];
    int pos = atomicAdd(cursor + d, 1);
    int slot = rowptr[d] + pos;
    csr_src[slot] = s;
    csr_eid[slot] = e;
}

// fp32 -> bf16 elementwise
__global__ void cvt_bf16_k(const float* __restrict__ in, unsigned short* __restrict__ outp, int n)
{
    int gid = blockIdx.x * 256 + threadIdx.x;
    if (gid >= n) return;
    outp[gid] = f2bf(in[gid]);
}

// ---------------------------------------------------------------------------
// nd_conv gather (bf16 tables): out[d,h] = sum_e leaky(p[src,h] + ea[e].W1b[h])
// ---------------------------------------------------------------------------
__global__ __launch_bounds__(128) void nd_gather_k(
    const int* __restrict__ rowptr, const int* __restrict__ csr_src,
    const int* __restrict__ csr_eid, const unsigned short* __restrict__ ea16,
    const float* __restrict__ ndw, const unsigned short* __restrict__ p16,
    float* __restrict__ outp)
{
    const int d = blockIdx.x;
    const int t = threadIdx.x;
    float wr[16];
#pragma unroll
    for (int k = 0; k < 16; ++k) wr[k] = ndw[t * 144 + 128 + k];
    const int b0 = rowptr[d], b1 = rowptr[d + 1];
    float acc = 0.f;
    for (int i = b0; i < b1; ++i) {
        const int s = csr_src[i], e = csr_eid[i];
        const unsigned short* ev = ea16 + e * 16;
        float q = 0.f;
#pragma unroll
        for (int k = 0; k < 16; ++k) q += bf2f(ev[k]) * wr[k];
        const float v = bf2f(p16[(size_t)s * 128 + t]) + q;
        acc += v >= 0.f ? v : 0.01f * v;
    }
    outp[(size_t)d * 128 + t] = acc;
}

// per-node dots (bf16 xp): ssrc[n] = xp[n].asrc, sdst[n] = xp[n].adst
__global__ void node_dots_k(const unsigned short* __restrict__ xp,
                            const float* __restrict__ asrc,
                            const float* __restrict__ adst,
                            float* __restrict__ ssrc, float* __restrict__ sdst)
{
    int n = blockIdx.x, t = threadIdx.x;   // 128 threads
    float v = bf2f(xp[(size_t)n * 128 + t]);
    float a = v * asrc[t];
    float b = v * adst[t];
    for (int off = 32; off; off >>= 1) { a += __shfl_down(a, off); b += __shfl_down(b, off); }
    __shared__ float sa[2], sb[2];
    if ((t & 63) == 0) { sa[t >> 6] = a; sb[t >> 6] = b; }
    __syncthreads();
    if (t == 0) { ssrc[n] = sa[0] + sa[1]; sdst[n] = sb[0] + sb[1]; }
}

// ---------------------------------------------------------------------------
// Fused GAT aggregation per dst node (exact softmax; bf16 xp gather)
// ---------------------------------------------------------------------------
__global__ __launch_bounds__(128) void gat_gather_k(
    const int* __restrict__ rowptr, const int* __restrict__ csr_src,
    const float* __restrict__ ssrc, const float* __restrict__ sdst,
    const unsigned short* __restrict__ xp, const float* __restrict__ bias,
    float* __restrict__ outp)
{
    const int d = blockIdx.x;
    const int t = threadIdx.x;
    __shared__ float red[128];
    __shared__ float lw[128];
    __shared__ int   ls[128];

    const int b0 = rowptr[d], b1 = rowptr[d + 1];
    const int deg = b1 - b0;
    const float sdd = sdst[d];

    float lm = -INFINITY;
    for (int i = b0 + t; i < b1; i += 128) {
        float a = ssrc[csr_src[i]] + sdd;
        a = a >= 0.f ? a : 0.01f * a;
        lm = fmaxf(lm, a);
    }
    red[t] = lm;
    __syncthreads();
#pragma unroll
    for (int off = 64; off; off >>= 1) {
        if (t < off) red[t] = fmaxf(red[t], red[t + off]);
        __syncthreads();
    }
    const float amax = red[0];
    __syncthreads();

    float acc = 0.f, dpart = 0.f;
    for (int base = b0; base < b1; base += 128) {
        int len = min(128, b1 - base);
        if (t < len) {
            int s = csr_src[base + t];
            float a = ssrc[s] + sdd;
            a = a >= 0.f ? a : 0.01f * a;
            float w = expf(a - amax);
            lw[t] = w;
            ls[t] = s;
            dpart += w;
        }
        __syncthreads();
        for (int j = 0; j < len; ++j)
            acc += lw[j] * bf2f(xp[(size_t)ls[j] * 128 + t]);
        __syncthreads();
    }
    red[t] = dpart;
    __syncthreads();
#pragma unroll
    for (int off = 64; off; off >>= 1) {
        if (t < off) red[t] += red[t + off];
        __syncthreads();
    }
    const float denom = red[0];

    float v = (deg > 0 ? acc / denom : 0.f) + bias[t];
    outp[(size_t)d * 128 + t] = v > 0.f ? v : expf(v) - 1.f;   // elu
}

// out[i] = act(in[i] + bias[i % 128])   (bias may be null)
__global__ void bias_act_k(const float* __restrict__ in, const float* __restrict__ bias,
                           float* __restrict__ outp, int total, int act)
{
    int gid = blockIdx.x * 256 + threadIdx.x;
    if (gid >= total) return;
    float v = in[gid];
    if (bias) v += bias[gid & 127];
    outp[gid] = actf(v, act);
}

__global__ void agg_k(const float* __restrict__ xin, const int* __restrict__ batch,
                      float* __restrict__ agg, int total)
{
    int gid = blockIdx.x * 256 + threadIdx.x;
    if (gid >= total) return;
    int n = gid >> 7, j = gid & 127;
    atomicAdd(agg + batch[n] * 128 + j, xin[gid]);
}

__global__ void add_k(const float* __restrict__ a, const float* __restrict__ b,
                      float* __restrict__ c, int total)
{
    int gid = blockIdx.x * 256 + threadIdx.x;
    if (gid >= total) return;
    c[gid] = a[gid] + b[gid];
}

__global__ void lstm_combine_k(const float* __restrict__ g1, const float* __restrict__ g2,
                               const float* __restrict__ hg, float* __restrict__ outp, int total)
{
    int gid = blockIdx.x * 256 + threadIdx.x;
    if (gid >= total) return;
    int g = gid >> 7, j = gid & 127;
    const float* a = g1 + g * 512;
    const float* b = g2 + g * 512;
    float ii = a[j]       + b[j];
    float ff = a[j + 128] + b[j + 128];
    float gg = a[j + 256] + b[j + 256];
    float oo = a[j + 384] + b[j + 384];
    float c  = hg[gid];
    float c2 = sigf(ff) * c + sigf(ii) * tanhf(gg);
    outp[gid] = sigf(oo) * tanhf(c2);
}

__global__ void final_k(const float* __restrict__ oin, const float* __restrict__ w,
                        const float* __restrict__ b, float* __restrict__ y)
{
    int g = blockIdx.x, t = threadIdx.x;  // 128 threads
    float v = oin[g * 128 + t] * w[t];
    for (int off = 32; off; off >>= 1) v += __shfl_down(v, off);
    __shared__ float s2[2];
    if ((t & 63) == 0) s2[t >> 6] = v;
    __syncthreads();
    if (t == 0) y[g] = s2[0] + s2[1] + b[0];
}

// ---------------------------------------------------------------------------

extern "C" void kernel_launch(void* const* d_in, const int* in_sizes, int n_in,
                              void* d_out, int out_size, void* d_ws, size_t ws_size,
                              hipStream_t stream)
{
    const float* x      = (const float*)d_in[0];
    const int*   ei     = (const int*)  d_in[1];
    const float* ea     = (const float*)d_in[2];
    const int*   batch  = (const int*)  d_in[3];
    const float* lin1_w = (const float*)d_in[4];
    const float* lin1_b = (const float*)d_in[5];
    const float* nd1w   = (const float*)d_in[6];
    const float* nd2w   = (const float*)d_in[7];
    const float* ndb    = (const float*)d_in[8];
    const float* g0wih  = (const float*)d_in[9];
    const float* g0whh  = (const float*)d_in[10];
    const float* g0bih  = (const float*)d_in[11];
    const float* g0bhh  = (const float*)d_in[12];
    const float* gatw   = (const float*)d_in[13];
    const float* gatas  = (const float*)d_in[14];
    const float* gatad  = (const float*)d_in[15];
    const float* gatb   = (const float*)d_in[16];
    const float* gwih   = (const float*)d_in[17];
    const float* gwhh   = (const float*)d_in[18];
    const float* gbih   = (const float*)d_in[19];
    const float* gbhh   = (const float*)d_in[20];
    const float* ginw   = (const float*)d_in[21];
    const float* ginb   = (const float*)d_in[22];
    const float* lwih   = (const float*)d_in[23];
    const float* lwhh   = (const float*)d_in[24];
    const float* lbih   = (const float*)d_in[25];
    const float* lbhh   = (const float*)d_in[26];
    const float* l2w    = (const float*)d_in[27];
    const float* l2b    = (const float*)d_in[28];
    float* outp = (float*)d_out;

    const int N = NN, E = EE, G = GG;

    float* ws = (float*)d_ws;
    size_t off = 0;
    auto alloc = [&](size_t n) {
        float* r = ws + off;
        off += (n + 63) & ~(size_t)63;
        return r;
    };
    float* x1   = alloc((size_t)N * 128);
    float* hbuf = alloc((size_t)N * 128);
    float* accb = alloc((size_t)N * 128);
    float* xc   = alloc((size_t)N * 128);
    unsigned short* pb16 = (unsigned short*)alloc((size_t)N * 64);  // N*128 bf16
    unsigned short* ea16 = (unsigned short*)alloc((size_t)E * 8);   // E*16 bf16
    float* ssrc = alloc((size_t)N);
    float* sdst = alloc((size_t)N);
    float* agg  = alloc((size_t)G * 128);
    float* oA   = alloc((size_t)G * 128);
    float* oB   = alloc((size_t)G * 128);
    float* hgb  = alloc((size_t)G * 128);
    float* tGA  = alloc((size_t)G * 128);
    float* g1b  = alloc((size_t)G * 512);
    float* g2b  = alloc((size_t)G * 512);
    // bf16 GRU weights: [3*128][128] each; gat grus: [2][3*128][128]
    unsigned short* g0wih16 = (unsigned short*)alloc(49152 / 2);
    unsigned short* g0whh16 = (unsigned short*)alloc(49152 / 2);
    unsigned short* gwih16  = (unsigned short*)alloc(98304 / 2);
    unsigned short* gwhh16  = (unsigned short*)alloc(98304 / 2);
    int* deg     = (int*)alloc((size_t)N);
    int* rowptr  = (int*)alloc((size_t)N + 1);
    int* cursor  = (int*)alloc((size_t)N);
    int* csr_src = (int*)alloc((size_t)E);
    int* csr_eid = (int*)alloc((size_t)E);
    (void)ws_size;

    auto gemm = [&](const float* A, const float* W, const float* bias, float* C,
                    int M, int K, int Nout, int wpitch, int act) {
        dim3 grid(Nout / 64, (M + 63) / 64);
        gemm_mfma_k<<<grid, 256, 0, stream>>>(A, W, bias, C, M, K, Nout, wpitch, act);
    };
    auto gemm16 = [&](const float* A, const float* W, unsigned short* C,
                      int M, int K, int Nout, int wpitch) {
        dim3 grid(Nout / 64, (M + 63) / 64);
        gemm_mfma_o16_k<<<grid, 256, 0, stream>>>(A, W, C, M, K, Nout, wpitch);
    };
    auto nb = [](int n) { return (n + 255) / 256; };

    auto gru = [&](const float* xin, const float* hin,
                   const unsigned short* wih16, const unsigned short* whh16,
                   const float* bih, const float* bhh, float* xout) {
        gru_fused2_k<<<(N + 63) / 64, 256, 0, stream>>>(
            xin, hin, wih16, whh16, bih, bhh, xout, N);
    };

    // 0) CSR build (dst-major) + bf16 conversions (ea, GRU weights)
    hipMemsetAsync(deg, 0, (size_t)N * 4, stream);
    hipMemsetAsync(cursor, 0, (size_t)N * 4, stream);
    hist_k<<<nb(E), 256, 0, stream>>>(ei, deg, E);
    scan_k<<<1, 1024, 0, stream>>>(deg, rowptr, N);
    fill_csr_k<<<nb(E), 256, 0, stream>>>(ei, rowptr, cursor, csr_src, csr_eid, E);
    cvt_bf16_k<<<nb(E * 16), 256, 0, stream>>>(ea, ea16, E * 16);
    cvt_bf16_k<<<nb(49152), 256, 0, stream>>>(g0wih, g0wih16, 49152);
    cvt_bf16_k<<<nb(49152), 256, 0, stream>>>(g0whh, g0whh16, 49152);
    cvt_bf16_k<<<nb(98304), 256, 0, stream>>>(gwih, gwih16, 98304);
    cvt_bf16_k<<<nb(98304), 256, 0, stream>>>(gwhh, gwhh16, 98304);

    // 1) x1 = leaky(x @ lin1_w^T + lin1_b)
    gemm(x, lin1_w, lin1_b, x1, N, 64, 128, 64, 1);

    // 2) nd_conv (W2 hoisted out of segment_sum); p stored bf16
    gemm16(x1, nd1w, pb16, N, 128, 128, 144);
    nd_gather_k<<<N, 128, 0, stream>>>(rowptr, csr_src, csr_eid, ea16, nd1w, pb16, accb);
    gemm(accb, nd2w, ndb, hbuf, N, 128, 128, 128, 2);

    // 3) xcur = relu(gru_cell(h, x1))  -> xc
    gru(hbuf, x1, g0wih16, g0whh16, g0bih, g0bhh, xc);

    // 4) GAT layers (xp stored bf16)
    const float* xcur = xc;
    float* xnext = x1;
    for (int l = 0; l < 2; ++l) {
        gemm16(xcur, gatw + (size_t)l * 128 * 128, pb16, N, 128, 128, 128);
        node_dots_k<<<N, 128, 0, stream>>>(pb16, gatas + l * 128, gatad + l * 128, ssrc, sdst);
        gat_gather_k<<<N, 128, 0, stream>>>(rowptr, csr_src, ssrc, sdst, pb16,
                                            gatb + l * 128, hbuf);
        gru(hbuf, xcur, gwih16 + (size_t)l * 49152, gwhh16 + (size_t)l * 49152,
            gbih + l * 384, gbhh + l * 384, xnext);
        const float* t = xcur; xcur = xnext; xnext = (float*)t;
    }

    // 5) readout
    hipMemsetAsync(agg, 0, (size_t)G * 128 * 4, stream);
    agg_k<<<nb(N * 128), 256, 0, stream>>>(xcur, batch, agg, N * 128);
    bias_act_k<<<nb(G * 128), 256, 0, stream>>>(agg, nullptr, oA, G * 128, 3);

    // 6) T=2 GIN+LSTM refinement
    float* cur = oA; float* nxt = oB;
    for (int t = 0; t < 2; ++t) {
        add_k<<<nb(G * 128), 256, 0, stream>>>(cur, agg, tGA, G * 128);
        gemm(tGA, ginw, ginb, hgb, G, 128, 128, 128, 2);
        gemm(cur, lwih, lbih, g1b, G, 128, 512, 128, 0);
        gemm(hgb, lwhh, lbhh, g2b, G, 128, 512, 128, 0);
        lstm_combine_k<<<nb(G * 128), 256, 0, stream>>>(g1b, g2b, hgb, nxt, G * 128);
        float* tmp = cur; cur = nxt; nxt = tmp;
    }

    // 7) y = out @ lin2_w^T + lin2_b
    final_k<<<G, 128, 0, stream>>>(cur, l2w, l2b, outp);
}

// Round 6
// 987.449 us; speedup vs baseline: 2.4659x; 1.0366x over previous
//
#include <hip/hip_runtime.h>
#include <cstdint>
#include <cmath>

// Problem constants (from reference):
#define NN 50000
#define EE 500000
#define GG 2000
// IN=64, H=128, ED=16, OUT=1, NUM_GAT=2, T=2

#define DEV __device__ __forceinline__

typedef __attribute__((ext_vector_type(8))) short short8;     // 8 bf16 (4 VGPRs)
typedef __attribute__((ext_vector_type(4))) float floatx4;
typedef __attribute__((ext_vector_type(4))) unsigned short ushort4v;
typedef _Float16 half2v __attribute__((ext_vector_type(2)));
typedef _Float16 half4v __attribute__((ext_vector_type(4)));
typedef _Float16 half8v __attribute__((ext_vector_type(8)));

DEV float sigf(float x) { return 1.f / (1.f + expf(-x)); }

DEV float actf(float x, int act) {
    if (act == 1) return x >= 0.f ? x : 0.01f * x;        // leaky 0.01
    if (act == 2) return x > 0.f ? x : expf(x) - 1.f;     // elu
    if (act == 3) return x > 0.f ? x : 0.f;               // relu
    return x;
}

// fp32 -> bf16 round-to-nearest-even
DEV unsigned short f2bf(float f) {
    unsigned u = __float_as_uint(f);
    u += 0x7FFFu + ((u >> 16) & 1u);
    return (unsigned short)(u >> 16);
}

DEV float hdot2(half2v a, half2v b, float c) {
#if __has_builtin(__builtin_amdgcn_fdot2)
    return __builtin_amdgcn_fdot2(a, b, c, false);
#else
    return c + (float)a[0] * (float)b[0] + (float)a[1] * (float)b[1];
#endif
}

#define H2(v, i) __builtin_shufflevector(v, v, 2 * (i), 2 * (i) + 1)

// ---------------------------------------------------------------------------
// MFMA GEMM: C[M,Nout] = act(A[M,K] @ W[Nout,K]^T + bias), fp32 in/out,
// bf16 MFMA compute. K in {64,128}, Nout % 64 == 0. Block 256/4 waves, 64x64.
// ---------------------------------------------------------------------------
__global__ __launch_bounds__(256) void gemm_mfma_k(
    const float* __restrict__ A, const float* __restrict__ W,
    const float* __restrict__ bias, float* __restrict__ C,
    int M, int K, int Nout, int wpitch, int act)
{
    __shared__ unsigned short Als[64 * 136];
    __shared__ unsigned short Bls[64 * 136];
    const int tid = threadIdx.x;
    const int bm = blockIdx.y * 64;
    const int bn = blockIdx.x * 64;

    const int ks = (K == 128) ? 7 : 6;
    const int km = K - 1;
    const int nvec = (64 * K) >> 2;
    for (int i = tid; i < nvec; i += 256) {
        const int e4 = i << 2;
        const int r = e4 >> ks;
        const int c = e4 & km;
        float4 av = make_float4(0.f, 0.f, 0.f, 0.f);
        if (bm + r < M) av = *(const float4*)(A + (size_t)(bm + r) * K + c);
        ushort4v ua;
        ua[0] = f2bf(av.x); ua[1] = f2bf(av.y); ua[2] = f2bf(av.z); ua[3] = f2bf(av.w);
        *(ushort4v*)(Als + r * 136 + c) = ua;
        const float4 wv = *(const float4*)(W + (size_t)(bn + r) * wpitch + c);
        ushort4v uw;
        uw[0] = f2bf(wv.x); uw[1] = f2bf(wv.y); uw[2] = f2bf(wv.z); uw[3] = f2bf(wv.w);
        *(ushort4v*)(Bls + r * 136 + c) = uw;
    }
    __syncthreads();

    const int wave = tid >> 6;
    const int lane = tid & 63;
    const int wr = (wave >> 1) * 32;
    const int wc = (wave & 1) * 32;
    const int l15 = lane & 15;
    const int quad = lane >> 4;

    floatx4 acc00 = {}, acc01 = {}, acc10 = {}, acc11 = {};
    for (int k0 = 0; k0 < K; k0 += 32) {
        const short8 a0 = *(const short8*)(Als + (wr + l15) * 136 + k0 + quad * 8);
        const short8 a1 = *(const short8*)(Als + (wr + 16 + l15) * 136 + k0 + quad * 8);
        const short8 b0 = *(const short8*)(Bls + (wc + l15) * 136 + k0 + quad * 8);
        const short8 b1 = *(const short8*)(Bls + (wc + 16 + l15) * 136 + k0 + quad * 8);
        acc00 = __builtin_amdgcn_mfma_f32_16x16x32_bf16(a0, b0, acc00, 0, 0, 0);
        acc01 = __builtin_amdgcn_mfma_f32_16x16x32_bf16(a0, b1, acc01, 0, 0, 0);
        acc10 = __builtin_amdgcn_mfma_f32_16x16x32_bf16(a1, b0, acc10, 0, 0, 0);
        acc11 = __builtin_amdgcn_mfma_f32_16x16x32_bf16(a1, b1, acc11, 0, 0, 0);
    }

    const floatx4* accs[4] = { &acc00, &acc01, &acc10, &acc11 };
#pragma unroll
    for (int r = 0; r < 2; ++r) {
#pragma unroll
        for (int c = 0; c < 2; ++c) {
            const floatx4 a = *accs[r * 2 + c];
            const int n = bn + wc + c * 16 + l15;
            const float bv = bias ? bias[n] : 0.f;
#pragma unroll
            for (int i = 0; i < 4; ++i) {
                const int m = bm + wr + r * 16 + quad * 4 + i;
                if (m < M) C[(size_t)m * Nout + n] = actf(a[i] + bv, act);
            }
        }
    }
}

// Same GEMM but f16 output (for gather tables p / xp), no bias.
__global__ __launch_bounds__(256) void gemm_mfma_o16_k(
    const float* __restrict__ A, const float* __restrict__ W,
    _Float16* __restrict__ C, int M, int K, int Nout, int wpitch)
{
    __shared__ unsigned short Als[64 * 136];
    __shared__ unsigned short Bls[64 * 136];
    const int tid = threadIdx.x;
    const int bm = blockIdx.y * 64;
    const int bn = blockIdx.x * 64;

    const int ks = (K == 128) ? 7 : 6;
    const int km = K - 1;
    const int nvec = (64 * K) >> 2;
    for (int i = tid; i < nvec; i += 256) {
        const int e4 = i << 2;
        const int r = e4 >> ks;
        const int c = e4 & km;
        float4 av = make_float4(0.f, 0.f, 0.f, 0.f);
        if (bm + r < M) av = *(const float4*)(A + (size_t)(bm + r) * K + c);
        ushort4v ua;
        ua[0] = f2bf(av.x); ua[1] = f2bf(av.y); ua[2] = f2bf(av.z); ua[3] = f2bf(av.w);
        *(ushort4v*)(Als + r * 136 + c) = ua;
        const float4 wv = *(const float4*)(W + (size_t)(bn + r) * wpitch + c);
        ushort4v uw;
        uw[0] = f2bf(wv.x); uw[1] = f2bf(wv.y); uw[2] = f2bf(wv.z); uw[3] = f2bf(wv.w);
        *(ushort4v*)(Bls + r * 136 + c) = uw;
    }
    __syncthreads();

    const int wave = tid >> 6;
    const int lane = tid & 63;
    const int wr = (wave >> 1) * 32;
    const int wc = (wave & 1) * 32;
    const int l15 = lane & 15;
    const int quad = lane >> 4;

    floatx4 acc00 = {}, acc01 = {}, acc10 = {}, acc11 = {};
    for (int k0 = 0; k0 < K; k0 += 32) {
        const short8 a0 = *(const short8*)(Als + (wr + l15) * 136 + k0 + quad * 8);
        const short8 a1 = *(const short8*)(Als + (wr + 16 + l15) * 136 + k0 + quad * 8);
        const short8 b0 = *(const short8*)(Bls + (wc + l15) * 136 + k0 + quad * 8);
        const short8 b1 = *(const short8*)(Bls + (wc + 16 + l15) * 136 + k0 + quad * 8);
        acc00 = __builtin_amdgcn_mfma_f32_16x16x32_bf16(a0, b0, acc00, 0, 0, 0);
        acc01 = __builtin_amdgcn_mfma_f32_16x16x32_bf16(a0, b1, acc01, 0, 0, 0);
        acc10 = __builtin_amdgcn_mfma_f32_16x16x32_bf16(a1, b0, acc10, 0, 0, 0);
        acc11 = __builtin_amdgcn_mfma_f32_16x16x32_bf16(a1, b1, acc11, 0, 0, 0);
    }

    const floatx4* accs[4] = { &acc00, &acc01, &acc10, &acc11 };
#pragma unroll
    for (int r = 0; r < 2; ++r) {
#pragma unroll
        for (int c = 0; c < 2; ++c) {
            const floatx4 a = *accs[r * 2 + c];
            const int n = bn + wc + c * 16 + l15;
#pragma unroll
            for (int i = 0; i < 4; ++i) {
                const int m = bm + wr + r * 16 + quad * 4 + i;
                if (m < M) C[(size_t)m * Nout + n] = (_Float16)a[i];
            }
        }
    }
}

// ---------------------------------------------------------------------------
// Fused GRU v2 (unchanged from R5): block = 64 rows, x/h staged once in LDS,
// bf16 weights read from global (L2-hot), in-register gate combine.
// ---------------------------------------------------------------------------
__global__ __launch_bounds__(256) void gru_fused2_k(
    const float* __restrict__ xin, const float* __restrict__ hin,
    const unsigned short* __restrict__ wih16, const unsigned short* __restrict__ whh16,
    const float* __restrict__ bih, const float* __restrict__ bhh,
    float* __restrict__ xout, int M)
{
    __shared__ unsigned short sX[64 * 136];
    __shared__ unsigned short sH[64 * 136];

    const int tid = threadIdx.x;
    const int bm = blockIdx.x * 64;

    for (int i = tid; i < 2048; i += 256) {
        const int e4 = i << 2;
        const int r = e4 >> 7;
        const int c = e4 & 127;
        const int m = bm + r;
        float4 xv = make_float4(0.f, 0.f, 0.f, 0.f);
        float4 hv = make_float4(0.f, 0.f, 0.f, 0.f);
        if (m < M) {
            xv = *(const float4*)(xin + (size_t)m * 128 + c);
            hv = *(const float4*)(hin + (size_t)m * 128 + c);
        }
        ushort4v ux, uh;
        ux[0] = f2bf(xv.x); ux[1] = f2bf(xv.y); ux[2] = f2bf(xv.z); ux[3] = f2bf(xv.w);
        uh[0] = f2bf(hv.x); uh[1] = f2bf(hv.y); uh[2] = f2bf(hv.z); uh[3] = f2bf(hv.w);
        *(ushort4v*)(sX + r * 136 + c) = ux;
        *(ushort4v*)(sH + r * 136 + c) = uh;
    }
    __syncthreads();

    const int wave = tid >> 6;
    const int lane = tid & 63;
    const int l15 = lane & 15;
    const int quad = lane >> 4;
    const int rbase = wave * 16;

    for (int ct = 0; ct < 8; ++ct) {
        const int j0 = ct * 16;
        floatx4 acc[6] = {};
#pragma unroll
        for (int k0 = 0; k0 < 128; k0 += 32) {
            const short8 ax = *(const short8*)(sX + (rbase + l15) * 136 + k0 + quad * 8);
            const short8 ah = *(const short8*)(sH + (rbase + l15) * 136 + k0 + quad * 8);
#pragma unroll
            for (int g = 0; g < 3; ++g) {
                const short8 bi = *(const short8*)(wih16 + (size_t)(g * 128 + j0 + l15) * 128 + k0 + quad * 8);
                const short8 bh = *(const short8*)(whh16 + (size_t)(g * 128 + j0 + l15) * 128 + k0 + quad * 8);
                acc[g]     = __builtin_amdgcn_mfma_f32_16x16x32_bf16(ax, bi, acc[g], 0, 0, 0);
                acc[3 + g] = __builtin_amdgcn_mfma_f32_16x16x32_bf16(ah, bh, acc[3 + g], 0, 0, 0);
            }
        }
        const int j = j0 + l15;
        const float bir = bih[j],       bhr = bhh[j];
        const float biz = bih[128 + j], bhz = bhh[128 + j];
        const float bin = bih[256 + j], bhn = bhh[256 + j];
#pragma unroll
        for (int i = 0; i < 4; ++i) {
            const int m = bm + rbase + quad * 4 + i;
            if (m >= M) continue;
            const float rg = sigf(acc[0][i] + bir + acc[3][i] + bhr);
            const float zg = sigf(acc[1][i] + biz + acc[4][i] + bhz);
            const float ng = tanhf(acc[2][i] + bin + rg * (acc[5][i] + bhn));
            const float hp = hin[(size_t)m * 128 + j];
            const float v = (1.f - zg) * ng + zg * hp;
            xout[(size_t)m * 128 + j] = v > 0.f ? v : 0.f;
        }
    }
}

// ---------------------------------------------------------------------------
// CSR build (dst-sorted), rebuilt every launch (stateless).
// ---------------------------------------------------------------------------
__global__ void hist_k(const int* __restrict__ ei, int* __restrict__ deg, int E)
{
    int e = blockIdx.x * 256 + threadIdx.x;
    if (e >= E) return;
    atomicAdd(deg + ei[E + e], 1);
}

__global__ __launch_bounds__(1024) void scan_k(const int* __restrict__ deg,
                                               int* __restrict__ rowptr, int n)
{
    __shared__ int buf[1024];
    __shared__ int sc;
    const int t = threadIdx.x;
    if (t == 0) sc = 0;
    __syncthreads();
    for (int base = 0; base < n; base += 1024) {
        int idx = base + t;
        int v = (idx < n) ? deg[idx] : 0;
        buf[t] = v;
        __syncthreads();
#pragma unroll
        for (int off = 1; off < 1024; off <<= 1) {
            int add = (t >= off) ? buf[t - off] : 0;
            __syncthreads();
            buf[t] += add;
            __syncthreads();
        }
        if (idx < n) rowptr[idx] = sc + buf[t] - v;
        __syncthreads();
        if (t == 0) sc += buf[1023];
        __syncthreads();
    }
    if (t == 0) rowptr[n] = sc;
}

__global__ void fill_csr_k(const int* __restrict__ ei, const int* __restrict__ rowptr,
                           int* __restrict__ cursor, int* __restrict__ csr_src,
                           int* __restrict__ csr_eid, int E)
{
    int e = blockIdx.x * 256 + threadIdx.x;
    if (e >= E) return;
    int s = ei[e], d = ei[E + e];
    int pos = atomicAdd(cursor + d, 1);
    int slot = rowptr[d] + pos;
    csr_src[slot] = s;
    csr_eid[slot] = e;
}

// fp32 -> bf16 elementwise (GRU weights)
__global__ void cvt_bf16_k(const float* __restrict__ in, unsigned short* __restrict__ outp, int n)
{
    int gid = blockIdx.x * 256 + threadIdx.x;
    if (gid >= n) return;
    outp[gid] = f2bf(in[gid]);
}

// fp32 -> f16 elementwise
__global__ void cvt_f16_k(const float* __restrict__ in, _Float16* __restrict__ outp, int n)
{
    int gid = blockIdx.x * 256 + threadIdx.x;
    if (gid >= n) return;
    outp[gid] = (_Float16)in[gid];
}

// nd_lin1_w[:,128:144] (pitch 144) -> f16 table [128][16]
__global__ void cvt_ndw_k(const float* __restrict__ ndw, _Float16* __restrict__ outp)
{
    int t = blockIdx.x * 256 + threadIdx.x;
    if (t >= 2048) return;
    int r = t >> 4, k = t & 15;
    outp[r * 16 + k] = (_Float16)ndw[r * 144 + 128 + k];
}

// ---------------------------------------------------------------------------
// nd_conv gather v3 (f16 + fdot2): out[d,h] = sum_e leaky(p[src,h]+ea[e].W1b[h])
// ---------------------------------------------------------------------------
__global__ __launch_bounds__(128) void nd_gather_k(
    const int* __restrict__ rowptr, const int* __restrict__ csr_src,
    const int* __restrict__ csr_eid, const _Float16* __restrict__ eaH,
    const _Float16* __restrict__ wH, const _Float16* __restrict__ pH,
    float* __restrict__ outp)
{
    const int d = blockIdx.x;
    const int t = threadIdx.x;   // feature 0..127
    const half8v w0 = *(const half8v*)(wH + t * 16);
    const half8v w1 = *(const half8v*)(wH + t * 16 + 8);

    const int b0 = rowptr[d], b1 = rowptr[d + 1];
    float acc = 0.f;
    for (int i = b0; i < b1; ++i) {
        const int s = csr_src[i], e = csr_eid[i];
        const half8v e0 = *(const half8v*)(eaH + (size_t)e * 16);
        const half8v e1 = *(const half8v*)(eaH + (size_t)e * 16 + 8);
        float q = 0.f;
        q = hdot2(H2(e0, 0), H2(w0, 0), q);
        q = hdot2(H2(e0, 1), H2(w0, 1), q);
        q = hdot2(H2(e0, 2), H2(w0, 2), q);
        q = hdot2(H2(e0, 3), H2(w0, 3), q);
        q = hdot2(H2(e1, 0), H2(w1, 0), q);
        q = hdot2(H2(e1, 1), H2(w1, 1), q);
        q = hdot2(H2(e1, 2), H2(w1, 2), q);
        q = hdot2(H2(e1, 3), H2(w1, 3), q);
        const float v = (float)pH[(size_t)s * 128 + t] + q;
        acc += v >= 0.f ? v : 0.01f * v;
    }
    outp[(size_t)d * 128 + t] = acc;
}

// per-node dots (f16 xp): ssrc[n] = xp[n].asrc, sdst[n] = xp[n].adst
__global__ void node_dots_k(const _Float16* __restrict__ xp,
                            const float* __restrict__ asrc,
                            const float* __restrict__ adst,
                            float* __restrict__ ssrc, float* __restrict__ sdst)
{
    int n = blockIdx.x, t = threadIdx.x;   // 128 threads
    float v = (float)xp[(size_t)n * 128 + t];
    float a = v * asrc[t];
    float b = v * adst[t];
    for (int off = 32; off; off >>= 1) { a += __shfl_down(a, off); b += __shfl_down(b, off); }
    __shared__ float sa[2], sb[2];
    if ((t & 63) == 0) { sa[t >> 6] = a; sb[t >> 6] = b; }
    __syncthreads();
    if (t == 0) { ssrc[n] = sa[0] + sa[1]; sdst[n] = sb[0] + sb[1]; }
}

// ---------------------------------------------------------------------------
// Fused GAT aggregation v3: exact softmax; weighted gather with 4 parallel
// edge-groups x 32 feature-quads (8B f16 loads, 4 loads in flight).
// ---------------------------------------------------------------------------
__global__ __launch_bounds__(128) void gat_gather_k(
    const int* __restrict__ rowptr, const int* __restrict__ csr_src,
    const float* __restrict__ ssrc, const float* __restrict__ sdst,
    const _Float16* __restrict__ xp, const float* __restrict__ bias,
    float* __restrict__ outp)
{
    const int d = blockIdx.x;
    const int t = threadIdx.x;
    __shared__ float red[128];
    __shared__ float lw[128];
    __shared__ int   ls[128];
    __shared__ float racc[4][128];

    const int b0 = rowptr[d], b1 = rowptr[d + 1];
    const int deg = b1 - b0;
    const float sdd = sdst[d];

    // pass A: exact segment max
    float lm = -INFINITY;
    for (int i = b0 + t; i < b1; i += 128) {
        float a = ssrc[csr_src[i]] + sdd;
        a = a >= 0.f ? a : 0.01f * a;
        lm = fmaxf(lm, a);
    }
    red[t] = lm;
    __syncthreads();
#pragma unroll
    for (int off = 64; off; off >>= 1) {
        if (t < off) red[t] = fmaxf(red[t], red[t + off]);
        __syncthreads();
    }
    const float amax = red[0];
    __syncthreads();

    // pass B: weights + gather (4 edge-groups x 32 feature-quads)
    const int g  = t >> 5;       // 0..3
    const int fq = t & 31;       // feature quad -> features 4fq..4fq+3
    float4 acc = make_float4(0.f, 0.f, 0.f, 0.f);
    float dpart = 0.f;
    for (int base = b0; base < b1; base += 128) {
        const int len = min(128, b1 - base);
        if (t < len) {
            const int s = csr_src[base + t];
            float a = ssrc[s] + sdd;
            a = a >= 0.f ? a : 0.01f * a;
            const float w = expf(a - amax);
            lw[t] = w;
            ls[t] = s;
            dpart += w;
        }
        __syncthreads();
        for (int j = 0; j < len; j += 4) {
            const int jj = j + g;
            if (jj < len) {
                const float w = lw[jj];
                const half4v hv = *(const half4v*)(xp + (size_t)ls[jj] * 128 + fq * 4);
                acc.x += w * (float)hv[0];
                acc.y += w * (float)hv[1];
                acc.z += w * (float)hv[2];
                acc.w += w * (float)hv[3];
            }
        }
        __syncthreads();
    }

    // denom
    red[t] = dpart;
    __syncthreads();
#pragma unroll
    for (int off = 64; off; off >>= 1) {
        if (t < off) red[t] += red[t + off];
        __syncthreads();
    }
    const float denom = red[0];

    // cross-group reduce
    racc[g][fq * 4 + 0] = acc.x;
    racc[g][fq * 4 + 1] = acc.y;
    racc[g][fq * 4 + 2] = acc.z;
    racc[g][fq * 4 + 3] = acc.w;
    __syncthreads();

    const float s4 = racc[0][t] + racc[1][t] + racc[2][t] + racc[3][t];
    float v = (deg > 0 ? s4 / denom : 0.f) + bias[t];
    outp[(size_t)d * 128 + t] = v > 0.f ? v : expf(v) - 1.f;   // elu
}

// out[i] = act(in[i] + bias[i % 128])   (bias may be null)
__global__ void bias_act_k(const float* __restrict__ in, const float* __restrict__ bias,
                           float* __restrict__ outp, int total, int act)
{
    int gid = blockIdx.x * 256 + threadIdx.x;
    if (gid >= total) return;
    float v = in[gid];
    if (bias) v += bias[gid & 127];
    outp[gid] = actf(v, act);
}

__global__ void agg_k(const float* __restrict__ xin, const int* __restrict__ batch,
                      float* __restrict__ agg, int total)
{
    int gid = blockIdx.x * 256 + threadIdx.x;
    if (gid >= total) return;
    int n = gid >> 7, j = gid & 127;
    atomicAdd(agg + batch[n] * 128 + j, xin[gid]);
}

__global__ void add_k(const float* __restrict__ a, const float* __restrict__ b,
                      float* __restrict__ c, int total)
{
    int gid = blockIdx.x * 256 + threadIdx.x;
    if (gid >= total) return;
    c[gid] = a[gid] + b[gid];
}

__global__ void lstm_combine_k(const float* __restrict__ g1, const float* __restrict__ g2,
                               const float* __restrict__ hg, float* __restrict__ outp, int total)
{
    int gid = blockIdx.x * 256 + threadIdx.x;
    if (gid >= total) return;
    int g = gid >> 7, j = gid & 127;
    const float* a = g1 + g * 512;
    const float* b = g2 + g * 512;
    float ii = a[j]       + b[j];
    float ff = a[j + 128] + b[j + 128];
    float gg = a[j + 256] + b[j + 256];
    float oo = a[j + 384] + b[j + 384];
    float c  = hg[gid];
    float c2 = sigf(ff) * c + sigf(ii) * tanhf(gg);
    outp[gid] = sigf(oo) * tanhf(c2);
}

__global__ void final_k(const float* __restrict__ oin, const float* __restrict__ w,
                        const float* __restrict__ b, float* __restrict__ y)
{
    int g = blockIdx.x, t = threadIdx.x;  // 128 threads
    float v = oin[g * 128 + t] * w[t];
    for (int off = 32; off; off >>= 1) v += __shfl_down(v, off);
    __shared__ float s2[2];
    if ((t & 63) == 0) s2[t >> 6] = v;
    __syncthreads();
    if (t == 0) y[g] = s2[0] + s2[1] + b[0];
}

// ---------------------------------------------------------------------------

extern "C" void kernel_launch(void* const* d_in, const int* in_sizes, int n_in,
                              void* d_out, int out_size, void* d_ws, size_t ws_size,
                              hipStream_t stream)
{
    const float* x      = (const float*)d_in[0];
    const int*   ei     = (const int*)  d_in[1];
    const float* ea     = (const float*)d_in[2];
    const int*   batch  = (const int*)  d_in[3];
    const float* lin1_w = (const float*)d_in[4];
    const float* lin1_b = (const float*)d_in[5];
    const float* nd1w   = (const float*)d_in[6];
    const float* nd2w   = (const float*)d_in[7];
    const float* ndb    = (const float*)d_in[8];
    const float* g0wih  = (const float*)d_in[9];
    const float* g0whh  = (const float*)d_in[10];
    const float* g0bih  = (const float*)d_in[11];
    const float* g0bhh  = (const float*)d_in[12];
    const float* gatw   = (const float*)d_in[13];
    const float* gatas  = (const float*)d_in[14];
    const float* gatad  = (const float*)d_in[15];
    const float* gatb   = (const float*)d_in[16];
    const float* gwih   = (const float*)d_in[17];
    const float* gwhh   = (const float*)d_in[18];
    const float* gbih   = (const float*)d_in[19];
    const float* gbhh   = (const float*)d_in[20];
    const float* ginw   = (const float*)d_in[21];
    const float* ginb   = (const float*)d_in[22];
    const float* lwih   = (const float*)d_in[23];
    const float* lwhh   = (const float*)d_in[24];
    const float* lbih   = (const float*)d_in[25];
    const float* lbhh   = (const float*)d_in[26];
    const float* l2w    = (const float*)d_in[27];
    const float* l2b    = (const float*)d_in[28];
    float* outp = (float*)d_out;

    const int N = NN, E = EE, G = GG;

    float* ws = (float*)d_ws;
    size_t off = 0;
    auto alloc = [&](size_t n) {
        float* r = ws + off;
        off += (n + 63) & ~(size_t)63;
        return r;
    };
    float* x1   = alloc((size_t)N * 128);
    float* hbuf = alloc((size_t)N * 128);
    float* accb = alloc((size_t)N * 128);
    float* xc   = alloc((size_t)N * 128);
    _Float16* pH  = (_Float16*)alloc((size_t)N * 64);   // N*128 f16 (p, then xp)
    _Float16* eaH = (_Float16*)alloc((size_t)E * 8);    // E*16 f16
    _Float16* ndwH = (_Float16*)alloc(1024);            // 128*16 f16
    float* ssrc = alloc((size_t)N);
    float* sdst = alloc((size_t)N);
    float* agg  = alloc((size_t)G * 128);
    float* oA   = alloc((size_t)G * 128);
    float* oB   = alloc((size_t)G * 128);
    float* hgb  = alloc((size_t)G * 128);
    float* tGA  = alloc((size_t)G * 128);
    float* g1b  = alloc((size_t)G * 512);
    float* g2b  = alloc((size_t)G * 512);
    unsigned short* g0wih16 = (unsigned short*)alloc(49152 / 2);
    unsigned short* g0whh16 = (unsigned short*)alloc(49152 / 2);
    unsigned short* gwih16  = (unsigned short*)alloc(98304 / 2);
    unsigned short* gwhh16  = (unsigned short*)alloc(98304 / 2);
    int* deg     = (int*)alloc((size_t)N);
    int* rowptr  = (int*)alloc((size_t)N + 1);
    int* cursor  = (int*)alloc((size_t)N);
    int* csr_src = (int*)alloc((size_t)E);
    int* csr_eid = (int*)alloc((size_t)E);
    (void)ws_size;

    auto gemm = [&](const float* A, const float* W, const float* bias, float* C,
                    int M, int K, int Nout, int wpitch, int act) {
        dim3 grid(Nout / 64, (M + 63) / 64);
        gemm_mfma_k<<<grid, 256, 0, stream>>>(A, W, bias, C, M, K, Nout, wpitch, act);
    };
    auto gemm16 = [&](const float* A, const float* W, _Float16* C,
                      int M, int K, int Nout, int wpitch) {
        dim3 grid(Nout / 64, (M + 63) / 64);
        gemm_mfma_o16_k<<<grid, 256, 0, stream>>>(A, W, C, M, K, Nout, wpitch);
    };
    auto nb = [](int n) { return (n + 255) / 256; };

    auto gru = [&](const float* xin, const float* hin,
                   const unsigned short* wih16, const unsigned short* whh16,
                   const float* bih, const float* bhh, float* xout) {
        gru_fused2_k<<<(N + 63) / 64, 256, 0, stream>>>(
            xin, hin, wih16, whh16, bih, bhh, xout, N);
    };

    // 0) CSR build + f16/bf16 conversions
    hipMemsetAsync(deg, 0, (size_t)N * 4, stream);
    hipMemsetAsync(cursor, 0, (size_t)N * 4, stream);
    hist_k<<<nb(E), 256, 0, stream>>>(ei, deg, E);
    scan_k<<<1, 1024, 0, stream>>>(deg, rowptr, N);
    fill_csr_k<<<nb(E), 256, 0, stream>>>(ei, rowptr, cursor, csr_src, csr_eid, E);
    cvt_f16_k<<<nb(E * 16), 256, 0, stream>>>(ea, eaH, E * 16);
    cvt_ndw_k<<<8, 256, 0, stream>>>(nd1w, ndwH);
    cvt_bf16_k<<<nb(49152), 256, 0, stream>>>(g0wih, g0wih16, 49152);
    cvt_bf16_k<<<nb(49152), 256, 0, stream>>>(g0whh, g0whh16, 49152);
    cvt_bf16_k<<<nb(98304), 256, 0, stream>>>(gwih, gwih16, 98304);
    cvt_bf16_k<<<nb(98304), 256, 0, stream>>>(gwhh, gwhh16, 98304);

    // 1) x1 = leaky(x @ lin1_w^T + lin1_b)
    gemm(x, lin1_w, lin1_b, x1, N, 64, 128, 64, 1);

    // 2) nd_conv (W2 hoisted out of segment_sum); p stored f16
    gemm16(x1, nd1w, pH, N, 128, 128, 144);
    nd_gather_k<<<N, 128, 0, stream>>>(rowptr, csr_src, csr_eid, eaH, ndwH, pH, accb);
    gemm(accb, nd2w, ndb, hbuf, N, 128, 128, 128, 2);

    // 3) xcur = relu(gru_cell(h, x1))  -> xc
    gru(hbuf, x1, g0wih16, g0whh16, g0bih, g0bhh, xc);

    // 4) GAT layers (xp stored f16)
    const float* xcur = xc;
    float* xnext = x1;
    for (int l = 0; l < 2; ++l) {
        gemm16(xcur, gatw + (size_t)l * 128 * 128, pH, N, 128, 128, 128);
        node_dots_k<<<N, 128, 0, stream>>>(pH, gatas + l * 128, gatad + l * 128, ssrc, sdst);
        gat_gather_k<<<N, 128, 0, stream>>>(rowptr, csr_src, ssrc, sdst, pH,
                                            gatb + l * 128, hbuf);
        gru(hbuf, xcur, gwih16 + (size_t)l * 49152, gwhh16 + (size_t)l * 49152,
            gbih + l * 384, gbhh + l * 384, xnext);
        const float* t = xcur; xcur = xnext; xnext = (float*)t;
    }

    // 5) readout
    hipMemsetAsync(agg, 0, (size_t)G * 128 * 4, stream);
    agg_k<<<nb(N * 128), 256, 0, stream>>>(xcur, batch, agg, N * 128);
    bias_act_k<<<nb(G * 128), 256, 0, stream>>>(agg, nullptr, oA, G * 128, 3);

    // 6) T=2 GIN+LSTM refinement
    float* cur = oA; float* nxt = oB;
    for (int t = 0; t < 2; ++t) {
        add_k<<<nb(G * 128), 256, 0, stream>>>(cur, agg, tGA, G * 128);
        gemm(tGA, ginw, ginb, hgb, G, 128, 128, 128, 2);
        gemm(cur, lwih, lbih, g1b, G, 128, 512, 128, 0);
        gemm(hgb, lwhh, lbhh, g2b, G, 128, 512, 128, 0);
        lstm_combine_k<<<nb(G * 128), 256, 0, stream>>>(g1b, g2b, hgb, nxt, G * 128);
        float* tmp = cur; cur = nxt; nxt = tmp;
    }

    // 7) y = out @ lin2_w^T + lin2_b
    final_k<<<G, 128, 0, stream>>>(cur, l2w, l2b, outp);
}

// Round 7
// 958.954 us; speedup vs baseline: 2.5392x; 1.0297x over previous
//
#include <hip/hip_runtime.h>
#include <cstdint>
#include <cmath>

// Problem constants (from reference):
#define NN 50000
#define EE 500000
#define GG 2000
// IN=64, H=128, ED=16, OUT=1, NUM_GAT=2, T=2

#define DEV __device__ __forceinline__

typedef __attribute__((ext_vector_type(8))) short short8;     // 8 bf16 (4 VGPRs)
typedef __attribute__((ext_vector_type(4))) float floatx4;
typedef __attribute__((ext_vector_type(4))) unsigned short ushort4v;
typedef _Float16 half2v __attribute__((ext_vector_type(2)));
typedef _Float16 half4v __attribute__((ext_vector_type(4)));
typedef _Float16 half8v __attribute__((ext_vector_type(8)));

DEV float sigf(float x) { return 1.f / (1.f + expf(-x)); }

DEV float actf(float x, int act) {
    if (act == 1) return x >= 0.f ? x : 0.01f * x;        // leaky 0.01
    if (act == 2) return x > 0.f ? x : expf(x) - 1.f;     // elu
    if (act == 3) return x > 0.f ? x : 0.f;               // relu
    return x;
}

// fp32 -> bf16 round-to-nearest-even
DEV unsigned short f2bf(float f) {
    unsigned u = __float_as_uint(f);
    u += 0x7FFFu + ((u >> 16) & 1u);
    return (unsigned short)(u >> 16);
}

DEV float hdot2(half2v a, half2v b, float c) {
#if __has_builtin(__builtin_amdgcn_fdot2)
    return __builtin_amdgcn_fdot2(a, b, c, false);
#else
    return c + (float)a[0] * (float)b[0] + (float)a[1] * (float)b[1];
#endif
}

#define H2(v, i) __builtin_shufflevector(v, v, 2 * (i), 2 * (i) + 1)

// ---------------------------------------------------------------------------
// MFMA GEMM: C[M,Nout] = act(A[M,K] @ W[Nout,K]^T + bias), fp32 in/out,
// bf16 MFMA compute. K in {64,128}, Nout % 64 == 0. Block 256/4 waves, 64x64.
// ---------------------------------------------------------------------------
__global__ __launch_bounds__(256) void gemm_mfma_k(
    const float* __restrict__ A, const float* __restrict__ W,
    const float* __restrict__ bias, float* __restrict__ C,
    int M, int K, int Nout, int wpitch, int act)
{
    __shared__ unsigned short Als[64 * 136];
    __shared__ unsigned short Bls[64 * 136];
    const int tid = threadIdx.x;
    const int bm = blockIdx.y * 64;
    const int bn = blockIdx.x * 64;

    const int ks = (K == 128) ? 7 : 6;
    const int km = K - 1;
    const int nvec = (64 * K) >> 2;
    for (int i = tid; i < nvec; i += 256) {
        const int e4 = i << 2;
        const int r = e4 >> ks;
        const int c = e4 & km;
        float4 av = make_float4(0.f, 0.f, 0.f, 0.f);
        if (bm + r < M) av = *(const float4*)(A + (size_t)(bm + r) * K + c);
        ushort4v ua;
        ua[0] = f2bf(av.x); ua[1] = f2bf(av.y); ua[2] = f2bf(av.z); ua[3] = f2bf(av.w);
        *(ushort4v*)(Als + r * 136 + c) = ua;
        const float4 wv = *(const float4*)(W + (size_t)(bn + r) * wpitch + c);
        ushort4v uw;
        uw[0] = f2bf(wv.x); uw[1] = f2bf(wv.y); uw[2] = f2bf(wv.z); uw[3] = f2bf(wv.w);
        *(ushort4v*)(Bls + r * 136 + c) = uw;
    }
    __syncthreads();

    const int wave = tid >> 6;
    const int lane = tid & 63;
    const int wr = (wave >> 1) * 32;
    const int wc = (wave & 1) * 32;
    const int l15 = lane & 15;
    const int quad = lane >> 4;

    floatx4 acc00 = {}, acc01 = {}, acc10 = {}, acc11 = {};
    for (int k0 = 0; k0 < K; k0 += 32) {
        const short8 a0 = *(const short8*)(Als + (wr + l15) * 136 + k0 + quad * 8);
        const short8 a1 = *(const short8*)(Als + (wr + 16 + l15) * 136 + k0 + quad * 8);
        const short8 b0 = *(const short8*)(Bls + (wc + l15) * 136 + k0 + quad * 8);
        const short8 b1 = *(const short8*)(Bls + (wc + 16 + l15) * 136 + k0 + quad * 8);
        acc00 = __builtin_amdgcn_mfma_f32_16x16x32_bf16(a0, b0, acc00, 0, 0, 0);
        acc01 = __builtin_amdgcn_mfma_f32_16x16x32_bf16(a0, b1, acc01, 0, 0, 0);
        acc10 = __builtin_amdgcn_mfma_f32_16x16x32_bf16(a1, b0, acc10, 0, 0, 0);
        acc11 = __builtin_amdgcn_mfma_f32_16x16x32_bf16(a1, b1, acc11, 0, 0, 0);
    }

    const floatx4* accs[4] = { &acc00, &acc01, &acc10, &acc11 };
#pragma unroll
    for (int r = 0; r < 2; ++r) {
#pragma unroll
        for (int c = 0; c < 2; ++c) {
            const floatx4 a = *accs[r * 2 + c];
            const int n = bn + wc + c * 16 + l15;
            const float bv = bias ? bias[n] : 0.f;
#pragma unroll
            for (int i = 0; i < 4; ++i) {
                const int m = bm + wr + r * 16 + quad * 4 + i;
                if (m < M) C[(size_t)m * Nout + n] = actf(a[i] + bv, act);
            }
        }
    }
}

// Same GEMM but f16 output (for gather tables p / xp), no bias.
__global__ __launch_bounds__(256) void gemm_mfma_o16_k(
    const float* __restrict__ A, const float* __restrict__ W,
    _Float16* __restrict__ C, int M, int K, int Nout, int wpitch)
{
    __shared__ unsigned short Als[64 * 136];
    __shared__ unsigned short Bls[64 * 136];
    const int tid = threadIdx.x;
    const int bm = blockIdx.y * 64;
    const int bn = blockIdx.x * 64;

    const int ks = (K == 128) ? 7 : 6;
    const int km = K - 1;
    const int nvec = (64 * K) >> 2;
    for (int i = tid; i < nvec; i += 256) {
        const int e4 = i << 2;
        const int r = e4 >> ks;
        const int c = e4 & km;
        float4 av = make_float4(0.f, 0.f, 0.f, 0.f);
        if (bm + r < M) av = *(const float4*)(A + (size_t)(bm + r) * K + c);
        ushort4v ua;
        ua[0] = f2bf(av.x); ua[1] = f2bf(av.y); ua[2] = f2bf(av.z); ua[3] = f2bf(av.w);
        *(ushort4v*)(Als + r * 136 + c) = ua;
        const float4 wv = *(const float4*)(W + (size_t)(bn + r) * wpitch + c);
        ushort4v uw;
        uw[0] = f2bf(wv.x); uw[1] = f2bf(wv.y); uw[2] = f2bf(wv.z); uw[3] = f2bf(wv.w);
        *(ushort4v*)(Bls + r * 136 + c) = uw;
    }
    __syncthreads();

    const int wave = tid >> 6;
    const int lane = tid & 63;
    const int wr = (wave >> 1) * 32;
    const int wc = (wave & 1) * 32;
    const int l15 = lane & 15;
    const int quad = lane >> 4;

    floatx4 acc00 = {}, acc01 = {}, acc10 = {}, acc11 = {};
    for (int k0 = 0; k0 < K; k0 += 32) {
        const short8 a0 = *(const short8*)(Als + (wr + l15) * 136 + k0 + quad * 8);
        const short8 a1 = *(const short8*)(Als + (wr + 16 + l15) * 136 + k0 + quad * 8);
        const short8 b0 = *(const short8*)(Bls + (wc + l15) * 136 + k0 + quad * 8);
        const short8 b1 = *(const short8*)(Bls + (wc + 16 + l15) * 136 + k0 + quad * 8);
        acc00 = __builtin_amdgcn_mfma_f32_16x16x32_bf16(a0, b0, acc00, 0, 0, 0);
        acc01 = __builtin_amdgcn_mfma_f32_16x16x32_bf16(a0, b1, acc01, 0, 0, 0);
        acc10 = __builtin_amdgcn_mfma_f32_16x16x32_bf16(a1, b0, acc10, 0, 0, 0);
        acc11 = __builtin_amdgcn_mfma_f32_16x16x32_bf16(a1, b1, acc11, 0, 0, 0);
    }

    const floatx4* accs[4] = { &acc00, &acc01, &acc10, &acc11 };
#pragma unroll
    for (int r = 0; r < 2; ++r) {
#pragma unroll
        for (int c = 0; c < 2; ++c) {
            const floatx4 a = *accs[r * 2 + c];
            const int n = bn + wc + c * 16 + l15;
#pragma unroll
            for (int i = 0; i < 4; ++i) {
                const int m = bm + wr + r * 16 + quad * 4 + i;
                if (m < M) C[(size_t)m * Nout + n] = (_Float16)a[i];
            }
        }
    }
}

// ---------------------------------------------------------------------------
// Fused GRU v3: 32-row blocks, column-split waves for 2x grid parallelism.
// Block = 256 thr / 4 waves: wave = (colhalf<<1)|rowgrp. Each wave: 16 rows
// (rowgrp) x 4 col-tiles (colhalf). x/h staged once in LDS (17.4 KB bf16,
// stride 136 conflict-free). Weights bf16 from global (L1/L2-hot). acc[6]
// per col-tile kept in registers, ci-loop NOT unrolled (VGPR<64 => 32-wave
// occupancy class). Grid 1563 blocks (~6 blocks/CU vs R6's 3).
// ---------------------------------------------------------------------------
__global__ __launch_bounds__(256) void gru_fused2_k(
    const float* __restrict__ xin, const float* __restrict__ hin,
    const unsigned short* __restrict__ wih16, const unsigned short* __restrict__ whh16,
    const float* __restrict__ bih, const float* __restrict__ bhh,
    float* __restrict__ xout, int M)
{
    __shared__ unsigned short sX[32 * 136];
    __shared__ unsigned short sH[32 * 136];

    const int tid = threadIdx.x;
    const int bm = blockIdx.x * 32;

    // ---- stage xin/hin (32x128, fp32 -> bf16), rows >= M zeroed ----
    for (int i = tid; i < 1024; i += 256) {
        const int e4 = i << 2;
        const int r = e4 >> 7;
        const int c = e4 & 127;
        const int m = bm + r;
        float4 xv = make_float4(0.f, 0.f, 0.f, 0.f);
        float4 hv = make_float4(0.f, 0.f, 0.f, 0.f);
        if (m < M) {
            xv = *(const float4*)(xin + (size_t)m * 128 + c);
            hv = *(const float4*)(hin + (size_t)m * 128 + c);
        }
        ushort4v ux, uh;
        ux[0] = f2bf(xv.x); ux[1] = f2bf(xv.y); ux[2] = f2bf(xv.z); ux[3] = f2bf(xv.w);
        uh[0] = f2bf(hv.x); uh[1] = f2bf(hv.y); uh[2] = f2bf(hv.z); uh[3] = f2bf(hv.w);
        *(ushort4v*)(sX + r * 136 + c) = ux;
        *(ushort4v*)(sH + r * 136 + c) = uh;
    }
    __syncthreads();

    const int wave = tid >> 6;
    const int lane = tid & 63;
    const int l15 = lane & 15;
    const int quad = lane >> 4;
    const int rbase = (wave & 1) * 16;      // row group within 32-row block
    const int ct0 = (wave >> 1) * 4;        // col-tile range [ct0, ct0+4)

    for (int ci = 0; ci < 4; ++ci) {
        const int j0 = (ct0 + ci) * 16;
        floatx4 acc[6] = {};                // [0..2]=gi r,z,n  [3..5]=gh r,z,n
#pragma unroll
        for (int k0 = 0; k0 < 128; k0 += 32) {
            const short8 ax = *(const short8*)(sX + (rbase + l15) * 136 + k0 + quad * 8);
            const short8 ah = *(const short8*)(sH + (rbase + l15) * 136 + k0 + quad * 8);
#pragma unroll
            for (int g = 0; g < 3; ++g) {
                const short8 bi = *(const short8*)(wih16 + (size_t)(g * 128 + j0 + l15) * 128 + k0 + quad * 8);
                const short8 bh = *(const short8*)(whh16 + (size_t)(g * 128 + j0 + l15) * 128 + k0 + quad * 8);
                acc[g]     = __builtin_amdgcn_mfma_f32_16x16x32_bf16(ax, bi, acc[g], 0, 0, 0);
                acc[3 + g] = __builtin_amdgcn_mfma_f32_16x16x32_bf16(ah, bh, acc[3 + g], 0, 0, 0);
            }
        }
        const int j = j0 + l15;
        const float bir = bih[j],       bhr = bhh[j];
        const float biz = bih[128 + j], bhz = bhh[128 + j];
        const float bin = bih[256 + j], bhn = bhh[256 + j];
#pragma unroll
        for (int i = 0; i < 4; ++i) {
            const int m = bm + rbase + quad * 4 + i;
            if (m >= M) continue;
            const float rg = sigf(acc[0][i] + bir + acc[3][i] + bhr);
            const float zg = sigf(acc[1][i] + biz + acc[4][i] + bhz);
            const float ng = tanhf(acc[2][i] + bin + rg * (acc[5][i] + bhn));
            const float hp = hin[(size_t)m * 128 + j];
            const float v = (1.f - zg) * ng + zg * hp;
            xout[(size_t)m * 128 + j] = v > 0.f ? v : 0.f;
        }
    }
}

// ---------------------------------------------------------------------------
// CSR build (dst-sorted), rebuilt every launch (stateless).
// ---------------------------------------------------------------------------
__global__ void hist_k(const int* __restrict__ ei, int* __restrict__ deg, int E)
{
    int e = blockIdx.x * 256 + threadIdx.x;
    if (e >= E) return;
    atomicAdd(deg + ei[E + e], 1);
}

__global__ __launch_bounds__(1024) void scan_k(const int* __restrict__ deg,
                                               int* __restrict__ rowptr, int n)
{
    __shared__ int buf[1024];
    __shared__ int sc;
    const int t = threadIdx.x;
    if (t == 0) sc = 0;
    __syncthreads();
    for (int base = 0; base < n; base += 1024) {
        int idx = base + t;
        int v = (idx < n) ? deg[idx] : 0;
        buf[t] = v;
        __syncthreads();
#pragma unroll
        for (int off = 1; off < 1024; off <<= 1) {
            int add = (t >= off) ? buf[t - off] : 0;
            __syncthreads();
            buf[t] += add;
            __syncthreads();
        }
        if (idx < n) rowptr[idx] = sc + buf[t] - v;
        __syncthreads();
        if (t == 0) sc += buf[1023];
        __syncthreads();
    }
    if (t == 0) rowptr[n] = sc;
}

__global__ void fill_csr_k(const int* __restrict__ ei, const int* __restrict__ rowptr,
                           int* __restrict__ cursor, int* __restrict__ csr_src,
                           int* __restrict__ csr_eid, int E)
{
    int e = blockIdx.x * 256 + threadIdx.x;
    if (e >= E) return;
    int s = ei[e], d = ei[E + e];
    int pos = atomicAdd(cursor + d, 1);
    int slot = rowptr[d] + pos;
    csr_src[slot] = s;
    csr_eid[slot] = e;
}

// fp32 -> bf16 elementwise (GRU weights)
__global__ void cvt_bf16_k(const float* __restrict__ in, unsigned short* __restrict__ outp, int n)
{
    int gid = blockIdx.x * 256 + threadIdx.x;
    if (gid >= n) return;
    outp[gid] = f2bf(in[gid]);
}

// fp32 -> f16 elementwise
__global__ void cvt_f16_k(const float* __restrict__ in, _Float16* __restrict__ outp, int n)
{
    int gid = blockIdx.x * 256 + threadIdx.x;
    if (gid >= n) return;
    outp[gid] = (_Float16)in[gid];
}

// nd_lin1_w[:,128:144] (pitch 144) -> f16 table [128][16]
__global__ void cvt_ndw_k(const float* __restrict__ ndw, _Float16* __restrict__ outp)
{
    int t = blockIdx.x * 256 + threadIdx.x;
    if (t >= 2048) return;
    int r = t >> 4, k = t & 15;
    outp[r * 16 + k] = (_Float16)ndw[r * 144 + 128 + k];
}

// ---------------------------------------------------------------------------
// nd_conv gather v3 (f16 + fdot2): out[d,h] = sum_e leaky(p[src,h]+ea[e].W1b[h])
// ---------------------------------------------------------------------------
__global__ __launch_bounds__(128) void nd_gather_k(
    const int* __restrict__ rowptr, const int* __restrict__ csr_src,
    const int* __restrict__ csr_eid, const _Float16* __restrict__ eaH,
    const _Float16* __restrict__ wH, const _Float16* __restrict__ pH,
    float* __restrict__ outp)
{
    const int d = blockIdx.x;
    const int t = threadIdx.x;   // feature 0..127
    const half8v w0 = *(const half8v*)(wH + t * 16);
    const half8v w1 = *(const half8v*)(wH + t * 16 + 8);

    const int b0 = rowptr[d], b1 = rowptr[d + 1];
    float acc = 0.f;
    for (int i = b0; i < b1; ++i) {
        const int s = csr_src[i], e = csr_eid[i];
        const half8v e0 = *(const half8v*)(eaH + (size_t)e * 16);
        const half8v e1 = *(const half8v*)(eaH + (size_t)e * 16 + 8);
        float q = 0.f;
        q = hdot2(H2(e0, 0), H2(w0, 0), q);
        q = hdot2(H2(e0, 1), H2(w0, 1), q);
        q = hdot2(H2(e0, 2), H2(w0, 2), q);
        q = hdot2(H2(e0, 3), H2(w0, 3), q);
        q = hdot2(H2(e1, 0), H2(w1, 0), q);
        q = hdot2(H2(e1, 1), H2(w1, 1), q);
        q = hdot2(H2(e1, 2), H2(w1, 2), q);
        q = hdot2(H2(e1, 3), H2(w1, 3), q);
        const float v = (float)pH[(size_t)s * 128 + t] + q;
        acc += v >= 0.f ? v : 0.01f * v;
    }
    outp[(size_t)d * 128 + t] = acc;
}

// per-node dots (f16 xp): ssrc[n] = xp[n].asrc, sdst[n] = xp[n].adst
__global__ void node_dots_k(const _Float16* __restrict__ xp,
                            const float* __restrict__ asrc,
                            const float* __restrict__ adst,
                            float* __restrict__ ssrc, float* __restrict__ sdst)
{
    int n = blockIdx.x, t = threadIdx.x;   // 128 threads
    float v = (float)xp[(size_t)n * 128 + t];
    float a = v * asrc[t];
    float b = v * adst[t];
    for (int off = 32; off; off >>= 1) { a += __shfl_down(a, off); b += __shfl_down(b, off); }
    __shared__ float sa[2], sb[2];
    if ((t & 63) == 0) { sa[t >> 6] = a; sb[t >> 6] = b; }
    __syncthreads();
    if (t == 0) { ssrc[n] = sa[0] + sa[1]; sdst[n] = sb[0] + sb[1]; }
}

// ---------------------------------------------------------------------------
// Fused GAT aggregation v3: exact softmax; weighted gather with 4 parallel
// edge-groups x 32 feature-quads (8B f16 loads, 4 loads in flight).
// ---------------------------------------------------------------------------
__global__ __launch_bounds__(128) void gat_gather_k(
    const int* __restrict__ rowptr, const int* __restrict__ csr_src,
    const float* __restrict__ ssrc, const float* __restrict__ sdst,
    const _Float16* __restrict__ xp, const float* __restrict__ bias,
    float* __restrict__ outp)
{
    const int d = blockIdx.x;
    const int t = threadIdx.x;
    __shared__ float red[128];
    __shared__ float lw[128];
    __shared__ int   ls[128];
    __shared__ float racc[4][128];

    const int b0 = rowptr[d], b1 = rowptr[d + 1];
    const int deg = b1 - b0;
    const float sdd = sdst[d];

    // pass A: exact segment max
    float lm = -INFINITY;
    for (int i = b0 + t; i < b1; i += 128) {
        float a = ssrc[csr_src[i]] + sdd;
        a = a >= 0.f ? a : 0.01f * a;
        lm = fmaxf(lm, a);
    }
    red[t] = lm;
    __syncthreads();
#pragma unroll
    for (int off = 64; off; off >>= 1) {
        if (t < off) red[t] = fmaxf(red[t], red[t + off]);
        __syncthreads();
    }
    const float amax = red[0];
    __syncthreads();

    // pass B: weights + gather (4 edge-groups x 32 feature-quads)
    const int g  = t >> 5;       // 0..3
    const int fq = t & 31;       // feature quad -> features 4fq..4fq+3
    float4 acc = make_float4(0.f, 0.f, 0.f, 0.f);
    float dpart = 0.f;
    for (int base = b0; base < b1; base += 128) {
        const int len = min(128, b1 - base);
        if (t < len) {
            const int s = csr_src[base + t];
            float a = ssrc[s] + sdd;
            a = a >= 0.f ? a : 0.01f * a;
            const float w = expf(a - amax);
            lw[t] = w;
            ls[t] = s;
            dpart += w;
        }
        __syncthreads();
        for (int j = 0; j < len; j += 4) {
            const int jj = j + g;
            if (jj < len) {
                const float w = lw[jj];
                const half4v hv = *(const half4v*)(xp + (size_t)ls[jj] * 128 + fq * 4);
                acc.x += w * (float)hv[0];
                acc.y += w * (float)hv[1];
                acc.z += w * (float)hv[2];
                acc.w += w * (float)hv[3];
            }
        }
        __syncthreads();
    }

    // denom
    red[t] = dpart;
    __syncthreads();
#pragma unroll
    for (int off = 64; off; off >>= 1) {
        if (t < off) red[t] += red[t + off];
        __syncthreads();
    }
    const float denom = red[0];

    // cross-group reduce
    racc[g][fq * 4 + 0] = acc.x;
    racc[g][fq * 4 + 1] = acc.y;
    racc[g][fq * 4 + 2] = acc.z;
    racc[g][fq * 4 + 3] = acc.w;
    __syncthreads();

    const float s4 = racc[0][t] + racc[1][t] + racc[2][t] + racc[3][t];
    float v = (deg > 0 ? s4 / denom : 0.f) + bias[t];
    outp[(size_t)d * 128 + t] = v > 0.f ? v : expf(v) - 1.f;   // elu
}

// out[i] = act(in[i] + bias[i % 128])   (bias may be null)
__global__ void bias_act_k(const float* __restrict__ in, const float* __restrict__ bias,
                           float* __restrict__ outp, int total, int act)
{
    int gid = blockIdx.x * 256 + threadIdx.x;
    if (gid >= total) return;
    float v = in[gid];
    if (bias) v += bias[gid & 127];
    outp[gid] = actf(v, act);
}

__global__ void agg_k(const float* __restrict__ xin, const int* __restrict__ batch,
                      float* __restrict__ agg, int total)
{
    int gid = blockIdx.x * 256 + threadIdx.x;
    if (gid >= total) return;
    int n = gid >> 7, j = gid & 127;
    atomicAdd(agg + batch[n] * 128 + j, xin[gid]);
}

__global__ void add_k(const float* __restrict__ a, const float* __restrict__ b,
                      float* __restrict__ c, int total)
{
    int gid = blockIdx.x * 256 + threadIdx.x;
    if (gid >= total) return;
    c[gid] = a[gid] + b[gid];
}

__global__ void lstm_combine_k(const float* __restrict__ g1, const float* __restrict__ g2,
                               const float* __restrict__ hg, float* __restrict__ outp, int total)
{
    int gid = blockIdx.x * 256 + threadIdx.x;
    if (gid >= total) return;
    int g = gid >> 7, j = gid & 127;
    const float* a = g1 + g * 512;
    const float* b = g2 + g * 512;
    float ii = a[j]       + b[j];
    float ff = a[j + 128] + b[j + 128];
    float gg = a[j + 256] + b[j + 256];
    float oo = a[j + 384] + b[j + 384];
    float c  = hg[gid];
    float c2 = sigf(ff) * c + sigf(ii) * tanhf(gg);
    outp[gid] = sigf(oo) * tanhf(c2);
}

__global__ void final_k(const float* __restrict__ oin, const float* __restrict__ w,
                        const float* __restrict__ b, float* __restrict__ y)
{
    int g = blockIdx.x, t = threadIdx.x;  // 128 threads
    float v = oin[g * 128 + t] * w[t];
    for (int off = 32; off; off >>= 1) v += __shfl_down(v, off);
    __shared__ float s2[2];
    if ((t & 63) == 0) s2[t >> 6] = v;
    __syncthreads();
    if (t == 0) y[g] = s2[0] + s2[1] + b[0];
}

// ---------------------------------------------------------------------------

extern "C" void kernel_launch(void* const* d_in, const int* in_sizes, int n_in,
                              void* d_out, int out_size, void* d_ws, size_t ws_size,
                              hipStream_t stream)
{
    const float* x      = (const float*)d_in[0];
    const int*   ei     = (const int*)  d_in[1];
    const float* ea     = (const float*)d_in[2];
    const int*   batch  = (const int*)  d_in[3];
    const float* lin1_w = (const float*)d_in[4];
    const float* lin1_b = (const float*)d_in[5];
    const float* nd1w   = (const float*)d_in[6];
    const float* nd2w   = (const float*)d_in[7];
    const float* ndb    = (const float*)d_in[8];
    const float* g0wih  = (const float*)d_in[9];
    const float* g0whh  = (const float*)d_in[10];
    const float* g0bih  = (const float*)d_in[11];
    const float* g0bhh  = (const float*)d_in[12];
    const float* gatw   = (const float*)d_in[13];
    const float* gatas  = (const float*)d_in[14];
    const float* gatad  = (const float*)d_in[15];
    const float* gatb   = (const float*)d_in[16];
    const float* gwih   = (const float*)d_in[17];
    const float* gwhh   = (const float*)d_in[18];
    const float* gbih   = (const float*)d_in[19];
    const float* gbhh   = (const float*)d_in[20];
    const float* ginw   = (const float*)d_in[21];
    const float* ginb   = (const float*)d_in[22];
    const float* lwih   = (const float*)d_in[23];
    const float* lwhh   = (const float*)d_in[24];
    const float* lbih   = (const float*)d_in[25];
    const float* lbhh   = (const float*)d_in[26];
    const float* l2w    = (const float*)d_in[27];
    const float* l2b    = (const float*)d_in[28];
    float* outp = (float*)d_out;

    const int N = NN, E = EE, G = GG;

    float* ws = (float*)d_ws;
    size_t off = 0;
    auto alloc = [&](size_t n) {
        float* r = ws + off;
        off += (n + 63) & ~(size_t)63;
        return r;
    };
    float* x1   = alloc((size_t)N * 128);
    float* hbuf = alloc((size_t)N * 128);
    float* accb = alloc((size_t)N * 128);
    float* xc   = alloc((size_t)N * 128);
    _Float16* pH  = (_Float16*)alloc((size_t)N * 64);   // N*128 f16 (p, then xp)
    _Float16* eaH = (_Float16*)alloc((size_t)E * 8);    // E*16 f16
    _Float16* ndwH = (_Float16*)alloc(1024);            // 128*16 f16
    float* ssrc = alloc((size_t)N);
    float* sdst = alloc((size_t)N);
    float* agg  = alloc((size_t)G * 128);
    float* oA   = alloc((size_t)G * 128);
    float* oB   = alloc((size_t)G * 128);
    float* hgb  = alloc((size_t)G * 128);
    float* tGA  = alloc((size_t)G * 128);
    float* g1b  = alloc((size_t)G * 512);
    float* g2b  = alloc((size_t)G * 512);
    unsigned short* g0wih16 = (unsigned short*)alloc(49152 / 2);
    unsigned short* g0whh16 = (unsigned short*)alloc(49152 / 2);
    unsigned short* gwih16  = (unsigned short*)alloc(98304 / 2);
    unsigned short* gwhh16  = (unsigned short*)alloc(98304 / 2);
    int* deg     = (int*)alloc((size_t)N);
    int* rowptr  = (int*)alloc((size_t)N + 1);
    int* cursor  = (int*)alloc((size_t)N);
    int* csr_src = (int*)alloc((size_t)E);
    int* csr_eid = (int*)alloc((size_t)E);
    (void)ws_size;

    auto gemm = [&](const float* A, const float* W, const float* bias, float* C,
                    int M, int K, int Nout, int wpitch, int act) {
        dim3 grid(Nout / 64, (M + 63) / 64);
        gemm_mfma_k<<<grid, 256, 0, stream>>>(A, W, bias, C, M, K, Nout, wpitch, act);
    };
    auto gemm16 = [&](const float* A, const float* W, _Float16* C,
                      int M, int K, int Nout, int wpitch) {
        dim3 grid(Nout / 64, (M + 63) / 64);
        gemm_mfma_o16_k<<<grid, 256, 0, stream>>>(A, W, C, M, K, Nout, wpitch);
    };
    auto nb = [](int n) { return (n + 255) / 256; };

    auto gru = [&](const float* xin, const float* hin,
                   const unsigned short* wih16, const unsigned short* whh16,
                   const float* bih, const float* bhh, float* xout) {
        gru_fused2_k<<<(N + 31) / 32, 256, 0, stream>>>(
            xin, hin, wih16, whh16, bih, bhh, xout, N);
    };

    // 0) CSR build + f16/bf16 conversions
    hipMemsetAsync(deg, 0, (size_t)N * 4, stream);
    hipMemsetAsync(cursor, 0, (size_t)N * 4, stream);
    hist_k<<<nb(E), 256, 0, stream>>>(ei, deg, E);
    scan_k<<<1, 1024, 0, stream>>>(deg, rowptr, N);
    fill_csr_k<<<nb(E), 256, 0, stream>>>(ei, rowptr, cursor, csr_src, csr_eid, E);
    cvt_f16_k<<<nb(E * 16), 256, 0, stream>>>(ea, eaH, E * 16);
    cvt_ndw_k<<<8, 256, 0, stream>>>(nd1w, ndwH);
    cvt_bf16_k<<<nb(49152), 256, 0, stream>>>(g0wih, g0wih16, 49152);
    cvt_bf16_k<<<nb(49152), 256, 0, stream>>>(g0whh, g0whh16, 49152);
    cvt_bf16_k<<<nb(98304), 256, 0, stream>>>(gwih, gwih16, 98304);
    cvt_bf16_k<<<nb(98304), 256, 0, stream>>>(gwhh, gwhh16, 98304);

    // 1) x1 = leaky(x @ lin1_w^T + lin1_b)
    gemm(x, lin1_w, lin1_b, x1, N, 64, 128, 64, 1);

    // 2) nd_conv (W2 hoisted out of segment_sum); p stored f16
    gemm16(x1, nd1w, pH, N, 128, 128, 144);
    nd_gather_k<<<N, 128, 0, stream>>>(rowptr, csr_src, csr_eid, eaH, ndwH, pH, accb);
    gemm(accb, nd2w, ndb, hbuf, N, 128, 128, 128, 2);

    // 3) xcur = relu(gru_cell(h, x1))  -> xc
    gru(hbuf, x1, g0wih16, g0whh16, g0bih, g0bhh, xc);

    // 4) GAT layers (xp stored f16)
    const float* xcur = xc;
    float* xnext = x1;
    for (int l = 0; l < 2; ++l) {
        gemm16(xcur, gatw + (size_t)l * 128 * 128, pH, N, 128, 128, 128);
        node_dots_k<<<N, 128, 0, stream>>>(pH, gatas + l * 128, gatad + l * 128, ssrc, sdst);
        gat_gather_k<<<N, 128, 0, stream>>>(rowptr, csr_src, ssrc, sdst, pH,
                                            gatb + l * 128, hbuf);
        gru(hbuf, xcur, gwih16 + (size_t)l * 49152, gwhh16 + (size_t)l * 49152,
            gbih + l * 384, gbhh + l * 384, xnext);
        const float* t = xcur; xcur = xnext; xnext = (float*)t;
    }

    // 5) readout
    hipMemsetAsync(agg, 0, (size_t)G * 128 * 4, stream);
    agg_k<<<nb(N * 128), 256, 0, stream>>>(xcur, batch, agg, N * 128);
    bias_act_k<<<nb(G * 128), 256, 0, stream>>>(agg, nullptr, oA, G * 128, 3);

    // 6) T=2 GIN+LSTM refinement
    float* cur = oA; float* nxt = oB;
    for (int t = 0; t < 2; ++t) {
        add_k<<<nb(G * 128), 256, 0, stream>>>(cur, agg, tGA, G * 128);
        gemm(tGA, ginw, ginb, hgb, G, 128, 128, 128, 2);
        gemm(cur, lwih, lbih, g1b, G, 128, 512, 128, 0);
        gemm(hgb, lwhh, lbhh, g2b, G, 128, 512, 128, 0);
        lstm_combine_k<<<nb(G * 128), 256, 0, stream>>>(g1b, g2b, hgb, nxt, G * 128);
        float* tmp = cur; cur = nxt; nxt = tmp;
    }

    // 7) y = out @ lin2_w^T + lin2_b
    final_k<<<G, 128, 0, stream>>>(cur, l2w, l2b, outp);
}

// Round 8
// 856.494 us; speedup vs baseline: 2.8429x; 1.1196x over previous
//
#include <hip/hip_runtime.h>
#include <cstdint>
#include <cmath>

// Problem constants (from reference):
#define NN 50000
#define EE 500000
#define GG 2000
// IN=64, H=128, ED=16, OUT=1, NUM_GAT=2, T=2

#define DEV __device__ __forceinline__

typedef __attribute__((ext_vector_type(8))) short short8;
typedef __attribute__((ext_vector_type(4))) float floatx4;
typedef __attribute__((ext_vector_type(4))) unsigned short ushort4v;
typedef _Float16 half2v __attribute__((ext_vector_type(2)));
typedef _Float16 half4v __attribute__((ext_vector_type(4)));
typedef _Float16 half8v __attribute__((ext_vector_type(8)));

DEV float sigf(float x) { return 1.f / (1.f + expf(-x)); }

DEV float actf(float x, int act) {
    if (act == 1) return x >= 0.f ? x : 0.01f * x;        // leaky 0.01
    if (act == 2) return x > 0.f ? x : expf(x) - 1.f;     // elu
    if (act == 3) return x > 0.f ? x : 0.f;               // relu
    return x;
}

// fp32 -> bf16 RNE (readout-path fp32 GEMM only)
DEV unsigned short f2bf(float f) {
    unsigned u = __float_as_uint(f);
    u += 0x7FFFu + ((u >> 16) & 1u);
    return (unsigned short)(u >> 16);
}

DEV float hdot2(half2v a, half2v b, float c) {
#if __has_builtin(__builtin_amdgcn_fdot2)
    return __builtin_amdgcn_fdot2(a, b, c, false);
#else
    return c + (float)a[0] * (float)b[0] + (float)a[1] * (float)b[1];
#endif
}

#define H2(v, i) __builtin_shufflevector(v, v, 2 * (i), 2 * (i) + 1)

// ---------------------------------------------------------------------------
// f16 MFMA GEMM: C[M,Nout] = act(A[M,K] @ W[Nout,K]^T + bias), f16 in/out,
// fp32 accum. A,W f16 (W packed pitch K). K in {64,128}. Block 256/4 waves,
// 64x64 tile. Staging = straight 16B copies (no cvt).
// ---------------------------------------------------------------------------
__global__ __launch_bounds__(256) void gemm_f16_k(
    const _Float16* __restrict__ A, const _Float16* __restrict__ W,
    const float* __restrict__ bias, _Float16* __restrict__ C,
    int M, int K, int Nout, int act)
{
    __shared__ unsigned short Als[64 * 136];
    __shared__ unsigned short Bls[64 * 136];
    const int tid = threadIdx.x;
    const int bm = blockIdx.y * 64;
    const int bn = blockIdx.x * 64;

    const int ks = (K == 128) ? 7 : 6;
    const int km = K - 1;
    const int nch = (64 * K) >> 3;          // 16B chunks
    for (int i = tid; i < nch; i += 256) {
        const int e8 = i << 3;
        const int r = e8 >> ks;
        const int c = e8 & km;
        short8 av = {};
        if (bm + r < M) av = *(const short8*)(A + (size_t)(bm + r) * K + c);
        *(short8*)(Als + r * 136 + c) = av;
        *(short8*)(Bls + r * 136 + c) = *(const short8*)(W + (size_t)(bn + r) * K + c);
    }
    __syncthreads();

    const int wave = tid >> 6;
    const int lane = tid & 63;
    const int wr = (wave >> 1) * 32;
    const int wc = (wave & 1) * 32;
    const int l15 = lane & 15;
    const int quad = lane >> 4;

    floatx4 acc00 = {}, acc01 = {}, acc10 = {}, acc11 = {};
    for (int k0 = 0; k0 < K; k0 += 32) {
        const half8v a0 = *(const half8v*)(Als + (wr + l15) * 136 + k0 + quad * 8);
        const half8v a1 = *(const half8v*)(Als + (wr + 16 + l15) * 136 + k0 + quad * 8);
        const half8v b0 = *(const half8v*)(Bls + (wc + l15) * 136 + k0 + quad * 8);
        const half8v b1 = *(const half8v*)(Bls + (wc + 16 + l15) * 136 + k0 + quad * 8);
        acc00 = __builtin_amdgcn_mfma_f32_16x16x32_f16(a0, b0, acc00, 0, 0, 0);
        acc01 = __builtin_amdgcn_mfma_f32_16x16x32_f16(a0, b1, acc01, 0, 0, 0);
        acc10 = __builtin_amdgcn_mfma_f32_16x16x32_f16(a1, b0, acc10, 0, 0, 0);
        acc11 = __builtin_amdgcn_mfma_f32_16x16x32_f16(a1, b1, acc11, 0, 0, 0);
    }

    const floatx4* accs[4] = { &acc00, &acc01, &acc10, &acc11 };
#pragma unroll
    for (int r = 0; r < 2; ++r) {
#pragma unroll
        for (int c = 0; c < 2; ++c) {
            const floatx4 a = *accs[r * 2 + c];
            const int n = bn + wc + c * 16 + l15;
            const float bv = bias ? bias[n] : 0.f;
#pragma unroll
            for (int i = 0; i < 4; ++i) {
                const int m = bm + wr + r * 16 + quad * 4 + i;
                if (m < M) C[(size_t)m * Nout + n] = (_Float16)actf(a[i] + bv, act);
            }
        }
    }
}

// ---------------------------------------------------------------------------
// fp32 MFMA GEMM (readout path only, G=2000 scale): unchanged from R7.
// ---------------------------------------------------------------------------
__global__ __launch_bounds__(256) void gemm_mfma_k(
    const float* __restrict__ A, const float* __restrict__ W,
    const float* __restrict__ bias, float* __restrict__ C,
    int M, int K, int Nout, int wpitch, int act)
{
    __shared__ unsigned short Als[64 * 136];
    __shared__ unsigned short Bls[64 * 136];
    const int tid = threadIdx.x;
    const int bm = blockIdx.y * 64;
    const int bn = blockIdx.x * 64;

    const int ks = (K == 128) ? 7 : 6;
    const int km = K - 1;
    const int nvec = (64 * K) >> 2;
    for (int i = tid; i < nvec; i += 256) {
        const int e4 = i << 2;
        const int r = e4 >> ks;
        const int c = e4 & km;
        float4 av = make_float4(0.f, 0.f, 0.f, 0.f);
        if (bm + r < M) av = *(const float4*)(A + (size_t)(bm + r) * K + c);
        ushort4v ua;
        ua[0] = f2bf(av.x); ua[1] = f2bf(av.y); ua[2] = f2bf(av.z); ua[3] = f2bf(av.w);
        *(ushort4v*)(Als + r * 136 + c) = ua;
        const float4 wv = *(const float4*)(W + (size_t)(bn + r) * wpitch + c);
        ushort4v uw;
        uw[0] = f2bf(wv.x); uw[1] = f2bf(wv.y); uw[2] = f2bf(wv.z); uw[3] = f2bf(wv.w);
        *(ushort4v*)(Bls + r * 136 + c) = uw;
    }
    __syncthreads();

    const int wave = tid >> 6;
    const int lane = tid & 63;
    const int wr = (wave >> 1) * 32;
    const int wc = (wave & 1) * 32;
    const int l15 = lane & 15;
    const int quad = lane >> 4;

    floatx4 acc00 = {}, acc01 = {}, acc10 = {}, acc11 = {};
    for (int k0 = 0; k0 < K; k0 += 32) {
        const short8 a0 = *(const short8*)(Als + (wr + l15) * 136 + k0 + quad * 8);
        const short8 a1 = *(const short8*)(Als + (wr + 16 + l15) * 136 + k0 + quad * 8);
        const short8 b0 = *(const short8*)(Bls + (wc + l15) * 136 + k0 + quad * 8);
        const short8 b1 = *(const short8*)(Bls + (wc + 16 + l15) * 136 + k0 + quad * 8);
        acc00 = __builtin_amdgcn_mfma_f32_16x16x32_bf16(a0, b0, acc00, 0, 0, 0);
        acc01 = __builtin_amdgcn_mfma_f32_16x16x32_bf16(a0, b1, acc01, 0, 0, 0);
        acc10 = __builtin_amdgcn_mfma_f32_16x16x32_bf16(a1, b0, acc10, 0, 0, 0);
        acc11 = __builtin_amdgcn_mfma_f32_16x16x32_bf16(a1, b1, acc11, 0, 0, 0);
    }

    const floatx4* accs[4] = { &acc00, &acc01, &acc10, &acc11 };
#pragma unroll
    for (int r = 0; r < 2; ++r) {
#pragma unroll
        for (int c = 0; c < 2; ++c) {
            const floatx4 a = *accs[r * 2 + c];
            const int n = bn + wc + c * 16 + l15;
            const float bv = bias ? bias[n] : 0.f;
#pragma unroll
            for (int i = 0; i < 4; ++i) {
                const int m = bm + wr + r * 16 + quad * 4 + i;
                if (m < M) C[(size_t)m * Nout + n] = actf(a[i] + bv, act);
            }
        }
    }
}

// ---------------------------------------------------------------------------
// Fused GRU v4 (f16): 32-row blocks, column-split waves (R7 mapping), f16
// x/h staged as straight copies, f16 weights from global (L2-hot), f16 MFMA.
// ---------------------------------------------------------------------------
__global__ __launch_bounds__(256) void gru_fused2_k(
    const _Float16* __restrict__ xin, const _Float16* __restrict__ hin,
    const _Float16* __restrict__ wih, const _Float16* __restrict__ whh,
    const float* __restrict__ bih, const float* __restrict__ bhh,
    _Float16* __restrict__ xout, int M)
{
    __shared__ unsigned short sX[32 * 136];
    __shared__ unsigned short sH[32 * 136];

    const int tid = threadIdx.x;
    const int bm = blockIdx.x * 32;

    for (int i = tid; i < 512; i += 256) {
        const int e8 = i << 3;
        const int r = e8 >> 7;
        const int c = e8 & 127;
        const int m = bm + r;
        short8 xv = {}, hv = {};
        if (m < M) {
            xv = *(const short8*)(xin + (size_t)m * 128 + c);
            hv = *(const short8*)(hin + (size_t)m * 128 + c);
        }
        *(short8*)(sX + r * 136 + c) = xv;
        *(short8*)(sH + r * 136 + c) = hv;
    }
    __syncthreads();

    const int wave = tid >> 6;
    const int lane = tid & 63;
    const int l15 = lane & 15;
    const int quad = lane >> 4;
    const int rbase = (wave & 1) * 16;
    const int ct0 = (wave >> 1) * 4;

    for (int ci = 0; ci < 4; ++ci) {
        const int j0 = (ct0 + ci) * 16;
        floatx4 acc[6] = {};
#pragma unroll
        for (int k0 = 0; k0 < 128; k0 += 32) {
            const half8v ax = *(const half8v*)(sX + (rbase + l15) * 136 + k0 + quad * 8);
            const half8v ah = *(const half8v*)(sH + (rbase + l15) * 136 + k0 + quad * 8);
#pragma unroll
            for (int g = 0; g < 3; ++g) {
                const half8v bi = *(const half8v*)(wih + (size_t)(g * 128 + j0 + l15) * 128 + k0 + quad * 8);
                const half8v bh = *(const half8v*)(whh + (size_t)(g * 128 + j0 + l15) * 128 + k0 + quad * 8);
                acc[g]     = __builtin_amdgcn_mfma_f32_16x16x32_f16(ax, bi, acc[g], 0, 0, 0);
                acc[3 + g] = __builtin_amdgcn_mfma_f32_16x16x32_f16(ah, bh, acc[3 + g], 0, 0, 0);
            }
        }
        const int j = j0 + l15;
        const float bir = bih[j],       bhr = bhh[j];
        const float biz = bih[128 + j], bhz = bhh[128 + j];
        const float bin = bih[256 + j], bhn = bhh[256 + j];
#pragma unroll
        for (int i = 0; i < 4; ++i) {
            const int m = bm + rbase + quad * 4 + i;
            if (m >= M) continue;
            const float rg = sigf(acc[0][i] + bir + acc[3][i] + bhr);
            const float zg = sigf(acc[1][i] + biz + acc[4][i] + bhz);
            const float ng = tanhf(acc[2][i] + bin + rg * (acc[5][i] + bhn));
            const float hp = (float)hin[(size_t)m * 128 + j];
            const float v = (1.f - zg) * ng + zg * hp;
            xout[(size_t)m * 128 + j] = (_Float16)(v > 0.f ? v : 0.f);
        }
    }
}

// ---------------------------------------------------------------------------
// CSR build: histogram + two-level scan + slot fill (stateless per launch).
// ---------------------------------------------------------------------------
__global__ void hist_k(const int* __restrict__ ei, int* __restrict__ deg, int E)
{
    int e = blockIdx.x * 256 + threadIdx.x;
    if (e >= E) return;
    atomicAdd(deg + ei[E + e], 1);
}

__global__ __launch_bounds__(1024) void scan_part_k(const int* __restrict__ deg,
                                                    int* __restrict__ bsum, int n)
{
    __shared__ int sh[1024];
    const int t = threadIdx.x;
    const int i = blockIdx.x * 1024 + t;
    sh[t] = (i < n) ? deg[i] : 0;
    __syncthreads();
#pragma unroll
    for (int off = 512; off; off >>= 1) {
        if (t < off) sh[t] += sh[t + off];
        __syncthreads();
    }
    if (t == 0) bsum[blockIdx.x] = sh[0];
}

__global__ void scan_tops_k(const int* __restrict__ bsum, int* __restrict__ boff,
                            int nb, int* __restrict__ rowptr, int n)
{
    if (threadIdx.x != 0 || blockIdx.x != 0) return;
    int run = 0;
    for (int b = 0; b < nb; ++b) { boff[b] = run; run += bsum[b]; }
    rowptr[n] = run;
}

__global__ __launch_bounds__(1024) void scan_final_k(const int* __restrict__ deg,
                                                     const int* __restrict__ boff,
                                                     int* __restrict__ rowptr, int n)
{
    __shared__ int sh[1024];
    const int t = threadIdx.x;
    const int i = blockIdx.x * 1024 + t;
    const int v = (i < n) ? deg[i] : 0;
    sh[t] = v;
    __syncthreads();
#pragma unroll
    for (int off = 1; off < 1024; off <<= 1) {
        int add = (t >= off) ? sh[t - off] : 0;
        __syncthreads();
        sh[t] += add;
        __syncthreads();
    }
    if (i < n) rowptr[i] = boff[blockIdx.x] + sh[t] - v;   // exclusive
}

__global__ void fill_csr_k(const int* __restrict__ ei, const int* __restrict__ rowptr,
                           int* __restrict__ cursor, int* __restrict__ csr_src,
                           int* __restrict__ csr_eid, int E)
{
    int e = blockIdx.x * 256 + threadIdx.x;
    if (e >= E) return;
    int s = ei[e], d = ei[E + e];
    int pos = atomicAdd(cursor + d, 1);
    int slot = rowptr[d] + pos;
    csr_src[slot] = s;
    csr_eid[slot] = e;
}

// ---------------------------------------------------------------------------
// Multi-segment fp32 -> f16 conversion (one dispatch for all flat tensors)
// ---------------------------------------------------------------------------
struct CvtSeg { const float* src; _Float16* dst; int n; };
struct CvtArgs { CvtSeg s[10]; int count; };

__global__ void cvt_multi_k(CvtArgs a)
{
    const int seg = blockIdx.y;
    if (seg >= a.count) return;
    const CvtSeg cs = a.s[seg];
    for (int i = blockIdx.x * 256 + threadIdx.x; i < cs.n; i += gridDim.x * 256)
        cs.dst[i] = (_Float16)cs.src[i];
}

// nd_lin1_w[:,0:128] (pitch 144) -> packed f16 [128][128]
__global__ void cvt_ndwA_k(const float* __restrict__ ndw, _Float16* __restrict__ outp)
{
    int t = blockIdx.x * 256 + threadIdx.x;
    if (t >= 16384) return;
    int r = t >> 7, c = t & 127;
    outp[r * 128 + c] = (_Float16)ndw[r * 144 + c];
}

// nd_lin1_w[:,128:144] (pitch 144) -> f16 table [128][16]
__global__ void cvt_ndwB_k(const float* __restrict__ ndw, _Float16* __restrict__ outp)
{
    int t = blockIdx.x * 256 + threadIdx.x;
    if (t >= 2048) return;
    int r = t >> 4, k = t & 15;
    outp[r * 16 + k] = (_Float16)ndw[r * 144 + 128 + k];
}

// ---------------------------------------------------------------------------
// nd_conv gather (f16 + fdot2): out f16
// ---------------------------------------------------------------------------
__global__ __launch_bounds__(128) void nd_gather_k(
    const int* __restrict__ rowptr, const int* __restrict__ csr_src,
    const int* __restrict__ csr_eid, const _Float16* __restrict__ eaH,
    const _Float16* __restrict__ wH, const _Float16* __restrict__ pH,
    _Float16* __restrict__ outp)
{
    const int d = blockIdx.x;
    const int t = threadIdx.x;
    const half8v w0 = *(const half8v*)(wH + t * 16);
    const half8v w1 = *(const half8v*)(wH + t * 16 + 8);

    const int b0 = rowptr[d], b1 = rowptr[d + 1];
    float acc = 0.f;
    for (int i = b0; i < b1; ++i) {
        const int s = csr_src[i], e = csr_eid[i];
        const half8v e0 = *(const half8v*)(eaH + (size_t)e * 16);
        const half8v e1 = *(const half8v*)(eaH + (size_t)e * 16 + 8);
        float q = 0.f;
        q = hdot2(H2(e0, 0), H2(w0, 0), q);
        q = hdot2(H2(e0, 1), H2(w0, 1), q);
        q = hdot2(H2(e0, 2), H2(w0, 2), q);
        q = hdot2(H2(e0, 3), H2(w0, 3), q);
        q = hdot2(H2(e1, 0), H2(w1, 0), q);
        q = hdot2(H2(e1, 1), H2(w1, 1), q);
        q = hdot2(H2(e1, 2), H2(w1, 2), q);
        q = hdot2(H2(e1, 3), H2(w1, 3), q);
        const float v = (float)pH[(size_t)s * 128 + t] + q;
        acc += v >= 0.f ? v : 0.01f * v;
    }
    outp[(size_t)d * 128 + t] = (_Float16)acc;
}

// per-node dots (f16 xp)
__global__ void node_dots_k(const _Float16* __restrict__ xp,
                            const float* __restrict__ asrc,
                            const float* __restrict__ adst,
                            float* __restrict__ ssrc, float* __restrict__ sdst)
{
    int n = blockIdx.x, t = threadIdx.x;   // 128 threads
    float v = (float)xp[(size_t)n * 128 + t];
    float a = v * asrc[t];
    float b = v * adst[t];
    for (int off = 32; off; off >>= 1) { a += __shfl_down(a, off); b += __shfl_down(b, off); }
    __shared__ float sa[2], sb[2];
    if ((t & 63) == 0) { sa[t >> 6] = a; sb[t >> 6] = b; }
    __syncthreads();
    if (t == 0) { ssrc[n] = sa[0] + sa[1]; sdst[n] = sb[0] + sb[1]; }
}

// ---------------------------------------------------------------------------
// Fused GAT aggregation (exact softmax; f16 xp gather; f16 out)
// ---------------------------------------------------------------------------
__global__ __launch_bounds__(128) void gat_gather_k(
    const int* __restrict__ rowptr, const int* __restrict__ csr_src,
    const float* __restrict__ ssrc, const float* __restrict__ sdst,
    const _Float16* __restrict__ xp, const float* __restrict__ bias,
    _Float16* __restrict__ outp)
{
    const int d = blockIdx.x;
    const int t = threadIdx.x;
    __shared__ float red[128];
    __shared__ float lw[128];
    __shared__ int   ls[128];
    __shared__ float racc[4][128];

    const int b0 = rowptr[d], b1 = rowptr[d + 1];
    const int deg = b1 - b0;
    const float sdd = sdst[d];

    float lm = -INFINITY;
    for (int i = b0 + t; i < b1; i += 128) {
        float a = ssrc[csr_src[i]] + sdd;
        a = a >= 0.f ? a : 0.01f * a;
        lm = fmaxf(lm, a);
    }
    red[t] = lm;
    __syncthreads();
#pragma unroll
    for (int off = 64; off; off >>= 1) {
        if (t < off) red[t] = fmaxf(red[t], red[t + off]);
        __syncthreads();
    }
    const float amax = red[0];
    __syncthreads();

    const int g  = t >> 5;
    const int fq = t & 31;
    float4 acc = make_float4(0.f, 0.f, 0.f, 0.f);
    float dpart = 0.f;
    for (int base = b0; base < b1; base += 128) {
        const int len = min(128, b1 - base);
        if (t < len) {
            const int s = csr_src[base + t];
            float a = ssrc[s] + sdd;
            a = a >= 0.f ? a : 0.01f * a;
            const float w = expf(a - amax);
            lw[t] = w;
            ls[t] = s;
            dpart += w;
        }
        __syncthreads();
        for (int j = 0; j < len; j += 4) {
            const int jj = j + g;
            if (jj < len) {
                const float w = lw[jj];
                const half4v hv = *(const half4v*)(xp + (size_t)ls[jj] * 128 + fq * 4);
                acc.x += w * (float)hv[0];
                acc.y += w * (float)hv[1];
                acc.z += w * (float)hv[2];
                acc.w += w * (float)hv[3];
            }
        }
        __syncthreads();
    }

    red[t] = dpart;
    __syncthreads();
#pragma unroll
    for (int off = 64; off; off >>= 1) {
        if (t < off) red[t] += red[t + off];
        __syncthreads();
    }
    const float denom = red[0];

    racc[g][fq * 4 + 0] = acc.x;
    racc[g][fq * 4 + 1] = acc.y;
    racc[g][fq * 4 + 2] = acc.z;
    racc[g][fq * 4 + 3] = acc.w;
    __syncthreads();

    const float s4 = racc[0][t] + racc[1][t] + racc[2][t] + racc[3][t];
    float v = (deg > 0 ? s4 / denom : 0.f) + bias[t];
    outp[(size_t)d * 128 + t] = (_Float16)(v > 0.f ? v : expf(v) - 1.f);   // elu
}

// out[i] = act(in[i] + bias)   fp32 (readout path)
__global__ void bias_act_k(const float* __restrict__ in, const float* __restrict__ bias,
                           float* __restrict__ outp, int total, int act)
{
    int gid = blockIdx.x * 256 + threadIdx.x;
    if (gid >= total) return;
    float v = in[gid];
    if (bias) v += bias[gid & 127];
    outp[gid] = actf(v, act);
}

__global__ void agg_k(const _Float16* __restrict__ xin, const int* __restrict__ batch,
                      float* __restrict__ agg, int total)
{
    int gid = blockIdx.x * 256 + threadIdx.x;
    if (gid >= total) return;
    int n = gid >> 7, j = gid & 127;
    atomicAdd(agg + batch[n] * 128 + j, (float)xin[gid]);
}

__global__ void add_k(const float* __restrict__ a, const float* __restrict__ b,
                      float* __restrict__ c, int total)
{
    int gid = blockIdx.x * 256 + threadIdx.x;
    if (gid >= total) return;
    c[gid] = a[gid] + b[gid];
}

__global__ void lstm_combine_k(const float* __restrict__ g1, const float* __restrict__ g2,
                               const float* __restrict__ hg, float* __restrict__ outp, int total)
{
    int gid = blockIdx.x * 256 + threadIdx.x;
    if (gid >= total) return;
    int g = gid >> 7, j = gid & 127;
    const float* a = g1 + g * 512;
    const float* b = g2 + g * 512;
    float ii = a[j]       + b[j];
    float ff = a[j + 128] + b[j + 128];
    float gg = a[j + 256] + b[j + 256];
    float oo = a[j + 384] + b[j + 384];
    float c  = hg[gid];
    float c2 = sigf(ff) * c + sigf(ii) * tanhf(gg);
    outp[gid] = sigf(oo) * tanhf(c2);
}

__global__ void final_k(const float* __restrict__ oin, const float* __restrict__ w,
                        const float* __restrict__ b, float* __restrict__ y)
{
    int g = blockIdx.x, t = threadIdx.x;  // 128 threads
    float v = oin[g * 128 + t] * w[t];
    for (int off = 32; off; off >>= 1) v += __shfl_down(v, off);
    __shared__ float s2[2];
    if ((t & 63) == 0) s2[t >> 6] = v;
    __syncthreads();
    if (t == 0) y[g] = s2[0] + s2[1] + b[0];
}

// ---------------------------------------------------------------------------

extern "C" void kernel_launch(void* const* d_in, const int* in_sizes, int n_in,
                              void* d_out, int out_size, void* d_ws, size_t ws_size,
                              hipStream_t stream)
{
    const float* x      = (const float*)d_in[0];
    const int*   ei     = (const int*)  d_in[1];
    const float* ea     = (const float*)d_in[2];
    const int*   batch  = (const int*)  d_in[3];
    const float* lin1_w = (const float*)d_in[4];
    const float* lin1_b = (const float*)d_in[5];
    const float* nd1w   = (const float*)d_in[6];
    const float* nd2w   = (const float*)d_in[7];
    const float* ndb    = (const float*)d_in[8];
    const float* g0wih  = (const float*)d_in[9];
    const float* g0whh  = (const float*)d_in[10];
    const float* g0bih  = (const float*)d_in[11];
    const float* g0bhh  = (const float*)d_in[12];
    const float* gatw   = (const float*)d_in[13];
    const float* gatas  = (const float*)d_in[14];
    const float* gatad  = (const float*)d_in[15];
    const float* gatb   = (const float*)d_in[16];
    const float* gwih   = (const float*)d_in[17];
    const float* gwhh   = (const float*)d_in[18];
    const float* gbih   = (const float*)d_in[19];
    const float* gbhh   = (const float*)d_in[20];
    const float* ginw   = (const float*)d_in[21];
    const float* ginb   = (const float*)d_in[22];
    const float* lwih   = (const float*)d_in[23];
    const float* lwhh   = (const float*)d_in[24];
    const float* lbih   = (const float*)d_in[25];
    const float* lbhh   = (const float*)d_in[26];
    const float* l2w    = (const float*)d_in[27];
    const float* l2b    = (const float*)d_in[28];
    float* outp = (float*)d_out;

    const int N = NN, E = EE, G = GG;

    float* ws = (float*)d_ws;
    size_t off = 0;
    auto alloc = [&](size_t n) {
        float* r = ws + off;
        off += (n + 63) & ~(size_t)63;
        return r;
    };
    // f16 node pipeline (sizes in floats = halves/2)
    _Float16* xH    = (_Float16*)alloc((size_t)N * 32);   // N*64
    _Float16* x1H   = (_Float16*)alloc((size_t)N * 64);   // N*128 (ping)
    _Float16* hbufH = (_Float16*)alloc((size_t)N * 64);
    _Float16* accbH = (_Float16*)alloc((size_t)N * 64);
    _Float16* xcH   = (_Float16*)alloc((size_t)N * 64);   // (pong)
    _Float16* pH    = (_Float16*)alloc((size_t)N * 64);
    _Float16* eaH   = (_Float16*)alloc((size_t)E * 8);    // E*16
    // f16 weights
    _Float16* lin1_wH = (_Float16*)alloc(4096);           // 128x64
    _Float16* nd1wAH  = (_Float16*)alloc(8192);           // 128x128
    _Float16* ndwBH   = (_Float16*)alloc(1024);           // 128x16
    _Float16* nd2wH   = (_Float16*)alloc(8192);
    _Float16* g0wihH  = (_Float16*)alloc(24576);
    _Float16* g0whhH  = (_Float16*)alloc(24576);
    _Float16* gwihH   = (_Float16*)alloc(49152);          // 2 layers
    _Float16* gwhhH   = (_Float16*)alloc(49152);
    _Float16* gatwH   = (_Float16*)alloc(16384);          // 2 layers
    // fp32 readout scratch
    float* ssrc = alloc((size_t)N);
    float* sdst = alloc((size_t)N);
    float* agg  = alloc((size_t)G * 128);
    float* oA   = alloc((size_t)G * 128);
    float* oB   = alloc((size_t)G * 128);
    float* hgb  = alloc((size_t)G * 128);
    float* tGA  = alloc((size_t)G * 128);
    float* g1b  = alloc((size_t)G * 512);
    float* g2b  = alloc((size_t)G * 512);
    // CSR
    int* deg     = (int*)alloc((size_t)N);
    int* rowptr  = (int*)alloc((size_t)N + 1);
    int* cursor  = (int*)alloc((size_t)N);
    int* bsum    = (int*)alloc(64);
    int* boff    = (int*)alloc(64);
    int* csr_src = (int*)alloc((size_t)E);
    int* csr_eid = (int*)alloc((size_t)E);
    (void)ws_size;

    auto gemmh = [&](const _Float16* A, const _Float16* W, const float* bias,
                     _Float16* C, int M, int K, int Nout, int act) {
        dim3 grid(Nout / 64, (M + 63) / 64);
        gemm_f16_k<<<grid, 256, 0, stream>>>(A, W, bias, C, M, K, Nout, act);
    };
    auto gemmf = [&](const float* A, const float* W, const float* bias, float* C,
                     int M, int K, int Nout, int wpitch, int act) {
        dim3 grid(Nout / 64, (M + 63) / 64);
        gemm_mfma_k<<<grid, 256, 0, stream>>>(A, W, bias, C, M, K, Nout, wpitch, act);
    };
    auto nb = [](int n) { return (n + 255) / 256; };

    auto gru = [&](const _Float16* xin, const _Float16* hin,
                   const _Float16* wih, const _Float16* whh,
                   const float* bih, const float* bhh, _Float16* xout) {
        gru_fused2_k<<<(N + 31) / 32, 256, 0, stream>>>(
            xin, hin, wih, whh, bih, bhh, xout, N);
    };

    // 0) CSR build + all f16 conversions
    hipMemsetAsync(deg, 0, (size_t)N * 4, stream);
    hipMemsetAsync(cursor, 0, (size_t)N * 4, stream);
    hist_k<<<nb(E), 256, 0, stream>>>(ei, deg, E);
    const int nblk = (N + 1023) / 1024;   // 49
    scan_part_k<<<nblk, 1024, 0, stream>>>(deg, bsum, N);
    scan_tops_k<<<1, 64, 0, stream>>>(bsum, boff, nblk, rowptr, N);
    scan_final_k<<<nblk, 1024, 0, stream>>>(deg, boff, rowptr, N);
    fill_csr_k<<<nb(E), 256, 0, stream>>>(ei, rowptr, cursor, csr_src, csr_eid, E);

    CvtArgs ca;
    ca.s[0] = { ea,     eaH,     E * 16 };
    ca.s[1] = { x,      xH,      N * 64 };
    ca.s[2] = { lin1_w, lin1_wH, 8192 };
    ca.s[3] = { nd2w,   nd2wH,   16384 };
    ca.s[4] = { g0wih,  g0wihH,  49152 };
    ca.s[5] = { g0whh,  g0whhH,  49152 };
    ca.s[6] = { gwih,   gwihH,   98304 };
    ca.s[7] = { gwhh,   gwhhH,   98304 };
    ca.s[8] = { gatw,   gatwH,   32768 };
    ca.count = 9;
    cvt_multi_k<<<dim3(2048, 9), 256, 0, stream>>>(ca);
    cvt_ndwA_k<<<64, 256, 0, stream>>>(nd1w, nd1wAH);
    cvt_ndwB_k<<<8, 256, 0, stream>>>(nd1w, ndwBH);

    // 1) x1 = leaky(x @ lin1_w^T + lin1_b)
    gemmh(xH, lin1_wH, lin1_b, x1H, N, 64, 128, 1);

    // 2) nd_conv (W2 hoisted): p = x1 @ W1a^T; gather; h = elu(acc @ W2^T + ndb)
    gemmh(x1H, nd1wAH, nullptr, pH, N, 128, 128, 0);
    nd_gather_k<<<N, 128, 0, stream>>>(rowptr, csr_src, csr_eid, eaH, ndwBH, pH, accbH);
    gemmh(accbH, nd2wH, ndb, hbufH, N, 128, 128, 2);

    // 3) xcur = relu(gru_cell(h, x1))
    gru(hbufH, x1H, g0wihH, g0whhH, g0bih, g0bhh, xcH);

    // 4) GAT layers
    const _Float16* xcur = xcH;
    _Float16* xnext = x1H;
    for (int l = 0; l < 2; ++l) {
        gemmh(xcur, gatwH + (size_t)l * 16384, nullptr, pH, N, 128, 128, 0);
        node_dots_k<<<N, 128, 0, stream>>>(pH, gatas + l * 128, gatad + l * 128, ssrc, sdst);
        gat_gather_k<<<N, 128, 0, stream>>>(rowptr, csr_src, ssrc, sdst, pH,
                                            gatb + l * 128, hbufH);
        gru(hbufH, xcur, gwihH + (size_t)l * 49152, gwhhH + (size_t)l * 49152,
            gbih + l * 384, gbhh + l * 384, xnext);
        const _Float16* t = xcur; xcur = xnext; xnext = (_Float16*)t;
    }

    // 5) readout
    hipMemsetAsync(agg, 0, (size_t)G * 128 * 4, stream);
    agg_k<<<nb(N * 128), 256, 0, stream>>>(xcur, batch, agg, N * 128);
    bias_act_k<<<nb(G * 128), 256, 0, stream>>>(agg, nullptr, oA, G * 128, 3);

    // 6) T=2 GIN+LSTM refinement (fp32, G-scale)
    float* cur = oA; float* nxt = oB;
    for (int t = 0; t < 2; ++t) {
        add_k<<<nb(G * 128), 256, 0, stream>>>(cur, agg, tGA, G * 128);
        gemmf(tGA, ginw, ginb, hgb, G, 128, 128, 128, 2);
        gemmf(cur, lwih, lbih, g1b, G, 128, 512, 128, 0);
        gemmf(hgb, lwhh, lbhh, g2b, G, 128, 512, 128, 0);
        lstm_combine_k<<<nb(G * 128), 256, 0, stream>>>(g1b, g2b, hgb, nxt, G * 128);
        float* tmp = cur; cur = nxt; nxt = tmp;
    }

    // 7) y = out @ lin2_w^T + lin2_b
    final_k<<<G, 128, 0, stream>>>(cur, l2w, l2b, outp);
}

// Round 9
// 805.559 us; speedup vs baseline: 3.0227x; 1.0632x over previous
//
#include <hip/hip_runtime.h>
#include <cstdint>
#include <cmath>

// Problem constants (from reference):
#define NN 50000
#define EE 500000
#define GG 2000
// IN=64, H=128, ED=16, OUT=1, NUM_GAT=2, T=2

#define DEV __device__ __forceinline__

typedef __attribute__((ext_vector_type(8))) short short8;
typedef __attribute__((ext_vector_type(4))) float floatx4;
typedef __attribute__((ext_vector_type(4))) unsigned short ushort4v;
typedef _Float16 half2v __attribute__((ext_vector_type(2)));
typedef _Float16 half4v __attribute__((ext_vector_type(4)));
typedef _Float16 half8v __attribute__((ext_vector_type(8)));

DEV float sigf(float x) { return 1.f / (1.f + expf(-x)); }

DEV float actf(float x, int act) {
    if (act == 1) return x >= 0.f ? x : 0.01f * x;        // leaky 0.01
    if (act == 2) return x > 0.f ? x : expf(x) - 1.f;     // elu
    if (act == 3) return x > 0.f ? x : 0.f;               // relu
    return x;
}

// fp32 -> bf16 RNE (readout-path fp32 GEMM only)
DEV unsigned short f2bf(float f) {
    unsigned u = __float_as_uint(f);
    u += 0x7FFFu + ((u >> 16) & 1u);
    return (unsigned short)(u >> 16);
}

DEV float hdot2(half2v a, half2v b, float c) {
#if __has_builtin(__builtin_amdgcn_fdot2)
    return __builtin_amdgcn_fdot2(a, b, c, false);
#else
    return c + (float)a[0] * (float)b[0] + (float)a[1] * (float)b[1];
#endif
}

#define H2(v, i) __builtin_shufflevector(v, v, 2 * (i), 2 * (i) + 1)

// ---------------------------------------------------------------------------
// f16 MFMA GEMM: C[M,Nout] = act(A[M,K] @ W[Nout,K]^T + bias), f16 in/out,
// fp32 accum. K in {64,128}. Block 256/4 waves, 64x64 tile.
// ---------------------------------------------------------------------------
__global__ __launch_bounds__(256) void gemm_f16_k(
    const _Float16* __restrict__ A, const _Float16* __restrict__ W,
    const float* __restrict__ bias, _Float16* __restrict__ C,
    int M, int K, int Nout, int act)
{
    __shared__ unsigned short Als[64 * 136];
    __shared__ unsigned short Bls[64 * 136];
    const int tid = threadIdx.x;
    const int bm = blockIdx.y * 64;
    const int bn = blockIdx.x * 64;

    const int ks = (K == 128) ? 7 : 6;
    const int km = K - 1;
    const int nch = (64 * K) >> 3;          // 16B chunks
    for (int i = tid; i < nch; i += 256) {
        const int e8 = i << 3;
        const int r = e8 >> ks;
        const int c = e8 & km;
        short8 av = {};
        if (bm + r < M) av = *(const short8*)(A + (size_t)(bm + r) * K + c);
        *(short8*)(Als + r * 136 + c) = av;
        *(short8*)(Bls + r * 136 + c) = *(const short8*)(W + (size_t)(bn + r) * K + c);
    }
    __syncthreads();

    const int wave = tid >> 6;
    const int lane = tid & 63;
    const int wr = (wave >> 1) * 32;
    const int wc = (wave & 1) * 32;
    const int l15 = lane & 15;
    const int quad = lane >> 4;

    floatx4 acc00 = {}, acc01 = {}, acc10 = {}, acc11 = {};
    for (int k0 = 0; k0 < K; k0 += 32) {
        const half8v a0 = *(const half8v*)(Als + (wr + l15) * 136 + k0 + quad * 8);
        const half8v a1 = *(const half8v*)(Als + (wr + 16 + l15) * 136 + k0 + quad * 8);
        const half8v b0 = *(const half8v*)(Bls + (wc + l15) * 136 + k0 + quad * 8);
        const half8v b1 = *(const half8v*)(Bls + (wc + 16 + l15) * 136 + k0 + quad * 8);
        acc00 = __builtin_amdgcn_mfma_f32_16x16x32_f16(a0, b0, acc00, 0, 0, 0);
        acc01 = __builtin_amdgcn_mfma_f32_16x16x32_f16(a0, b1, acc01, 0, 0, 0);
        acc10 = __builtin_amdgcn_mfma_f32_16x16x32_f16(a1, b0, acc10, 0, 0, 0);
        acc11 = __builtin_amdgcn_mfma_f32_16x16x32_f16(a1, b1, acc11, 0, 0, 0);
    }

    const floatx4* accs[4] = { &acc00, &acc01, &acc10, &acc11 };
#pragma unroll
    for (int r = 0; r < 2; ++r) {
#pragma unroll
        for (int c = 0; c < 2; ++c) {
            const floatx4 a = *accs[r * 2 + c];
            const int n = bn + wc + c * 16 + l15;
            const float bv = bias ? bias[n] : 0.f;
#pragma unroll
            for (int i = 0; i < 4; ++i) {
                const int m = bm + wr + r * 16 + quad * 4 + i;
                if (m < M) C[(size_t)m * Nout + n] = (_Float16)actf(a[i] + bv, act);
            }
        }
    }
}

// ---------------------------------------------------------------------------
// fp32 MFMA GEMM (readout path only, G=2000 scale)
// ---------------------------------------------------------------------------
__global__ __launch_bounds__(256) void gemm_mfma_k(
    const float* __restrict__ A, const float* __restrict__ W,
    const float* __restrict__ bias, float* __restrict__ C,
    int M, int K, int Nout, int wpitch, int act)
{
    __shared__ unsigned short Als[64 * 136];
    __shared__ unsigned short Bls[64 * 136];
    const int tid = threadIdx.x;
    const int bm = blockIdx.y * 64;
    const int bn = blockIdx.x * 64;

    const int ks = (K == 128) ? 7 : 6;
    const int km = K - 1;
    const int nvec = (64 * K) >> 2;
    for (int i = tid; i < nvec; i += 256) {
        const int e4 = i << 2;
        const int r = e4 >> ks;
        const int c = e4 & km;
        float4 av = make_float4(0.f, 0.f, 0.f, 0.f);
        if (bm + r < M) av = *(const float4*)(A + (size_t)(bm + r) * K + c);
        ushort4v ua;
        ua[0] = f2bf(av.x); ua[1] = f2bf(av.y); ua[2] = f2bf(av.z); ua[3] = f2bf(av.w);
        *(ushort4v*)(Als + r * 136 + c) = ua;
        const float4 wv = *(const float4*)(W + (size_t)(bn + r) * wpitch + c);
        ushort4v uw;
        uw[0] = f2bf(wv.x); uw[1] = f2bf(wv.y); uw[2] = f2bf(wv.z); uw[3] = f2bf(wv.w);
        *(ushort4v*)(Bls + r * 136 + c) = uw;
    }
    __syncthreads();

    const int wave = tid >> 6;
    const int lane = tid & 63;
    const int wr = (wave >> 1) * 32;
    const int wc = (wave & 1) * 32;
    const int l15 = lane & 15;
    const int quad = lane >> 4;

    floatx4 acc00 = {}, acc01 = {}, acc10 = {}, acc11 = {};
    for (int k0 = 0; k0 < K; k0 += 32) {
        const short8 a0 = *(const short8*)(Als + (wr + l15) * 136 + k0 + quad * 8);
        const short8 a1 = *(const short8*)(Als + (wr + 16 + l15) * 136 + k0 + quad * 8);
        const short8 b0 = *(const short8*)(Bls + (wc + l15) * 136 + k0 + quad * 8);
        const short8 b1 = *(const short8*)(Bls + (wc + 16 + l15) * 136 + k0 + quad * 8);
        acc00 = __builtin_amdgcn_mfma_f32_16x16x32_bf16(a0, b0, acc00, 0, 0, 0);
        acc01 = __builtin_amdgcn_mfma_f32_16x16x32_bf16(a0, b1, acc01, 0, 0, 0);
        acc10 = __builtin_amdgcn_mfma_f32_16x16x32_bf16(a1, b0, acc10, 0, 0, 0);
        acc11 = __builtin_amdgcn_mfma_f32_16x16x32_bf16(a1, b1, acc11, 0, 0, 0);
    }

    const floatx4* accs[4] = { &acc00, &acc01, &acc10, &acc11 };
#pragma unroll
    for (int r = 0; r < 2; ++r) {
#pragma unroll
        for (int c = 0; c < 2; ++c) {
            const floatx4 a = *accs[r * 2 + c];
            const int n = bn + wc + c * 16 + l15;
            const float bv = bias ? bias[n] : 0.f;
#pragma unroll
            for (int i = 0; i < 4; ++i) {
                const int m = bm + wr + r * 16 + quad * 4 + i;
                if (m < M) C[(size_t)m * Nout + n] = actf(a[i] + bv, act);
            }
        }
    }
}

// ---------------------------------------------------------------------------
// Fused GRU v5 (f16, register-cached weights): block = 64 rows / 4 waves.
// Each wave owns 2 col-tiles; per col-tile it preloads ALL 24 B-fragments
// (wih+whh, 96 VGPRs) once, then streams 4 row-fragments from LDS through
// 24 MFMAs each -- inner loop has ZERO global loads (fixes R8's 1:1
// load:MFMA L2-latency chain). Epilogue h_prev comes from staged sH.
// ---------------------------------------------------------------------------
__global__ __launch_bounds__(256) void gru_fused3_k(
    const _Float16* __restrict__ xin, const _Float16* __restrict__ hin,
    const _Float16* __restrict__ wih, const _Float16* __restrict__ whh,
    const float* __restrict__ bih, const float* __restrict__ bhh,
    _Float16* __restrict__ xout, int M)
{
    __shared__ unsigned short sX[64 * 136];
    __shared__ unsigned short sH[64 * 136];

    const int tid = threadIdx.x;
    const int bm = blockIdx.x * 64;

    // stage x/h (64x128 f16, straight copies; rows >= M zeroed)
    for (int i = tid; i < 1024; i += 256) {
        const int e8 = i << 3;
        const int r = e8 >> 7;
        const int c = e8 & 127;
        const int m = bm + r;
        short8 xv = {}, hv = {};
        if (m < M) {
            xv = *(const short8*)(xin + (size_t)m * 128 + c);
            hv = *(const short8*)(hin + (size_t)m * 128 + c);
        }
        *(short8*)(sX + r * 136 + c) = xv;
        *(short8*)(sH + r * 136 + c) = hv;
    }
    __syncthreads();

    const int wave = tid >> 6;
    const int lane = tid & 63;
    const int l15 = lane & 15;
    const int quad = lane >> 4;

    for (int ci = 0; ci < 2; ++ci) {
        const int j0 = (wave * 2 + ci) * 16;
        // ---- preload all B fragments for this col-tile into VGPRs ----
        half8v bi[4][3], bh[4][3];
#pragma unroll
        for (int k = 0; k < 4; ++k)
#pragma unroll
            for (int g = 0; g < 3; ++g) {
                bi[k][g] = *(const half8v*)(wih + (size_t)(g * 128 + j0 + l15) * 128 + k * 32 + quad * 8);
                bh[k][g] = *(const half8v*)(whh + (size_t)(g * 128 + j0 + l15) * 128 + k * 32 + quad * 8);
            }
        const int j = j0 + l15;
        const float bir = bih[j],       bhr = bhh[j];
        const float biz = bih[128 + j], bhz = bhh[128 + j];
        const float bin = bih[256 + j], bhn = bhh[256 + j];

#pragma unroll
        for (int rf = 0; rf < 4; ++rf) {
            floatx4 acc[6] = {};
#pragma unroll
            for (int k = 0; k < 4; ++k) {
                const half8v ax = *(const half8v*)(sX + (rf * 16 + l15) * 136 + k * 32 + quad * 8);
                const half8v ah = *(const half8v*)(sH + (rf * 16 + l15) * 136 + k * 32 + quad * 8);
#pragma unroll
                for (int g = 0; g < 3; ++g) {
                    acc[g]     = __builtin_amdgcn_mfma_f32_16x16x32_f16(ax, bi[k][g], acc[g], 0, 0, 0);
                    acc[3 + g] = __builtin_amdgcn_mfma_f32_16x16x32_f16(ah, bh[k][g], acc[3 + g], 0, 0, 0);
                }
            }
#pragma unroll
            for (int i = 0; i < 4; ++i) {
                const int m = bm + rf * 16 + quad * 4 + i;
                if (m >= M) continue;
                const float rg = sigf(acc[0][i] + bir + acc[3][i] + bhr);
                const float zg = sigf(acc[1][i] + biz + acc[4][i] + bhz);
                const float ng = tanhf(acc[2][i] + bin + rg * (acc[5][i] + bhn));
                const float hp = (float)((const _Float16*)sH)[(rf * 16 + quad * 4 + i) * 136 + j];
                const float v = (1.f - zg) * ng + zg * hp;
                xout[(size_t)m * 128 + j] = (_Float16)(v > 0.f ? v : 0.f);
            }
        }
    }
}

// ---------------------------------------------------------------------------
// CSR build: histogram + two-level scan + slot fill (stateless per launch).
// ---------------------------------------------------------------------------
__global__ void hist_k(const int* __restrict__ ei, int* __restrict__ deg, int E)
{
    int e = blockIdx.x * 256 + threadIdx.x;
    if (e >= E) return;
    atomicAdd(deg + ei[E + e], 1);
}

__global__ __launch_bounds__(1024) void scan_part_k(const int* __restrict__ deg,
                                                    int* __restrict__ bsum, int n)
{
    __shared__ int sh[1024];
    const int t = threadIdx.x;
    const int i = blockIdx.x * 1024 + t;
    sh[t] = (i < n) ? deg[i] : 0;
    __syncthreads();
#pragma unroll
    for (int off = 512; off; off >>= 1) {
        if (t < off) sh[t] += sh[t + off];
        __syncthreads();
    }
    if (t == 0) bsum[blockIdx.x] = sh[0];
}

__global__ void scan_tops_k(const int* __restrict__ bsum, int* __restrict__ boff,
                            int nb, int* __restrict__ rowptr, int n)
{
    if (threadIdx.x != 0 || blockIdx.x != 0) return;
    int run = 0;
    for (int b = 0; b < nb; ++b) { boff[b] = run; run += bsum[b]; }
    rowptr[n] = run;
}

__global__ __launch_bounds__(1024) void scan_final_k(const int* __restrict__ deg,
                                                     const int* __restrict__ boff,
                                                     int* __restrict__ rowptr, int n)
{
    __shared__ int sh[1024];
    const int t = threadIdx.x;
    const int i = blockIdx.x * 1024 + t;
    const int v = (i < n) ? deg[i] : 0;
    sh[t] = v;
    __syncthreads();
#pragma unroll
    for (int off = 1; off < 1024; off <<= 1) {
        int add = (t >= off) ? sh[t - off] : 0;
        __syncthreads();
        sh[t] += add;
        __syncthreads();
    }
    if (i < n) rowptr[i] = boff[blockIdx.x] + sh[t] - v;   // exclusive
}

__global__ void fill_csr_k(const int* __restrict__ ei, const int* __restrict__ rowptr,
                           int* __restrict__ cursor, int* __restrict__ csr_src,
                           int* __restrict__ csr_eid, int E)
{
    int e = blockIdx.x * 256 + threadIdx.x;
    if (e >= E) return;
    int s = ei[e], d = ei[E + e];
    int pos = atomicAdd(cursor + d, 1);
    int slot = rowptr[d] + pos;
    csr_src[slot] = s;
    csr_eid[slot] = e;
}

// ---------------------------------------------------------------------------
// Multi-segment fp32 -> f16 conversion (one dispatch for all flat tensors)
// ---------------------------------------------------------------------------
struct CvtSeg { const float* src; _Float16* dst; int n; };
struct CvtArgs { CvtSeg s[10]; int count; };

__global__ void cvt_multi_k(CvtArgs a)
{
    const int seg = blockIdx.y;
    if (seg >= a.count) return;
    const CvtSeg cs = a.s[seg];
    for (int i = blockIdx.x * 256 + threadIdx.x; i < cs.n; i += gridDim.x * 256)
        cs.dst[i] = (_Float16)cs.src[i];
}

// nd_lin1_w[:,0:128] (pitch 144) -> packed f16 [128][128]
__global__ void cvt_ndwA_k(const float* __restrict__ ndw, _Float16* __restrict__ outp)
{
    int t = blockIdx.x * 256 + threadIdx.x;
    if (t >= 16384) return;
    int r = t >> 7, c = t & 127;
    outp[r * 128 + c] = (_Float16)ndw[r * 144 + c];
}

// nd_lin1_w[:,128:144] (pitch 144) -> f16 table [128][16]
__global__ void cvt_ndwB_k(const float* __restrict__ ndw, _Float16* __restrict__ outp)
{
    int t = blockIdx.x * 256 + threadIdx.x;
    if (t >= 2048) return;
    int r = t >> 4, k = t & 15;
    outp[r * 16 + k] = (_Float16)ndw[r * 144 + 128 + k];
}

// ---------------------------------------------------------------------------
// nd_conv gather (f16 + fdot2): out f16
// ---------------------------------------------------------------------------
__global__ __launch_bounds__(128) void nd_gather_k(
    const int* __restrict__ rowptr, const int* __restrict__ csr_src,
    const int* __restrict__ csr_eid, const _Float16* __restrict__ eaH,
    const _Float16* __restrict__ wH, const _Float16* __restrict__ pH,
    _Float16* __restrict__ outp)
{
    const int d = blockIdx.x;
    const int t = threadIdx.x;
    const half8v w0 = *(const half8v*)(wH + t * 16);
    const half8v w1 = *(const half8v*)(wH + t * 16 + 8);

    const int b0 = rowptr[d], b1 = rowptr[d + 1];
    float acc = 0.f;
    for (int i = b0; i < b1; ++i) {
        const int s = csr_src[i], e = csr_eid[i];
        const half8v e0 = *(const half8v*)(eaH + (size_t)e * 16);
        const half8v e1 = *(const half8v*)(eaH + (size_t)e * 16 + 8);
        float q = 0.f;
        q = hdot2(H2(e0, 0), H2(w0, 0), q);
        q = hdot2(H2(e0, 1), H2(w0, 1), q);
        q = hdot2(H2(e0, 2), H2(w0, 2), q);
        q = hdot2(H2(e0, 3), H2(w0, 3), q);
        q = hdot2(H2(e1, 0), H2(w1, 0), q);
        q = hdot2(H2(e1, 1), H2(w1, 1), q);
        q = hdot2(H2(e1, 2), H2(w1, 2), q);
        q = hdot2(H2(e1, 3), H2(w1, 3), q);
        const float v = (float)pH[(size_t)s * 128 + t] + q;
        acc += v >= 0.f ? v : 0.01f * v;
    }
    outp[(size_t)d * 128 + t] = (_Float16)acc;
}

// per-node dots (f16 xp)
__global__ void node_dots_k(const _Float16* __restrict__ xp,
                            const float* __restrict__ asrc,
                            const float* __restrict__ adst,
                            float* __restrict__ ssrc, float* __restrict__ sdst)
{
    int n = blockIdx.x, t = threadIdx.x;   // 128 threads
    float v = (float)xp[(size_t)n * 128 + t];
    float a = v * asrc[t];
    float b = v * adst[t];
    for (int off = 32; off; off >>= 1) { a += __shfl_down(a, off); b += __shfl_down(b, off); }
    __shared__ float sa[2], sb[2];
    if ((t & 63) == 0) { sa[t >> 6] = a; sb[t >> 6] = b; }
    __syncthreads();
    if (t == 0) { ssrc[n] = sa[0] + sa[1]; sdst[n] = sb[0] + sb[1]; }
}

// ---------------------------------------------------------------------------
// Fused GAT aggregation (exact softmax; f16 xp gather; f16 out)
// ---------------------------------------------------------------------------
__global__ __launch_bounds__(128) void gat_gather_k(
    const int* __restrict__ rowptr, const int* __restrict__ csr_src,
    const float* __restrict__ ssrc, const float* __restrict__ sdst,
    const _Float16* __restrict__ xp, const float* __restrict__ bias,
    _Float16* __restrict__ outp)
{
    const int d = blockIdx.x;
    const int t = threadIdx.x;
    __shared__ float red[128];
    __shared__ float lw[128];
    __shared__ int   ls[128];
    __shared__ float racc[4][128];

    const int b0 = rowptr[d], b1 = rowptr[d + 1];
    const int deg = b1 - b0;
    const float sdd = sdst[d];

    float lm = -INFINITY;
    for (int i = b0 + t; i < b1; i += 128) {
        float a = ssrc[csr_src[i]] + sdd;
        a = a >= 0.f ? a : 0.01f * a;
        lm = fmaxf(lm, a);
    }
    red[t] = lm;
    __syncthreads();
#pragma unroll
    for (int off = 64; off; off >>= 1) {
        if (t < off) red[t] = fmaxf(red[t], red[t + off]);
        __syncthreads();
    }
    const float amax = red[0];
    __syncthreads();

    const int g  = t >> 5;
    const int fq = t & 31;
    float4 acc = make_float4(0.f, 0.f, 0.f, 0.f);
    float dpart = 0.f;
    for (int base = b0; base < b1; base += 128) {
        const int len = min(128, b1 - base);
        if (t < len) {
            const int s = csr_src[base + t];
            float a = ssrc[s] + sdd;
            a = a >= 0.f ? a : 0.01f * a;
            const float w = expf(a - amax);
            lw[t] = w;
            ls[t] = s;
            dpart += w;
        }
        __syncthreads();
        for (int j = 0; j < len; j += 4) {
            const int jj = j + g;
            if (jj < len) {
                const float w = lw[jj];
                const half4v hv = *(const half4v*)(xp + (size_t)ls[jj] * 128 + fq * 4);
                acc.x += w * (float)hv[0];
                acc.y += w * (float)hv[1];
                acc.z += w * (float)hv[2];
                acc.w += w * (float)hv[3];
            }
        }
        __syncthreads();
    }

    red[t] = dpart;
    __syncthreads();
#pragma unroll
    for (int off = 64; off; off >>= 1) {
        if (t < off) red[t] += red[t + off];
        __syncthreads();
    }
    const float denom = red[0];

    racc[g][fq * 4 + 0] = acc.x;
    racc[g][fq * 4 + 1] = acc.y;
    racc[g][fq * 4 + 2] = acc.z;
    racc[g][fq * 4 + 3] = acc.w;
    __syncthreads();

    const float s4 = racc[0][t] + racc[1][t] + racc[2][t] + racc[3][t];
    float v = (deg > 0 ? s4 / denom : 0.f) + bias[t];
    outp[(size_t)d * 128 + t] = (_Float16)(v > 0.f ? v : expf(v) - 1.f);   // elu
}

// out[i] = act(in[i] + bias)   fp32 (readout path)
__global__ void bias_act_k(const float* __restrict__ in, const float* __restrict__ bias,
                           float* __restrict__ outp, int total, int act)
{
    int gid = blockIdx.x * 256 + threadIdx.x;
    if (gid >= total) return;
    float v = in[gid];
    if (bias) v += bias[gid & 127];
    outp[gid] = actf(v, act);
}

__global__ void agg_k(const _Float16* __restrict__ xin, const int* __restrict__ batch,
                      float* __restrict__ agg, int total)
{
    int gid = blockIdx.x * 256 + threadIdx.x;
    if (gid >= total) return;
    int n = gid >> 7, j = gid & 127;
    atomicAdd(agg + batch[n] * 128 + j, (float)xin[gid]);
}

__global__ void add_k(const float* __restrict__ a, const float* __restrict__ b,
                      float* __restrict__ c, int total)
{
    int gid = blockIdx.x * 256 + threadIdx.x;
    if (gid >= total) return;
    c[gid] = a[gid] + b[gid];
}

__global__ void lstm_combine_k(const float* __restrict__ g1, const float* __restrict__ g2,
                               const float* __restrict__ hg, float* __restrict__ outp, int total)
{
    int gid = blockIdx.x * 256 + threadIdx.x;
    if (gid >= total) return;
    int g = gid >> 7, j = gid & 127;
    const float* a = g1 + g * 512;
    const float* b = g2 + g * 512;
    float ii = a[j]       + b[j];
    float ff = a[j + 128] + b[j + 128];
    float gg = a[j + 256] + b[j + 256];
    float oo = a[j + 384] + b[j + 384];
    float c  = hg[gid];
    float c2 = sigf(ff) * c + sigf(ii) * tanhf(gg);
    outp[gid] = sigf(oo) * tanhf(c2);
}

__global__ void final_k(const float* __restrict__ oin, const float* __restrict__ w,
                        const float* __restrict__ b, float* __restrict__ y)
{
    int g = blockIdx.x, t = threadIdx.x;  // 128 threads
    float v = oin[g * 128 + t] * w[t];
    for (int off = 32; off; off >>= 1) v += __shfl_down(v, off);
    __shared__ float s2[2];
    if ((t & 63) == 0) s2[t >> 6] = v;
    __syncthreads();
    if (t == 0) y[g] = s2[0] + s2[1] + b[0];
}

// ---------------------------------------------------------------------------

extern "C" void kernel_launch(void* const* d_in, const int* in_sizes, int n_in,
                              void* d_out, int out_size, void* d_ws, size_t ws_size,
                              hipStream_t stream)
{
    const float* x      = (const float*)d_in[0];
    const int*   ei     = (const int*)  d_in[1];
    const float* ea     = (const float*)d_in[2];
    const int*   batch  = (const int*)  d_in[3];
    const float* lin1_w = (const float*)d_in[4];
    const float* lin1_b = (const float*)d_in[5];
    const float* nd1w   = (const float*)d_in[6];
    const float* nd2w   = (const float*)d_in[7];
    const float* ndb    = (const float*)d_in[8];
    const float* g0wih  = (const float*)d_in[9];
    const float* g0whh  = (const float*)d_in[10];
    const float* g0bih  = (const float*)d_in[11];
    const float* g0bhh  = (const float*)d_in[12];
    const float* gatw   = (const float*)d_in[13];
    const float* gatas  = (const float*)d_in[14];
    const float* gatad  = (const float*)d_in[15];
    const float* gatb   = (const float*)d_in[16];
    const float* gwih   = (const float*)d_in[17];
    const float* gwhh   = (const float*)d_in[18];
    const float* gbih   = (const float*)d_in[19];
    const float* gbhh   = (const float*)d_in[20];
    const float* ginw   = (const float*)d_in[21];
    const float* ginb   = (const float*)d_in[22];
    const float* lwih   = (const float*)d_in[23];
    const float* lwhh   = (const float*)d_in[24];
    const float* lbih   = (const float*)d_in[25];
    const float* lbhh   = (const float*)d_in[26];
    const float* l2w    = (const float*)d_in[27];
    const float* l2b    = (const float*)d_in[28];
    float* outp = (float*)d_out;

    const int N = NN, E = EE, G = GG;

    float* ws = (float*)d_ws;
    size_t off = 0;
    auto alloc = [&](size_t n) {
        float* r = ws + off;
        off += (n + 63) & ~(size_t)63;
        return r;
    };
    // f16 node pipeline (sizes in floats = halves/2)
    _Float16* xH    = (_Float16*)alloc((size_t)N * 32);   // N*64
    _Float16* x1H   = (_Float16*)alloc((size_t)N * 64);   // N*128 (ping)
    _Float16* hbufH = (_Float16*)alloc((size_t)N * 64);
    _Float16* accbH = (_Float16*)alloc((size_t)N * 64);
    _Float16* xcH   = (_Float16*)alloc((size_t)N * 64);   // (pong)
    _Float16* pH    = (_Float16*)alloc((size_t)N * 64);
    _Float16* eaH   = (_Float16*)alloc((size_t)E * 8);    // E*16
    // f16 weights
    _Float16* lin1_wH = (_Float16*)alloc(4096);           // 128x64
    _Float16* nd1wAH  = (_Float16*)alloc(8192);           // 128x128
    _Float16* ndwBH   = (_Float16*)alloc(1024);           // 128x16
    _Float16* nd2wH   = (_Float16*)alloc(8192);
    _Float16* g0wihH  = (_Float16*)alloc(24576);
    _Float16* g0whhH  = (_Float16*)alloc(24576);
    _Float16* gwihH   = (_Float16*)alloc(49152);          // 2 layers
    _Float16* gwhhH   = (_Float16*)alloc(49152);
    _Float16* gatwH   = (_Float16*)alloc(16384);          // 2 layers
    // fp32 readout scratch
    float* ssrc = alloc((size_t)N);
    float* sdst = alloc((size_t)N);
    float* agg  = alloc((size_t)G * 128);
    float* oA   = alloc((size_t)G * 128);
    float* oB   = alloc((size_t)G * 128);
    float* hgb  = alloc((size_t)G * 128);
    float* tGA  = alloc((size_t)G * 128);
    float* g1b  = alloc((size_t)G * 512);
    float* g2b  = alloc((size_t)G * 512);
    // CSR
    int* deg     = (int*)alloc((size_t)N);
    int* rowptr  = (int*)alloc((size_t)N + 1);
    int* cursor  = (int*)alloc((size_t)N);
    int* bsum    = (int*)alloc(64);
    int* boff    = (int*)alloc(64);
    int* csr_src = (int*)alloc((size_t)E);
    int* csr_eid = (int*)alloc((size_t)E);
    (void)ws_size;

    auto gemmh = [&](const _Float16* A, const _Float16* W, const float* bias,
                     _Float16* C, int M, int K, int Nout, int act) {
        dim3 grid(Nout / 64, (M + 63) / 64);
        gemm_f16_k<<<grid, 256, 0, stream>>>(A, W, bias, C, M, K, Nout, act);
    };
    auto gemmf = [&](const float* A, const float* W, const float* bias, float* C,
                     int M, int K, int Nout, int wpitch, int act) {
        dim3 grid(Nout / 64, (M + 63) / 64);
        gemm_mfma_k<<<grid, 256, 0, stream>>>(A, W, bias, C, M, K, Nout, wpitch, act);
    };
    auto nb = [](int n) { return (n + 255) / 256; };

    auto gru = [&](const _Float16* xin, const _Float16* hin,
                   const _Float16* wih, const _Float16* whh,
                   const float* bih, const float* bhh, _Float16* xout) {
        gru_fused3_k<<<(N + 63) / 64, 256, 0, stream>>>(
            xin, hin, wih, whh, bih, bhh, xout, N);
    };

    // 0) CSR build + all f16 conversions
    hipMemsetAsync(deg, 0, (size_t)N * 4, stream);
    hipMemsetAsync(cursor, 0, (size_t)N * 4, stream);
    hist_k<<<nb(E), 256, 0, stream>>>(ei, deg, E);
    const int nblk = (N + 1023) / 1024;   // 49
    scan_part_k<<<nblk, 1024, 0, stream>>>(deg, bsum, N);
    scan_tops_k<<<1, 64, 0, stream>>>(bsum, boff, nblk, rowptr, N);
    scan_final_k<<<nblk, 1024, 0, stream>>>(deg, boff, rowptr, N);
    fill_csr_k<<<nb(E), 256, 0, stream>>>(ei, rowptr, cursor, csr_src, csr_eid, E);

    CvtArgs ca;
    ca.s[0] = { ea,     eaH,     E * 16 };
    ca.s[1] = { x,      xH,      N * 64 };
    ca.s[2] = { lin1_w, lin1_wH, 8192 };
    ca.s[3] = { nd2w,   nd2wH,   16384 };
    ca.s[4] = { g0wih,  g0wihH,  49152 };
    ca.s[5] = { g0whh,  g0whhH,  49152 };
    ca.s[6] = { gwih,   gwihH,   98304 };
    ca.s[7] = { gwhh,   gwhhH,   98304 };
    ca.s[8] = { gatw,   gatwH,   32768 };
    ca.count = 9;
    cvt_multi_k<<<dim3(2048, 9), 256, 0, stream>>>(ca);
    cvt_ndwA_k<<<64, 256, 0, stream>>>(nd1w, nd1wAH);
    cvt_ndwB_k<<<8, 256, 0, stream>>>(nd1w, ndwBH);

    // 1) x1 = leaky(x @ lin1_w^T + lin1_b)
    gemmh(xH, lin1_wH, lin1_b, x1H, N, 64, 128, 1);

    // 2) nd_conv (W2 hoisted): p = x1 @ W1a^T; gather; h = elu(acc @ W2^T + ndb)
    gemmh(x1H, nd1wAH, nullptr, pH, N, 128, 128, 0);
    nd_gather_k<<<N, 128, 0, stream>>>(rowptr, csr_src, csr_eid, eaH, ndwBH, pH, accbH);
    gemmh(accbH, nd2wH, ndb, hbufH, N, 128, 128, 2);

    // 3) xcur = relu(gru_cell(h, x1))
    gru(hbufH, x1H, g0wihH, g0whhH, g0bih, g0bhh, xcH);

    // 4) GAT layers
    const _Float16* xcur = xcH;
    _Float16* xnext = x1H;
    for (int l = 0; l < 2; ++l) {
        gemmh(xcur, gatwH + (size_t)l * 16384, nullptr, pH, N, 128, 128, 0);
        node_dots_k<<<N, 128, 0, stream>>>(pH, gatas + l * 128, gatad + l * 128, ssrc, sdst);
        gat_gather_k<<<N, 128, 0, stream>>>(rowptr, csr_src, ssrc, sdst, pH,
                                            gatb + l * 128, hbufH);
        gru(hbufH, xcur, gwihH + (size_t)l * 49152, gwhhH + (size_t)l * 49152,
            gbih + l * 384, gbhh + l * 384, xnext);
        const _Float16* t = xcur; xcur = xnext; xnext = (_Float16*)t;
    }

    // 5) readout
    hipMemsetAsync(agg, 0, (size_t)G * 128 * 4, stream);
    agg_k<<<nb(N * 128), 256, 0, stream>>>(xcur, batch, agg, N * 128);
    bias_act_k<<<nb(G * 128), 256, 0, stream>>>(agg, nullptr, oA, G * 128, 3);

    // 6) T=2 GIN+LSTM refinement (fp32, G-scale)
    float* cur = oA; float* nxt = oB;
    for (int t = 0; t < 2; ++t) {
        add_k<<<nb(G * 128), 256, 0, stream>>>(cur, agg, tGA, G * 128);
        gemmf(tGA, ginw, ginb, hgb, G, 128, 128, 128, 2);
        gemmf(cur, lwih, lbih, g1b, G, 128, 512, 128, 0);
        gemmf(hgb, lwhh, lbhh, g2b, G, 128, 512, 128, 0);
        lstm_combine_k<<<nb(G * 128), 256, 0, stream>>>(g1b, g2b, hgb, nxt, G * 128);
        float* tmp = cur; cur = nxt; nxt = tmp;
    }

    // 7) y = out @ lin2_w^T + lin2_b
    final_k<<<G, 128, 0, stream>>>(cur, l2w, l2b, outp);
}

// Round 10
// 696.713 us; speedup vs baseline: 3.4949x; 1.1562x over previous
//
#include <hip/hip_runtime.h>
#include <cstdint>
#include <cmath>

// Problem constants (from reference):
#define NN 50000
#define EE 500000
#define GG 2000
// IN=64, H=128, ED=16, OUT=1, NUM_GAT=2, T=2

#define DEV __device__ __forceinline__

typedef __attribute__((ext_vector_type(8))) short short8;
typedef __attribute__((ext_vector_type(4))) float floatx4;
typedef __attribute__((ext_vector_type(4))) unsigned short ushort4v;
typedef _Float16 half2v __attribute__((ext_vector_type(2)));
typedef _Float16 half4v __attribute__((ext_vector_type(4)));
typedef _Float16 half8v __attribute__((ext_vector_type(8)));

DEV float sigf(float x) { return 1.f / (1.f + expf(-x)); }

// fast overflow-safe sigmoid/tanh via hardware exp
DEV float fsig(float x) { return 1.f / (1.f + __expf(-x)); }
DEV float ftanh(float x) {
    const float e = __expf(-2.f * fabsf(x));   // in (0,1], never overflows
    const float t = (1.f - e) / (1.f + e);
    return x >= 0.f ? t : -t;
}

DEV float actf(float x, int act) {
    if (act == 1) return x >= 0.f ? x : 0.01f * x;          // leaky 0.01
    if (act == 2) return x > 0.f ? x : __expf(x) - 1.f;     // elu
    if (act == 3) return x > 0.f ? x : 0.f;                 // relu
    return x;
}

// fp32 -> bf16 RNE (readout-path fp32 GEMM only)
DEV unsigned short f2bf(float f) {
    unsigned u = __float_as_uint(f);
    u += 0x7FFFu + ((u >> 16) & 1u);
    return (unsigned short)(u >> 16);
}

DEV float hdot2(half2v a, half2v b, float c) {
#if __has_builtin(__builtin_amdgcn_fdot2)
    return __builtin_amdgcn_fdot2(a, b, c, false);
#else
    return c + (float)a[0] * (float)b[0] + (float)a[1] * (float)b[1];
#endif
}

#define H2(v, i) __builtin_shufflevector(v, v, 2 * (i), 2 * (i) + 1)

// ---------------------------------------------------------------------------
// f16 MFMA GEMM: C[M,Nout] = act(A[M,K] @ W[Nout,K]^T + bias), f16 in/out,
// fp32 accum. K in {64,128}. Block 256/4 waves, 64x64 tile.
// ---------------------------------------------------------------------------
__global__ __launch_bounds__(256) void gemm_f16_k(
    const _Float16* __restrict__ A, const _Float16* __restrict__ W,
    const float* __restrict__ bias, _Float16* __restrict__ C,
    int M, int K, int Nout, int act)
{
    __shared__ unsigned short Als[64 * 136];
    __shared__ unsigned short Bls[64 * 136];
    const int tid = threadIdx.x;
    const int bm = blockIdx.y * 64;
    const int bn = blockIdx.x * 64;

    const int ks = (K == 128) ? 7 : 6;
    const int km = K - 1;
    const int nch = (64 * K) >> 3;          // 16B chunks
    for (int i = tid; i < nch; i += 256) {
        const int e8 = i << 3;
        const int r = e8 >> ks;
        const int c = e8 & km;
        short8 av = {};
        if (bm + r < M) av = *(const short8*)(A + (size_t)(bm + r) * K + c);
        *(short8*)(Als + r * 136 + c) = av;
        *(short8*)(Bls + r * 136 + c) = *(const short8*)(W + (size_t)(bn + r) * K + c);
    }
    __syncthreads();

    const int wave = tid >> 6;
    const int lane = tid & 63;
    const int wr = (wave >> 1) * 32;
    const int wc = (wave & 1) * 32;
    const int l15 = lane & 15;
    const int quad = lane >> 4;

    floatx4 acc00 = {}, acc01 = {}, acc10 = {}, acc11 = {};
    for (int k0 = 0; k0 < K; k0 += 32) {
        const half8v a0 = *(const half8v*)(Als + (wr + l15) * 136 + k0 + quad * 8);
        const half8v a1 = *(const half8v*)(Als + (wr + 16 + l15) * 136 + k0 + quad * 8);
        const half8v b0 = *(const half8v*)(Bls + (wc + l15) * 136 + k0 + quad * 8);
        const half8v b1 = *(const half8v*)(Bls + (wc + 16 + l15) * 136 + k0 + quad * 8);
        acc00 = __builtin_amdgcn_mfma_f32_16x16x32_f16(a0, b0, acc00, 0, 0, 0);
        acc01 = __builtin_amdgcn_mfma_f32_16x16x32_f16(a0, b1, acc01, 0, 0, 0);
        acc10 = __builtin_amdgcn_mfma_f32_16x16x32_f16(a1, b0, acc10, 0, 0, 0);
        acc11 = __builtin_amdgcn_mfma_f32_16x16x32_f16(a1, b1, acc11, 0, 0, 0);
    }

    const floatx4* accs[4] = { &acc00, &acc01, &acc10, &acc11 };
#pragma unroll
    for (int r = 0; r < 2; ++r) {
#pragma unroll
        for (int c = 0; c < 2; ++c) {
            const floatx4 a = *accs[r * 2 + c];
            const int n = bn + wc + c * 16 + l15;
            const float bv = bias ? bias[n] : 0.f;
#pragma unroll
            for (int i = 0; i < 4; ++i) {
                const int m = bm + wr + r * 16 + quad * 4 + i;
                if (m < M) C[(size_t)m * Nout + n] = (_Float16)actf(a[i] + bv, act);
            }
        }
    }
}

// ---------------------------------------------------------------------------
// fp32 MFMA GEMM (readout path only, G=2000 scale)
// ---------------------------------------------------------------------------
__global__ __launch_bounds__(256) void gemm_mfma_k(
    const float* __restrict__ A, const float* __restrict__ W,
    const float* __restrict__ bias, float* __restrict__ C,
    int M, int K, int Nout, int wpitch, int act)
{
    __shared__ unsigned short Als[64 * 136];
    __shared__ unsigned short Bls[64 * 136];
    const int tid = threadIdx.x;
    const int bm = blockIdx.y * 64;
    const int bn = blockIdx.x * 64;

    const int ks = (K == 128) ? 7 : 6;
    const int km = K - 1;
    const int nvec = (64 * K) >> 2;
    for (int i = tid; i < nvec; i += 256) {
        const int e4 = i << 2;
        const int r = e4 >> ks;
        const int c = e4 & km;
        float4 av = make_float4(0.f, 0.f, 0.f, 0.f);
        if (bm + r < M) av = *(const float4*)(A + (size_t)(bm + r) * K + c);
        ushort4v ua;
        ua[0] = f2bf(av.x); ua[1] = f2bf(av.y); ua[2] = f2bf(av.z); ua[3] = f2bf(av.w);
        *(ushort4v*)(Als + r * 136 + c) = ua;
        const float4 wv = *(const float4*)(W + (size_t)(bn + r) * wpitch + c);
        ushort4v uw;
        uw[0] = f2bf(wv.x); uw[1] = f2bf(wv.y); uw[2] = f2bf(wv.z); uw[3] = f2bf(wv.w);
        *(ushort4v*)(Bls + r * 136 + c) = uw;
    }
    __syncthreads();

    const int wave = tid >> 6;
    const int lane = tid & 63;
    const int wr = (wave >> 1) * 32;
    const int wc = (wave & 1) * 32;
    const int l15 = lane & 15;
    const int quad = lane >> 4;

    floatx4 acc00 = {}, acc01 = {}, acc10 = {}, acc11 = {};
    for (int k0 = 0; k0 < K; k0 += 32) {
        const short8 a0 = *(const short8*)(Als + (wr + l15) * 136 + k0 + quad * 8);
        const short8 a1 = *(const short8*)(Als + (wr + 16 + l15) * 136 + k0 + quad * 8);
        const short8 b0 = *(const short8*)(Bls + (wc + l15) * 136 + k0 + quad * 8);
        const short8 b1 = *(const short8*)(Bls + (wc + 16 + l15) * 136 + k0 + quad * 8);
        acc00 = __builtin_amdgcn_mfma_f32_16x16x32_bf16(a0, b0, acc00, 0, 0, 0);
        acc01 = __builtin_amdgcn_mfma_f32_16x16x32_bf16(a0, b1, acc01, 0, 0, 0);
        acc10 = __builtin_amdgcn_mfma_f32_16x16x32_bf16(a1, b0, acc10, 0, 0, 0);
        acc11 = __builtin_amdgcn_mfma_f32_16x16x32_bf16(a1, b1, acc11, 0, 0, 0);
    }

    const floatx4* accs[4] = { &acc00, &acc01, &acc10, &acc11 };
#pragma unroll
    for (int r = 0; r < 2; ++r) {
#pragma unroll
        for (int c = 0; c < 2; ++c) {
            const floatx4 a = *accs[r * 2 + c];
            const int n = bn + wc + c * 16 + l15;
            const float bv = bias ? bias[n] : 0.f;
#pragma unroll
            for (int i = 0; i < 4; ++i) {
                const int m = bm + wr + r * 16 + quad * 4 + i;
                if (m < M) C[(size_t)m * Nout + n] = actf(a[i] + bv, act);
            }
        }
    }
}

// ---------------------------------------------------------------------------
// Fused GRU v6 (f16): block = 64 rows x 64 cols, grid.y=2 col-halves.
// Wave = 1 col-tile (16 cols) x all 4 row-frags. Loop k outer / rf inner:
// only 6 B-frags live per k-step (24 VGPR), accs = 4 gates x 4 rf (64 VGPR)
// using the rz-fusion (r,z gates accumulate x@wih + h@whh into ONE acc).
// VGPR <= 128 enforced -> 4 waves/SIMD (2x R9 occupancy). Fast exp epilogue.
// ---------------------------------------------------------------------------
__global__ __launch_bounds__(256, 4) void gru_fused4_k(
    const _Float16* __restrict__ xin, const _Float16* __restrict__ hin,
    const _Float16* __restrict__ wih, const _Float16* __restrict__ whh,
    const float* __restrict__ bih, const float* __restrict__ bhh,
    _Float16* __restrict__ xout, int M)
{
    __shared__ unsigned short sX[64 * 136];
    __shared__ unsigned short sH[64 * 136];

    const int tid = threadIdx.x;
    const int bm = blockIdx.x * 64;

    // stage x/h (64x128 f16, straight copies; rows >= M zeroed)
    for (int i = tid; i < 1024; i += 256) {
        const int e8 = i << 3;
        const int r = e8 >> 7;
        const int c = e8 & 127;
        const int m = bm + r;
        short8 xv = {}, hv = {};
        if (m < M) {
            xv = *(const short8*)(xin + (size_t)m * 128 + c);
            hv = *(const short8*)(hin + (size_t)m * 128 + c);
        }
        *(short8*)(sX + r * 136 + c) = xv;
        *(short8*)(sH + r * 136 + c) = hv;
    }
    __syncthreads();

    const int wave = tid >> 6;
    const int lane = tid & 63;
    const int l15 = lane & 15;
    const int quad = lane >> 4;
    const int j0 = (blockIdx.y * 4 + wave) * 16;   // this wave's col-tile
    const int j = j0 + l15;

    const float br  = bih[j] + bhh[j];             // rz-fused biases
    const float bz  = bih[128 + j] + bhh[128 + j];
    const float bni = bih[256 + j];
    const float bnh = bhh[256 + j];

    floatx4 aR[4] = {}, aZ[4] = {}, aNi[4] = {}, aNh[4] = {};

#pragma unroll
    for (int k = 0; k < 4; ++k) {
        const size_t wrow = (size_t)(j0 + l15) * 128 + k * 32 + quad * 8;
        const half8v wri = *(const half8v*)(wih + wrow);
        const half8v wzi = *(const half8v*)(wih + 128 * 128 + wrow);
        const half8v wni = *(const half8v*)(wih + 2 * 128 * 128 + wrow);
        const half8v wrh = *(const half8v*)(whh + wrow);
        const half8v wzh = *(const half8v*)(whh + 128 * 128 + wrow);
        const half8v wnh = *(const half8v*)(whh + 2 * 128 * 128 + wrow);
#pragma unroll
        for (int rf = 0; rf < 4; ++rf) {
            const half8v ax = *(const half8v*)(sX + (rf * 16 + l15) * 136 + k * 32 + quad * 8);
            const half8v ah = *(const half8v*)(sH + (rf * 16 + l15) * 136 + k * 32 + quad * 8);
            aR[rf]  = __builtin_amdgcn_mfma_f32_16x16x32_f16(ax, wri, aR[rf], 0, 0, 0);
            aR[rf]  = __builtin_amdgcn_mfma_f32_16x16x32_f16(ah, wrh, aR[rf], 0, 0, 0);
            aZ[rf]  = __builtin_amdgcn_mfma_f32_16x16x32_f16(ax, wzi, aZ[rf], 0, 0, 0);
            aZ[rf]  = __builtin_amdgcn_mfma_f32_16x16x32_f16(ah, wzh, aZ[rf], 0, 0, 0);
            aNi[rf] = __builtin_amdgcn_mfma_f32_16x16x32_f16(ax, wni, aNi[rf], 0, 0, 0);
            aNh[rf] = __builtin_amdgcn_mfma_f32_16x16x32_f16(ah, wnh, aNh[rf], 0, 0, 0);
        }
    }

#pragma unroll
    for (int rf = 0; rf < 4; ++rf) {
#pragma unroll
        for (int i = 0; i < 4; ++i) {
            const int m = bm + rf * 16 + quad * 4 + i;
            if (m >= M) continue;
            const float rg = fsig(aR[rf][i] + br);
            const float zg = fsig(aZ[rf][i] + bz);
            const float ng = ftanh(aNi[rf][i] + bni + rg * (aNh[rf][i] + bnh));
            const float hp = (float)((const _Float16*)sH)[(rf * 16 + quad * 4 + i) * 136 + j];
            const float v = (1.f - zg) * ng + zg * hp;
            xout[(size_t)m * 128 + j] = (_Float16)(v > 0.f ? v : 0.f);
        }
    }
}

// ---------------------------------------------------------------------------
// CSR build: histogram + two-level scan + slot fill (stateless per launch).
// ---------------------------------------------------------------------------
__global__ void hist_k(const int* __restrict__ ei, int* __restrict__ deg, int E)
{
    int e = blockIdx.x * 256 + threadIdx.x;
    if (e >= E) return;
    atomicAdd(deg + ei[E + e], 1);
}

__global__ __launch_bounds__(1024) void scan_part_k(const int* __restrict__ deg,
                                                    int* __restrict__ bsum, int n)
{
    __shared__ int sh[1024];
    const int t = threadIdx.x;
    const int i = blockIdx.x * 1024 + t;
    sh[t] = (i < n) ? deg[i] : 0;
    __syncthreads();
#pragma unroll
    for (int off = 512; off; off >>= 1) {
        if (t < off) sh[t] += sh[t + off];
        __syncthreads();
    }
    if (t == 0) bsum[blockIdx.x] = sh[0];
}

__global__ void scan_tops_k(const int* __restrict__ bsum, int* __restrict__ boff,
                            int nb, int* __restrict__ rowptr, int n)
{
    if (threadIdx.x != 0 || blockIdx.x != 0) return;
    int run = 0;
    for (int b = 0; b < nb; ++b) { boff[b] = run; run += bsum[b]; }
    rowptr[n] = run;
}

__global__ __launch_bounds__(1024) void scan_final_k(const int* __restrict__ deg,
                                                     const int* __restrict__ boff,
                                                     int* __restrict__ rowptr, int n)
{
    __shared__ int sh[1024];
    const int t = threadIdx.x;
    const int i = blockIdx.x * 1024 + t;
    const int v = (i < n) ? deg[i] : 0;
    sh[t] = v;
    __syncthreads();
#pragma unroll
    for (int off = 1; off < 1024; off <<= 1) {
        int add = (t >= off) ? sh[t - off] : 0;
        __syncthreads();
        sh[t] += add;
        __syncthreads();
    }
    if (i < n) rowptr[i] = boff[blockIdx.x] + sh[t] - v;   // exclusive
}

__global__ void fill_csr_k(const int* __restrict__ ei, const int* __restrict__ rowptr,
                           int* __restrict__ cursor, int* __restrict__ csr_src,
                           int* __restrict__ csr_eid, int E)
{
    int e = blockIdx.x * 256 + threadIdx.x;
    if (e >= E) return;
    int s = ei[e], d = ei[E + e];
    int pos = atomicAdd(cursor + d, 1);
    int slot = rowptr[d] + pos;
    csr_src[slot] = s;
    csr_eid[slot] = e;
}

// batch is sorted: fill gptr[g] = first node of graph g (gptr[G] = N)
__global__ void gptr_k(const int* __restrict__ batch, int* __restrict__ gptr,
                       int N, int G)
{
    int n = blockIdx.x * 256 + threadIdx.x;
    if (n >= N) return;
    if (n == 0) {
        for (int g = 0; g <= batch[0]; ++g) gptr[g] = 0;
    } else {
        const int a = batch[n - 1], b = batch[n];
        for (int g = a + 1; g <= b; ++g) gptr[g] = n;
    }
    if (n == N - 1) {
        for (int g = batch[N - 1] + 1; g <= G; ++g) gptr[g] = N;
    }
}

// per-graph contiguous sum (no atomics): agg = sum, oA = relu(sum)
__global__ __launch_bounds__(128) void graph_sum_k(
    const _Float16* __restrict__ xc, const int* __restrict__ gptr,
    float* __restrict__ agg, float* __restrict__ oA)
{
    const int g = blockIdx.x;
    const int t = threadIdx.x;   // feature
    const int n0 = gptr[g], n1 = gptr[g + 1];
    float acc = 0.f;
    for (int n = n0; n < n1; ++n) acc += (float)xc[(size_t)n * 128 + t];
    agg[(size_t)g * 128 + t] = acc;
    oA[(size_t)g * 128 + t] = acc > 0.f ? acc : 0.f;
}

// ---------------------------------------------------------------------------
// Multi-segment fp32 -> f16 conversion (one dispatch for all flat tensors)
// ---------------------------------------------------------------------------
struct CvtSeg { const float* src; _Float16* dst; int n; };
struct CvtArgs { CvtSeg s[10]; int count; };

__global__ void cvt_multi_k(CvtArgs a)
{
    const int seg = blockIdx.y;
    if (seg >= a.count) return;
    const CvtSeg cs = a.s[seg];
    for (int i = blockIdx.x * 256 + threadIdx.x; i < cs.n; i += gridDim.x * 256)
        cs.dst[i] = (_Float16)cs.src[i];
}

// nd_lin1_w[:,0:128] (pitch 144) -> packed f16 [128][128]
__global__ void cvt_ndwA_k(const float* __restrict__ ndw, _Float16* __restrict__ outp)
{
    int t = blockIdx.x * 256 + threadIdx.x;
    if (t >= 16384) return;
    int r = t >> 7, c = t & 127;
    outp[r * 128 + c] = (_Float16)ndw[r * 144 + c];
}

// nd_lin1_w[:,128:144] (pitch 144) -> f16 table [128][16]
__global__ void cvt_ndwB_k(const float* __restrict__ ndw, _Float16* __restrict__ outp)
{
    int t = blockIdx.x * 256 + threadIdx.x;
    if (t >= 2048) return;
    int r = t >> 4, k = t & 15;
    outp[r * 16 + k] = (_Float16)ndw[r * 144 + 128 + k];
}

// ---------------------------------------------------------------------------
// nd_conv gather (f16 + fdot2): out f16
// ---------------------------------------------------------------------------
__global__ __launch_bounds__(128) void nd_gather_k(
    const int* __restrict__ rowptr, const int* __restrict__ csr_src,
    const int* __restrict__ csr_eid, const _Float16* __restrict__ eaH,
    const _Float16* __restrict__ wH, const _Float16* __restrict__ pH,
    _Float16* __restrict__ outp)
{
    const int d = blockIdx.x;
    const int t = threadIdx.x;
    const half8v w0 = *(const half8v*)(wH + t * 16);
    const half8v w1 = *(const half8v*)(wH + t * 16 + 8);

    const int b0 = rowptr[d], b1 = rowptr[d + 1];
    float acc = 0.f;
    for (int i = b0; i < b1; ++i) {
        const int s = csr_src[i], e = csr_eid[i];
        const half8v e0 = *(const half8v*)(eaH + (size_t)e * 16);
        const half8v e1 = *(const half8v*)(eaH + (size_t)e * 16 + 8);
        float q = 0.f;
        q = hdot2(H2(e0, 0), H2(w0, 0), q);
        q = hdot2(H2(e0, 1), H2(w0, 1), q);
        q = hdot2(H2(e0, 2), H2(w0, 2), q);
        q = hdot2(H2(e0, 3), H2(w0, 3), q);
        q = hdot2(H2(e1, 0), H2(w1, 0), q);
        q = hdot2(H2(e1, 1), H2(w1, 1), q);
        q = hdot2(H2(e1, 2), H2(w1, 2), q);
        q = hdot2(H2(e1, 3), H2(w1, 3), q);
        const float v = (float)pH[(size_t)s * 128 + t] + q;
        acc += v >= 0.f ? v : 0.01f * v;
    }
    outp[(size_t)d * 128 + t] = (_Float16)acc;
}

// per-node dots (f16 xp)
__global__ void node_dots_k(const _Float16* __restrict__ xp,
                            const float* __restrict__ asrc,
                            const float* __restrict__ adst,
                            float* __restrict__ ssrc, float* __restrict__ sdst)
{
    int n = blockIdx.x, t = threadIdx.x;   // 128 threads
    float v = (float)xp[(size_t)n * 128 + t];
    float a = v * asrc[t];
    float b = v * adst[t];
    for (int off = 32; off; off >>= 1) { a += __shfl_down(a, off); b += __shfl_down(b, off); }
    __shared__ float sa[2], sb[2];
    if ((t & 63) == 0) { sa[t >> 6] = a; sb[t >> 6] = b; }
    __syncthreads();
    if (t == 0) { ssrc[n] = sa[0] + sa[1]; sdst[n] = sb[0] + sb[1]; }
}

// ---------------------------------------------------------------------------
// Fused GAT aggregation (exact softmax; f16 xp gather; f16 out; fast exp)
// ---------------------------------------------------------------------------
__global__ __launch_bounds__(128) void gat_gather_k(
    const int* __restrict__ rowptr, const int* __restrict__ csr_src,
    const float* __restrict__ ssrc, const float* __restrict__ sdst,
    const _Float16* __restrict__ xp, const float* __restrict__ bias,
    _Float16* __restrict__ outp)
{
    const int d = blockIdx.x;
    const int t = threadIdx.x;
    __shared__ float red[128];
    __shared__ float lw[128];
    __shared__ int   ls[128];
    __shared__ float racc[4][128];

    const int b0 = rowptr[d], b1 = rowptr[d + 1];
    const int deg = b1 - b0;
    const float sdd = sdst[d];

    float lm = -INFINITY;
    for (int i = b0 + t; i < b1; i += 128) {
        float a = ssrc[csr_src[i]] + sdd;
        a = a >= 0.f ? a : 0.01f * a;
        lm = fmaxf(lm, a);
    }
    red[t] = lm;
    __syncthreads();
#pragma unroll
    for (int off = 64; off; off >>= 1) {
        if (t < off) red[t] = fmaxf(red[t], red[t + off]);
        __syncthreads();
    }
    const float amax = red[0];
    __syncthreads();

    const int g  = t >> 5;
    const int fq = t & 31;
    float4 acc = make_float4(0.f, 0.f, 0.f, 0.f);
    float dpart = 0.f;
    for (int base = b0; base < b1; base += 128) {
        const int len = min(128, b1 - base);
        if (t < len) {
            const int s = csr_src[base + t];
            float a = ssrc[s] + sdd;
            a = a >= 0.f ? a : 0.01f * a;
            const float w = __expf(a - amax);   // <= 0 arg, safe
            lw[t] = w;
            ls[t] = s;
            dpart += w;
        }
        __syncthreads();
        for (int j = 0; j < len; j += 4) {
            const int jj = j + g;
            if (jj < len) {
                const float w = lw[jj];
                const half4v hv = *(const half4v*)(xp + (size_t)ls[jj] * 128 + fq * 4);
                acc.x += w * (float)hv[0];
                acc.y += w * (float)hv[1];
                acc.z += w * (float)hv[2];
                acc.w += w * (float)hv[3];
            }
        }
        __syncthreads();
    }

    red[t] = dpart;
    __syncthreads();
#pragma unroll
    for (int off = 64; off; off >>= 1) {
        if (t < off) red[t] += red[t + off];
        __syncthreads();
    }
    const float denom = red[0];

    racc[g][fq * 4 + 0] = acc.x;
    racc[g][fq * 4 + 1] = acc.y;
    racc[g][fq * 4 + 2] = acc.z;
    racc[g][fq * 4 + 3] = acc.w;
    __syncthreads();

    const float s4 = racc[0][t] + racc[1][t] + racc[2][t] + racc[3][t];
    float v = (deg > 0 ? s4 / denom : 0.f) + bias[t];
    outp[(size_t)d * 128 + t] = (_Float16)(v > 0.f ? v : __expf(v) - 1.f);   // elu
}

__global__ void add_k(const float* __restrict__ a, const float* __restrict__ b,
                      float* __restrict__ c, int total)
{
    int gid = blockIdx.x * 256 + threadIdx.x;
    if (gid >= total) return;
    c[gid] = a[gid] + b[gid];
}

__global__ void lstm_combine_k(const float* __restrict__ g1, const float* __restrict__ g2,
                               const float* __restrict__ hg, float* __restrict__ outp, int total)
{
    int gid = blockIdx.x * 256 + threadIdx.x;
    if (gid >= total) return;
    int g = gid >> 7, j = gid & 127;
    const float* a = g1 + g * 512;
    const float* b = g2 + g * 512;
    float ii = a[j]       + b[j];
    float ff = a[j + 128] + b[j + 128];
    float gg = a[j + 256] + b[j + 256];
    float oo = a[j + 384] + b[j + 384];
    float c  = hg[gid];
    float c2 = sigf(ff) * c + sigf(ii) * tanhf(gg);
    outp[gid] = sigf(oo) * tanhf(c2);
}

__global__ void final_k(const float* __restrict__ oin, const float* __restrict__ w,
                        const float* __restrict__ b, float* __restrict__ y)
{
    int g = blockIdx.x, t = threadIdx.x;  // 128 threads
    float v = oin[g * 128 + t] * w[t];
    for (int off = 32; off; off >>= 1) v += __shfl_down(v, off);
    __shared__ float s2[2];
    if ((t & 63) == 0) s2[t >> 6] = v;
    __syncthreads();
    if (t == 0) y[g] = s2[0] + s2[1] + b[0];
}

// ---------------------------------------------------------------------------

extern "C" void kernel_launch(void* const* d_in, const int* in_sizes, int n_in,
                              void* d_out, int out_size, void* d_ws, size_t ws_size,
                              hipStream_t stream)
{
    const float* x      = (const float*)d_in[0];
    const int*   ei     = (const int*)  d_in[1];
    const float* ea     = (const float*)d_in[2];
    const int*   batch  = (const int*)  d_in[3];
    const float* lin1_w = (const float*)d_in[4];
    const float* lin1_b = (const float*)d_in[5];
    const float* nd1w   = (const float*)d_in[6];
    const float* nd2w   = (const float*)d_in[7];
    const float* ndb    = (const float*)d_in[8];
    const float* g0wih  = (const float*)d_in[9];
    const float* g0whh  = (const float*)d_in[10];
    const float* g0bih  = (const float*)d_in[11];
    const float* g0bhh  = (const float*)d_in[12];
    const float* gatw   = (const float*)d_in[13];
    const float* gatas  = (const float*)d_in[14];
    const float* gatad  = (const float*)d_in[15];
    const float* gatb   = (const float*)d_in[16];
    const float* gwih   = (const float*)d_in[17];
    const float* gwhh   = (const float*)d_in[18];
    const float* gbih   = (const float*)d_in[19];
    const float* gbhh   = (const float*)d_in[20];
    const float* ginw   = (const float*)d_in[21];
    const float* ginb   = (const float*)d_in[22];
    const float* lwih   = (const float*)d_in[23];
    const float* lwhh   = (const float*)d_in[24];
    const float* lbih   = (const float*)d_in[25];
    const float* lbhh   = (const float*)d_in[26];
    const float* l2w    = (const float*)d_in[27];
    const float* l2b    = (const float*)d_in[28];
    float* outp = (float*)d_out;

    const int N = NN, E = EE, G = GG;

    float* ws = (float*)d_ws;
    size_t off = 0;
    auto alloc = [&](size_t n) {
        float* r = ws + off;
        off += (n + 63) & ~(size_t)63;
        return r;
    };
    // f16 node pipeline (sizes in floats = halves/2)
    _Float16* xH    = (_Float16*)alloc((size_t)N * 32);   // N*64
    _Float16* x1H   = (_Float16*)alloc((size_t)N * 64);   // N*128 (ping)
    _Float16* hbufH = (_Float16*)alloc((size_t)N * 64);
    _Float16* accbH = (_Float16*)alloc((size_t)N * 64);
    _Float16* xcH   = (_Float16*)alloc((size_t)N * 64);   // (pong)
    _Float16* pH    = (_Float16*)alloc((size_t)N * 64);
    _Float16* eaH   = (_Float16*)alloc((size_t)E * 8);    // E*16
    // f16 weights
    _Float16* lin1_wH = (_Float16*)alloc(4096);           // 128x64
    _Float16* nd1wAH  = (_Float16*)alloc(8192);           // 128x128
    _Float16* ndwBH   = (_Float16*)alloc(1024);           // 128x16
    _Float16* nd2wH   = (_Float16*)alloc(8192);
    _Float16* g0wihH  = (_Float16*)alloc(24576);
    _Float16* g0whhH  = (_Float16*)alloc(24576);
    _Float16* gwihH   = (_Float16*)alloc(49152);          // 2 layers
    _Float16* gwhhH   = (_Float16*)alloc(49152);
    _Float16* gatwH   = (_Float16*)alloc(16384);          // 2 layers
    // fp32 readout scratch
    float* ssrc = alloc((size_t)N);
    float* sdst = alloc((size_t)N);
    float* agg  = alloc((size_t)G * 128);
    float* oA   = alloc((size_t)G * 128);
    float* oB   = alloc((size_t)G * 128);
    float* hgb  = alloc((size_t)G * 128);
    float* tGA  = alloc((size_t)G * 128);
    float* g1b  = alloc((size_t)G * 512);
    float* g2b  = alloc((size_t)G * 512);
    // CSR + graph ptr
    int* deg     = (int*)alloc((size_t)N);
    int* rowptr  = (int*)alloc((size_t)N + 1);
    int* cursor  = (int*)alloc((size_t)N);
    int* bsum    = (int*)alloc(64);
    int* boff    = (int*)alloc(64);
    int* csr_src = (int*)alloc((size_t)E);
    int* csr_eid = (int*)alloc((size_t)E);
    int* gptr    = (int*)alloc((size_t)G + 1);
    (void)ws_size;

    auto gemmh = [&](const _Float16* A, const _Float16* W, const float* bias,
                     _Float16* C, int M, int K, int Nout, int act) {
        dim3 grid(Nout / 64, (M + 63) / 64);
        gemm_f16_k<<<grid, 256, 0, stream>>>(A, W, bias, C, M, K, Nout, act);
    };
    auto gemmf = [&](const float* A, const float* W, const float* bias, float* C,
                     int M, int K, int Nout, int wpitch, int act) {
        dim3 grid(Nout / 64, (M + 63) / 64);
        gemm_mfma_k<<<grid, 256, 0, stream>>>(A, W, bias, C, M, K, Nout, wpitch, act);
    };
    auto nb = [](int n) { return (n + 255) / 256; };

    auto gru = [&](const _Float16* xin, const _Float16* hin,
                   const _Float16* wih, const _Float16* whh,
                   const float* bih, const float* bhh, _Float16* xout) {
        dim3 grid((N + 63) / 64, 2);
        gru_fused4_k<<<grid, 256, 0, stream>>>(
            xin, hin, wih, whh, bih, bhh, xout, N);
    };

    // 0) CSR build + gptr + all f16 conversions
    hipMemsetAsync(deg, 0, (size_t)N * 4, stream);
    hipMemsetAsync(cursor, 0, (size_t)N * 4, stream);
    hist_k<<<nb(E), 256, 0, stream>>>(ei, deg, E);
    const int nblk = (N + 1023) / 1024;   // 49
    scan_part_k<<<nblk, 1024, 0, stream>>>(deg, bsum, N);
    scan_tops_k<<<1, 64, 0, stream>>>(bsum, boff, nblk, rowptr, N);
    scan_final_k<<<nblk, 1024, 0, stream>>>(deg, boff, rowptr, N);
    fill_csr_k<<<nb(E), 256, 0, stream>>>(ei, rowptr, cursor, csr_src, csr_eid, E);
    gptr_k<<<nb(N), 256, 0, stream>>>(batch, gptr, N, G);

    CvtArgs ca;
    ca.s[0] = { ea,     eaH,     E * 16 };
    ca.s[1] = { x,      xH,      N * 64 };
    ca.s[2] = { lin1_w, lin1_wH, 8192 };
    ca.s[3] = { nd2w,   nd2wH,   16384 };
    ca.s[4] = { g0wih,  g0wihH,  49152 };
    ca.s[5] = { g0whh,  g0whhH,  49152 };
    ca.s[6] = { gwih,   gwihH,   98304 };
    ca.s[7] = { gwhh,   gwhhH,   98304 };
    ca.s[8] = { gatw,   gatwH,   32768 };
    ca.count = 9;
    cvt_multi_k<<<dim3(2048, 9), 256, 0, stream>>>(ca);
    cvt_ndwA_k<<<64, 256, 0, stream>>>(nd1w, nd1wAH);
    cvt_ndwB_k<<<8, 256, 0, stream>>>(nd1w, ndwBH);

    // 1) x1 = leaky(x @ lin1_w^T + lin1_b)
    gemmh(xH, lin1_wH, lin1_b, x1H, N, 64, 128, 1);

    // 2) nd_conv (W2 hoisted): p = x1 @ W1a^T; gather; h = elu(acc @ W2^T + ndb)
    gemmh(x1H, nd1wAH, nullptr, pH, N, 128, 128, 0);
    nd_gather_k<<<N, 128, 0, stream>>>(rowptr, csr_src, csr_eid, eaH, ndwBH, pH, accbH);
    gemmh(accbH, nd2wH, ndb, hbufH, N, 128, 128, 2);

    // 3) xcur = relu(gru_cell(h, x1))
    gru(hbufH, x1H, g0wihH, g0whhH, g0bih, g0bhh, xcH);

    // 4) GAT layers
    const _Float16* xcur = xcH;
    _Float16* xnext = x1H;
    for (int l = 0; l < 2; ++l) {
        gemmh(xcur, gatwH + (size_t)l * 16384, nullptr, pH, N, 128, 128, 0);
        node_dots_k<<<N, 128, 0, stream>>>(pH, gatas + l * 128, gatad + l * 128, ssrc, sdst);
        gat_gather_k<<<N, 128, 0, stream>>>(rowptr, csr_src, ssrc, sdst, pH,
                                            gatb + l * 128, hbufH);
        gru(hbufH, xcur, gwihH + (size_t)l * 49152, gwhhH + (size_t)l * 49152,
            gbih + l * 384, gbhh + l * 384, xnext);
        const _Float16* t = xcur; xcur = xnext; xnext = (_Float16*)t;
    }

    // 5) readout: per-graph contiguous sum (batch sorted; no atomics)
    graph_sum_k<<<G, 128, 0, stream>>>(xcur, gptr, agg, oA);

    // 6) T=2 GIN+LSTM refinement (fp32, G-scale)
    float* cur = oA; float* nxt = oB;
    for (int t = 0; t < 2; ++t) {
        add_k<<<nb(G * 128), 256, 0, stream>>>(cur, agg, tGA, G * 128);
        gemmf(tGA, ginw, ginb, hgb, G, 128, 128, 128, 2);
        gemmf(cur, lwih, lbih, g1b, G, 128, 512, 128, 0);
        gemmf(hgb, lwhh, lbhh, g2b, G, 128, 512, 128, 0);
        lstm_combine_k<<<nb(G * 128), 256, 0, stream>>>(g1b, g2b, hgb, nxt, G * 128);
        float* tmp = cur; cur = nxt; nxt = tmp;
    }

    // 7) y = out @ lin2_w^T + lin2_b
    final_k<<<G, 128, 0, stream>>>(cur, l2w, l2b, outp);
}